// Round 1
// baseline (1252.497 us; speedup 1.0000x reference)
//
#include <hip/hip_runtime.h>
#include <float.h>

#define DD 768
#define SS 2048
#define BB 4
#define BSR (BB*SS)   // 8192 total rows
#define KNEI 32

// C[m][n] = epilogue( sum_k A[m][k]*Bw[n][k] )   (NT gemm, both row-major over k)
// MODE 0: + bias[n]
// MODE 1: relu(+ bias[n])
// MODE 2: rm[m] + rn[n] - 2*acc      (squared euclidean distance)
template<int MODE>
__global__ __launch_bounds__(256)
void gemm_nt(const float* __restrict__ A, const float* __restrict__ Bw,
             const float* __restrict__ bias,
             const float* __restrict__ rm, const float* __restrict__ rn,
             float* __restrict__ C,
             int M, int N, int K,
             long sA, long sB, long sC, long sR)
{
    int z = blockIdx.z;
    A  += (long)z * sA;
    Bw += (long)z * sB;
    C  += (long)z * sC;
    const float* rmz = (MODE == 2) ? rm + (long)z * sR : nullptr;
    const float* rnz = (MODE == 2) ? rn + (long)z * sR : nullptr;

    __shared__ float As[16][68];  // [k][m], padded: write banks 2-way (free)
    __shared__ float Bs[16][68];  // [k][n]

    int tid = threadIdx.x;
    int tx = tid & 15, ty = tid >> 4;
    int m0 = blockIdx.y * 64;
    int n0 = blockIdx.x * 64;

    float acc[4][4] = {};

    for (int k0 = 0; k0 < K; k0 += 16) {
        #pragma unroll
        for (int i = 0; i < 4; ++i) {
            int l = tid + 256 * i;      // 0..1023
            int row = l >> 4;           // 0..63
            int kk  = l & 15;
            As[kk][row] = A [(long)(m0 + row) * K + k0 + kk];
            Bs[kk][row] = Bw[(long)(n0 + row) * K + k0 + kk];
        }
        __syncthreads();
        #pragma unroll
        for (int kk = 0; kk < 16; ++kk) {
            float a[4], b[4];
            #pragma unroll
            for (int i = 0; i < 4; ++i) a[i] = As[kk][ty * 4 + i];
            #pragma unroll
            for (int j = 0; j < 4; ++j) b[j] = Bs[kk][tx * 4 + j];
            #pragma unroll
            for (int i = 0; i < 4; ++i)
                #pragma unroll
                for (int j = 0; j < 4; ++j)
                    acc[i][j] += a[i] * b[j];
        }
        __syncthreads();
    }

    #pragma unroll
    for (int i = 0; i < 4; ++i) {
        int m = m0 + ty * 4 + i;
        #pragma unroll
        for (int j = 0; j < 4; ++j) {
            int n = n0 + tx * 4 + j;
            float val = acc[i][j];
            if (MODE == 0) { val += bias[n]; }
            if (MODE == 1) { val += bias[n]; val = val > 0.f ? val : 0.f; }
            if (MODE == 2) { val = rmz[m] + rnz[n] - 2.f * val; }
            C[(long)m * N + n] = val;
        }
    }
}

// row squared-norms of q and k (16384 rows total, one wave per row)
__global__ __launch_bounds__(256)
void rownorm(const float* __restrict__ q, const float* __restrict__ k,
             float* __restrict__ qn, float* __restrict__ kn)
{
    int row  = blockIdx.x * 4 + (threadIdx.x >> 6);
    int lane = threadIdx.x & 63;
    const float* src;
    float* dst;
    if (row < BSR) { src = q + (long)row * DD;         dst = qn + row; }
    else           { src = k + (long)(row - BSR) * DD; dst = kn + (row - BSR); }
    float s = 0.f;
    #pragma unroll
    for (int j = 0; j < DD / 64; ++j) {
        float x = src[lane + j * 64];
        s += x * x;
    }
    #pragma unroll
    for (int off = 32; off; off >>= 1) s += __shfl_down(s, off);
    if (lane == 0) *dst = s;
}

// per query row: 32x masked argmin over 2048 sq-distances, accumulate mean of v rows
__global__ __launch_bounds__(256)
void select_mean(const float* __restrict__ dist, const float* __restrict__ v,
                 float* __restrict__ topo)
{
    int g = blockIdx.x;               // global row 0..8191
    int b = g >> 11;                  // batch
    const float* drow = dist + (long)b * SS * SS + (long)(g & (SS - 1)) * SS;
    const float* vb   = v    + (long)b * SS * DD;

    __shared__ float sd[SS];
    __shared__ float wmin[4];
    __shared__ int   widx[4];
    __shared__ int   ssel;

    int tid = threadIdx.x;
    #pragma unroll
    for (int i = 0; i < SS / 256; ++i) {
        int j = tid + i * 256;
        float x = drow[j];
        sd[j] = x > 0.f ? x : 0.f;    // clamp like reference's max(sq,0)
    }
    __syncthreads();

    float acc0 = 0.f, acc1 = 0.f, acc2 = 0.f;

    for (int t = 0; t < KNEI; ++t) {
        float val = FLT_MAX;
        int   idx = SS;
        #pragma unroll
        for (int i = 0; i < SS / 256; ++i) {
            int j = tid + i * 256;
            float x = sd[j];
            if (x < val) { val = x; idx = j; }   // strict < keeps lowest index
        }
        #pragma unroll
        for (int off = 32; off; off >>= 1) {
            float ov = __shfl_down(val, off);
            int   oi = __shfl_down(idx, off);
            if (ov < val || (ov == val && oi < idx)) { val = ov; idx = oi; }
        }
        if ((tid & 63) == 0) { wmin[tid >> 6] = val; widx[tid >> 6] = idx; }
        __syncthreads();
        if (tid == 0) {
            float bv = wmin[0]; int bi = widx[0];
            #pragma unroll
            for (int w = 1; w < 4; ++w) {
                if (wmin[w] < bv || (wmin[w] == bv && widx[w] < bi)) { bv = wmin[w]; bi = widx[w]; }
            }
            ssel = bi;
            sd[bi] = FLT_MAX;         // mask the chosen one
        }
        __syncthreads();
        const float* vr = vb + (long)ssel * DD;
        acc0 += vr[tid];
        acc1 += vr[tid + 256];
        acc2 += vr[tid + 512];
    }

    const float sc = 1.0f / 32.0f;
    float* tr = topo + (long)g * DD;
    tr[tid]       = acc0 * sc;
    tr[tid + 256] = acc1 * sc;
    tr[tid + 512] = acc2 * sc;
}

extern "C" void kernel_launch(void* const* d_in, const int* in_sizes, int n_in,
                              void* d_out, int out_size, void* d_ws, size_t ws_size,
                              hipStream_t stream)
{
    const float* hs = (const float*)d_in[0];
    const float* Wq = (const float*)d_in[1];
    const float* bq = (const float*)d_in[2];
    const float* Wk = (const float*)d_in[3];
    const float* bk = (const float*)d_in[4];
    const float* Wv = (const float*)d_in[5];
    const float* bv = (const float*)d_in[6];
    const float* W1 = (const float*)d_in[7];
    const float* b1 = (const float*)d_in[8];
    const float* W2 = (const float*)d_in[9];
    const float* b2 = (const float*)d_in[10];
    float* out = (float*)d_out;

    float* ws = (float*)d_ws;
    float* q    = ws;                        // 8192*768
    float* k    = q    + (long)BSR * DD;     // 8192*768
    float* v    = k    + (long)BSR * DD;     // 8192*768
    float* qn   = v    + (long)BSR * DD;     // 8192
    float* kn   = qn   + BSR;                // 8192
    float* dist = kn   + BSR;                // 4*2048*2048
    float* topo = dist + (long)BB * SS * SS; // 8192*768
    float* h    = q;                         // reuse q region after selection

    dim3 blk(256);

    // QKV projections
    gemm_nt<0><<<dim3(DD / 64, BSR / 64, 1), blk, 0, stream>>>(
        hs, Wq, bq, nullptr, nullptr, q, BSR, DD, DD, 0, 0, 0, 0);
    gemm_nt<0><<<dim3(DD / 64, BSR / 64, 1), blk, 0, stream>>>(
        hs, Wk, bk, nullptr, nullptr, k, BSR, DD, DD, 0, 0, 0, 0);
    gemm_nt<0><<<dim3(DD / 64, BSR / 64, 1), blk, 0, stream>>>(
        hs, Wv, bv, nullptr, nullptr, v, BSR, DD, DD, 0, 0, 0, 0);

    // row norms
    rownorm<<<(2 * BSR) / 4, blk, 0, stream>>>(q, k, qn, kn);

    // squared distance matrix, per batch
    gemm_nt<2><<<dim3(SS / 64, SS / 64, BB), blk, 0, stream>>>(
        q, k, nullptr, qn, kn, dist, SS, SS, DD,
        (long)SS * DD, (long)SS * DD, (long)SS * SS, SS);

    // top-32 select + gather-mean of v
    select_mean<<<BSR, blk, 0, stream>>>(dist, v, topo);

    // MLP
    gemm_nt<1><<<dim3(DD / 64, BSR / 64, 1), blk, 0, stream>>>(
        topo, W1, b1, nullptr, nullptr, h, BSR, DD, DD, 0, 0, 0, 0);
    gemm_nt<0><<<dim3(DD / 64, BSR / 64, 1), blk, 0, stream>>>(
        h, W2, b2, nullptr, nullptr, out, BSR, DD, DD, 0, 0, 0, 0);
}

// Round 4
// 697.667 us; speedup vs baseline: 1.7953x; 1.7953x over previous
//
#include <hip/hip_runtime.h>
#include <float.h>

#define DD 768
#define SS 2048
#define BB 4
#define BSR (BB*SS)   // 8192 total rows
#define KNEI 32
#define K2 (3*DD)     // 2304: [hi | x | y] split concat along K
#define MARGIN 5e-4f

typedef __attribute__((ext_vector_type(8))) _Float16 f16x8;
typedef __attribute__((ext_vector_type(4))) float f32x4;
typedef __attribute__((ext_vector_type(8))) unsigned short u16x8;

__device__ __forceinline__ float f16f(unsigned short u) {
    return (float)__builtin_bit_cast(_Float16, u);
}
__device__ __forceinline__ unsigned short ff16(float x) {
    return __builtin_bit_cast(unsigned short, (_Float16)x);
}

__device__ __forceinline__ void gload_lds16(const void* g, void* l) {
    __builtin_amdgcn_global_load_lds(
        (const __attribute__((address_space(1))) unsigned int*)g,
        (__attribute__((address_space(3))) unsigned int*)l, 16, 0, 0);
}

// fp32 -> 3-slot f16 split with power-of-2 rebalanced correction slots.
// A-layout (LO_SLOT=1): [h, l*2^6, h*2^-6];  B-layout (LO_SLOT=2): [h, h*2^-6, l*2^6]
// Paired products: h*h + (l_a*2^6)(h_b*2^-6) + (h_a*2^-6)(l_b*2^6) = h_a h_b + l_a h_b + h_a l_b
template<int LO_SLOT>
__global__ __launch_bounds__(256)
void split_f16(const float* __restrict__ in, unsigned short* __restrict__ out, int Kc)
{
    int idx = blockIdx.x * 256 + threadIdx.x;   // one 8-elem chunk per thread
    int perRow = Kc >> 3;
    int row = idx / perRow, c8 = idx - row * perRow;
    const float* src = in + (long)row * Kc + c8 * 8;
    f32x4 x0 = *(const f32x4*)&src[0];
    f32x4 x1 = *(const f32x4*)&src[4];
    u16x8 hi, lsc, hsc;
    #pragma unroll
    for (int e = 0; e < 8; ++e) {
        float xv = (e < 4) ? x0[e] : x1[e - 4];
        _Float16 h = (_Float16)xv;
        float hf = (float)h;
        float l = xv - hf;
        hi[e]  = __builtin_bit_cast(unsigned short, h);
        lsc[e] = ff16(l * 64.f);
        hsc[e] = ff16(hf * 0.015625f);
    }
    long base = (long)row * (3 * Kc) + c8 * 8;
    *(u16x8*)&out[base] = hi;
    *(u16x8*)&out[base + Kc]     = (LO_SLOT == 1) ? lsc : hsc;
    *(u16x8*)&out[base + 2 * Kc] = (LO_SLOT == 1) ? hsc : lsc;
}

// C[m][n] = epilogue( sum_k A[m][k]*B[n][k] ), A:[M][Kd] f16, B:[N][Kd] f16, NT.
// MODE 0: +bias[n];  MODE 1: relu(+bias[n]);  MODE 2: rm[m]+rn[n]-2*acc
template<int MODE>
__global__ __launch_bounds__(256)
void gemm_mfma(const unsigned short* __restrict__ A, const unsigned short* __restrict__ B,
               const float* __restrict__ bias,
               const float* __restrict__ rm, const float* __restrict__ rn,
               float* __restrict__ C,
               int M, int N, int Kd,
               long sA, long sB, long sC, long sR)
{
    int z = blockIdx.z;
    A += (long)z * sA;
    B += (long)z * sB;
    C += (long)z * sC;
    const float* rmz = (MODE == 2) ? rm + (long)z * sR : nullptr;
    const float* rnz = (MODE == 2) ? rn + (long)z * sR : nullptr;

    __shared__ __align__(16) unsigned short Asm[128 * 64];  // [row][64k], 16B chunks XOR-swizzled
    __shared__ __align__(16) unsigned short Bsm[128 * 64];

    const int tid = threadIdx.x;
    const int lane = tid & 63;
    const int wave = tid >> 6;
    const int wm = wave >> 1, wn = wave & 1;
    const int m0 = blockIdx.y * 128, n0 = blockIdx.x * 128;
    const int r15 = lane & 15;
    const int g4 = lane >> 4;

    f32x4 acc[4][4] = {};

    // staging: linear LDS dest, XOR-swizzled global source chunk (involution matches read)
    long aByte[4], bByte[4];
    int ldsOff[4];
    #pragma unroll
    for (int i = 0; i < 4; ++i) {
        int L = i * 256 + tid;
        int row = L >> 3, ch = L & 7;
        int chs = ch ^ (row & 7);
        aByte[i] = (long)(m0 + row) * Kd * 2 + chs * 16;
        bByte[i] = (long)(n0 + row) * Kd * 2 + chs * 16;
        ldsOff[i] = L * 8;
    }

    for (int k0 = 0; k0 < Kd; k0 += 64) {
        long kb = (long)k0 * 2;
        #pragma unroll
        for (int i = 0; i < 4; ++i)
            gload_lds16((const char*)A + aByte[i] + kb, &Asm[ldsOff[i]]);
        #pragma unroll
        for (int i = 0; i < 4; ++i)
            gload_lds16((const char*)B + bByte[i] + kb, &Bsm[ldsOff[i]]);
        __syncthreads();

        #pragma unroll
        for (int ks = 0; ks < 2; ++ks) {
            f16x8 af[4], bfr[4];
            #pragma unroll
            for (int i = 0; i < 4; ++i) {
                int row = wm * 64 + i * 16 + r15;
                int chs = (ks * 4 + g4) ^ (r15 & 7);
                af[i] = *(const f16x8*)&Asm[row * 64 + chs * 8];
            }
            #pragma unroll
            for (int j = 0; j < 4; ++j) {
                int row = wn * 64 + j * 16 + r15;
                int chs = (ks * 4 + g4) ^ (r15 & 7);
                bfr[j] = *(const f16x8*)&Bsm[row * 64 + chs * 8];
            }
            #pragma unroll
            for (int i = 0; i < 4; ++i)
                #pragma unroll
                for (int j = 0; j < 4; ++j)
                    acc[i][j] = __builtin_amdgcn_mfma_f32_16x16x32_f16(
                        af[i], bfr[j], acc[i][j], 0, 0, 0);
        }
        __syncthreads();
    }

    // epilogue: C/D layout col=lane&15, row=(lane>>4)*4+reg
    float bj[4];
    #pragma unroll
    for (int j = 0; j < 4; ++j) {
        int n = n0 + wn * 64 + j * 16 + r15;
        bj[j] = (MODE == 2) ? rnz[n] : bias[n];
    }
    #pragma unroll
    for (int i = 0; i < 4; ++i) {
        #pragma unroll
        for (int r = 0; r < 4; ++r) {
            int m = m0 + wm * 64 + i * 16 + g4 * 4 + r;
            float rmv = (MODE == 2) ? rmz[m] : 0.f;
            #pragma unroll
            for (int j = 0; j < 4; ++j) {
                int n = n0 + wn * 64 + j * 16 + r15;
                float val = acc[i][j][r];
                if (MODE == 0) val += bj[j];
                if (MODE == 1) { val += bj[j]; val = fmaxf(val, 0.f); }
                if (MODE == 2) val = rmv + bj[j] - 2.f * val;
                C[(long)m * N + n] = val;
            }
        }
    }
}

// row squared-norms of q and k (fp32 sources)
__global__ __launch_bounds__(256)
void rownorm(const float* __restrict__ q, const float* __restrict__ k,
             float* __restrict__ qn, float* __restrict__ kn)
{
    int row  = blockIdx.x * 4 + (threadIdx.x >> 6);
    int lane = threadIdx.x & 63;
    const float* src;
    float* dst;
    if (row < BSR) { src = q + (long)row * DD;         dst = qn + row; }
    else           { src = k + (long)(row - BSR) * DD; dst = kn + (row - BSR); }
    float s = 0.f;
    #pragma unroll
    for (int j = 0; j < DD / 64; ++j) {
        float x = src[lane + j * 64];
        s += x * x;
    }
    #pragma unroll
    for (int off = 32; off; off >>= 1) s += __shfl_down(s, off);
    if (lane == 0) *dst = s;
}

// Block per query row (proven round-1 structure + barriers everywhere).
// 33 masked block-argmin iterations; boundary-gap guard with exact fp32
// recompute; then gather-mean of v. All fallback branches are block-uniform.
__global__ __launch_bounds__(256)
void select_mean(const float* __restrict__ dist, const float* __restrict__ v,
                 const unsigned short* __restrict__ q_s, const unsigned short* __restrict__ k_s,
                 const float* __restrict__ qn, const float* __restrict__ kn,
                 float* __restrict__ topo)
{
    int g = blockIdx.x;               // global row 0..8191
    int b = g >> 11;                  // batch
    const float* drow = dist + (long)b * SS * SS + (long)(g & (SS - 1)) * SS;
    const float* vb   = v    + (long)b * SS * DD;

    __shared__ float sd[SS];
    __shared__ float wmin[4];
    __shared__ int   widx[4];
    __shared__ int   sidx[KNEI];
    __shared__ float sred[4];
    __shared__ int   scnt;
    __shared__ int   bidx[64];
    __shared__ float bval[64];
    __shared__ float sd32, sd33;

    int tid = threadIdx.x;
    #pragma unroll
    for (int i = 0; i < SS / 256; ++i) {
        int j = tid + i * 256;
        float x = drow[j];
        sd[j] = x > 0.f ? x : 0.f;    // clamp like reference's max(sq,0)
    }
    __syncthreads();

    // 33 block-argmin iterations; mask the first 32 picks
    for (int t = 0; t < 33; ++t) {
        float val = FLT_MAX;
        int   idx = SS;
        #pragma unroll
        for (int i = 0; i < SS / 256; ++i) {
            int j = tid + i * 256;
            float x = sd[j];
            if (x < val) { val = x; idx = j; }   // strict < keeps lowest index
        }
        #pragma unroll
        for (int off = 32; off; off >>= 1) {
            float ov = __shfl_down(val, off);
            int   oi = __shfl_down(idx, off);
            if (ov < val || (ov == val && oi < idx)) { val = ov; idx = oi; }
        }
        if ((tid & 63) == 0) { wmin[tid >> 6] = val; widx[tid >> 6] = idx; }
        __syncthreads();
        if (tid == 0) {
            float bv = wmin[0]; int bi = widx[0];
            #pragma unroll
            for (int ww = 1; ww < 4; ++ww) {
                if (wmin[ww] < bv || (wmin[ww] == bv && widx[ww] < bi)) { bv = wmin[ww]; bi = widx[ww]; }
            }
            if (t < 32) {
                sidx[t] = bi;
                sd[bi] = FLT_MAX;     // mask the chosen one
                if (t == 31) sd32 = bv;
            } else {
                sd33 = bv;
            }
        }
        __syncthreads();
    }

    float d32v = sd32, d33v = sd33;   // block-uniform

    if (d33v - d32v < MARGIN) {
        float lo = d32v - MARGIN, hi = d33v + MARGIN;
        // compact boundary-window candidates (bounded LDS-atomic writes)
        if (tid == 0) scnt = 0;
        __syncthreads();
        #pragma unroll
        for (int i = 0; i < SS / 256; ++i) {
            int j = tid + i * 256;
            float x = drow[j]; x = x > 0.f ? x : 0.f;   // original value
            if (x >= lo && x <= hi) {
                int p = atomicAdd(&scnt, 1);
                if (p < 64) bidx[p] = j;
            }
        }
        __syncthreads();
        int bc = scnt;                 // uniform
        if (bc <= 64) {
            // exact fp32 recompute for each candidate (block-parallel dot)
            const unsigned short* qrow = q_s + (long)g * K2;
            for (int c = 0; c < bc; ++c) {
                int j = bidx[c] & (SS - 1);
                const unsigned short* krow = k_s + ((long)b * SS + j) * K2;
                float part = 0.f;
                #pragma unroll
                for (int i = 0; i < 3; ++i) {
                    int e = tid + i * 256;
                    float qv = f16f(qrow[e]) + f16f(qrow[DD + e]) * 0.015625f;      // A: slot1=l*2^6
                    float kv = f16f(krow[e]) + f16f(krow[2 * DD + e]) * 0.015625f;  // B: slot2=l*2^6
                    part = fmaf(qv, kv, part);
                }
                #pragma unroll
                for (int off = 32; off; off >>= 1) part += __shfl_down(part, off);
                if ((tid & 63) == 0) sred[tid >> 6] = part;
                __syncthreads();
                if (tid == 0) {
                    float dot = sred[0] + sred[1] + sred[2] + sred[3];
                    float dd = qn[g] + kn[(long)b * SS + j] - 2.f * dot;
                    bval[c] = dd > 0.f ? dd : 0.f;
                }
                __syncthreads();
            }
            // rebuild: certain members (selected & clearly inside), bounded writes
            if (tid == 0) scnt = 0;
            __syncthreads();
            #pragma unroll
            for (int i = 0; i < SS / 256; ++i) {
                int j = tid + i * 256;
                float x = drow[j]; x = x > 0.f ? x : 0.f;
                if (sd[j] == FLT_MAX && x < lo) {        // was selected & certain
                    int p = atomicAdd(&scnt, 1);
                    if (p < KNEI) sidx[p] = j;
                }
            }
            __syncthreads();
            if (tid == 0) {
                int C = scnt; if (C > KNEI) C = KNEI;
                int need = KNEI - C;
                for (int t = 0; t < need; ++t) {
                    float mv = FLT_MAX; int mc = -1;
                    for (int c = 0; c < bc; ++c) {
                        if (bval[c] < mv || (bval[c] == mv && mc >= 0 && bidx[c] < bidx[mc])) {
                            mv = bval[c]; mc = c;
                        }
                    }
                    if (mc >= 0) { sidx[C + t] = bidx[mc]; bval[mc] = FLT_MAX; }
                    else         { sidx[C + t] = sidx[0]; }   // unreachable; crash-safe
                }
            }
            __syncthreads();
        }
        // bc > 64: window absurdly crowded — keep approximate picks (no crash)
    }

    // gather-mean of v over the selected 32 rows (order irrelevant up to fp assoc.)
    float a0 = 0.f, a1 = 0.f, a2 = 0.f;
    for (int t = 0; t < KNEI; ++t) {
        int j = sidx[t] & (SS - 1);
        const float* vr = vb + (long)j * DD;
        a0 += vr[tid];
        a1 += vr[tid + 256];
        a2 += vr[tid + 512];
    }
    const float sc = 1.0f / 32.0f;
    float* tr = topo + (long)g * DD;
    tr[tid]       = a0 * sc;
    tr[tid + 256] = a1 * sc;
    tr[tid + 512] = a2 * sc;
}

extern "C" void kernel_launch(void* const* d_in, const int* in_sizes, int n_in,
                              void* d_out, int out_size, void* d_ws, size_t ws_size,
                              hipStream_t stream)
{
    const float* hs = (const float*)d_in[0];
    const float* Wq = (const float*)d_in[1];
    const float* bq = (const float*)d_in[2];
    const float* Wk = (const float*)d_in[3];
    const float* bk = (const float*)d_in[4];
    const float* Wv = (const float*)d_in[5];
    const float* bv = (const float*)d_in[6];
    const float* W1 = (const float*)d_in[7];
    const float* b1 = (const float*)d_in[8];
    const float* W2 = (const float*)d_in[9];
    const float* b2 = (const float*)d_in[10];
    float* out = (float*)d_out;

    // ---- workspace layout (peak ~211 MB), time-overlaid ----
    char* w = (char*)d_ws;
    const long QKB   = (long)BSR * DD * 4;            // 25165824 B
    const long DISTB = (long)BB * SS * SS * 4;        // 67108864 B
    float* q    = (float*)w;                          // dead after split
    float* k    = (float*)(w + QKB);                  // dead after split
    float* dist = (float*)w;                          // overlays dead q,k
    float* v    = (float*)(w + DISTB);
    float* topo = (float*)(w + DISTB + QKB);
    float* h    = q;                                  // reuses [0,25.2M) after dist dead
    float* qn   = (float*)(w + DISTB + 2 * QKB);
    float* kn   = qn + BSR;
    unsigned short* Ws   = (unsigned short*)(w + DISTB + 2 * QKB + 65536);
    const long WSPLIT = (long)DD * K2;
    unsigned short* Wq_s = Ws;
    unsigned short* Wk_s = Ws + WSPLIT;
    unsigned short* Wv_s = Ws + 2 * WSPLIT;
    unsigned short* W1_s = Ws + 3 * WSPLIT;
    unsigned short* W2_s = Ws + 4 * WSPLIT;
    unsigned short* hs_s = Ws + 5 * WSPLIT;
    unsigned short* q_s  = hs_s;                      // overlays hs_s (dead after projections)
    unsigned short* k_s  = hs_s + (long)BSR * K2;     // fresh region
    unsigned short* topo_s = k_s;                     // overlays k_s (dead after select)
    unsigned short* h_s    = hs_s;                    // overlays q_s (dead after select)

    dim3 blk(256);
    const int convW  = (DD * (DD / 8)) / 256;         // 288 blocks per weight
    const int convHS = (BSR * (DD / 8)) / 256;        // 3072 blocks

    split_f16<2><<<convW, blk, 0, stream>>>(Wq, Wq_s, DD);
    split_f16<2><<<convW, blk, 0, stream>>>(Wk, Wk_s, DD);
    split_f16<2><<<convW, blk, 0, stream>>>(Wv, Wv_s, DD);
    split_f16<2><<<convW, blk, 0, stream>>>(W1, W1_s, DD);
    split_f16<2><<<convW, blk, 0, stream>>>(W2, W2_s, DD);
    split_f16<1><<<convHS, blk, 0, stream>>>(hs, hs_s, DD);

    gemm_mfma<0><<<dim3(DD / 128, BSR / 128, 1), blk, 0, stream>>>(
        hs_s, Wq_s, bq, nullptr, nullptr, q, BSR, DD, K2, 0, 0, 0, 0);
    gemm_mfma<0><<<dim3(DD / 128, BSR / 128, 1), blk, 0, stream>>>(
        hs_s, Wk_s, bk, nullptr, nullptr, k, BSR, DD, K2, 0, 0, 0, 0);
    gemm_mfma<0><<<dim3(DD / 128, BSR / 128, 1), blk, 0, stream>>>(
        hs_s, Wv_s, bv, nullptr, nullptr, v, BSR, DD, K2, 0, 0, 0, 0);

    rownorm<<<(2 * BSR) / 4, blk, 0, stream>>>(q, k, qn, kn);

    split_f16<1><<<convHS, blk, 0, stream>>>(q, q_s, DD);
    split_f16<2><<<convHS, blk, 0, stream>>>(k, k_s, DD);

    gemm_mfma<2><<<dim3(SS / 128, SS / 128, BB), blk, 0, stream>>>(
        q_s, k_s, nullptr, qn, kn, dist, SS, SS, K2,
        (long)SS * K2, (long)SS * K2, (long)SS * SS, SS);

    select_mean<<<BSR, blk, 0, stream>>>(dist, v, q_s, k_s, qn, kn, topo);

    split_f16<1><<<convHS, blk, 0, stream>>>(topo, topo_s, DD);
    gemm_mfma<1><<<dim3(DD / 128, BSR / 128, 1), blk, 0, stream>>>(
        topo_s, W1_s, b1, nullptr, nullptr, h, BSR, DD, K2, 0, 0, 0, 0);
    split_f16<1><<<convHS, blk, 0, stream>>>(h, h_s, DD);
    gemm_mfma<0><<<dim3(DD / 128, BSR / 128, 1), blk, 0, stream>>>(
        h_s, W2_s, b2, nullptr, nullptr, out, BSR, DD, K2, 0, 0, 0, 0);
}

// Round 5
// 559.982 us; speedup vs baseline: 2.2367x; 1.2459x over previous
//
#include <hip/hip_runtime.h>
#include <float.h>

#define DD 768
#define SS 2048
#define BB 4
#define BSR (BB*SS)   // 8192 total rows
#define KNEI 32
#define K2 (3*DD)     // 2304: [hi | x | y] split concat along K
#define MARGIN 5e-4f

typedef __attribute__((ext_vector_type(8))) _Float16 f16x8;
typedef __attribute__((ext_vector_type(4))) float f32x4;
typedef __attribute__((ext_vector_type(8))) unsigned short u16x8;

__device__ __forceinline__ float f16f(unsigned short u) {
    return (float)__builtin_bit_cast(_Float16, u);
}
__device__ __forceinline__ unsigned short ff16(float x) {
    return __builtin_bit_cast(unsigned short, (_Float16)x);
}

__device__ __forceinline__ void gload_lds16(const void* g, void* l) {
    __builtin_amdgcn_global_load_lds(
        (const __attribute__((address_space(1))) unsigned int*)g,
        (__attribute__((address_space(3))) unsigned int*)l, 16, 0, 0);
}

// fp32 -> 3-slot f16 split with power-of-2 rebalanced correction slots.
// A-layout (LO_SLOT=1): [h, l*2^6, h*2^-6];  B-layout (LO_SLOT=2): [h, h*2^-6, l*2^6]
// Paired products: h*h + (l_a*2^6)(h_b*2^-6) + (h_a*2^-6)(l_b*2^6) = h_a h_b + l_a h_b + h_a l_b
template<int LO_SLOT>
__global__ __launch_bounds__(256)
void split_f16(const float* __restrict__ in, unsigned short* __restrict__ out, int Kc)
{
    int idx = blockIdx.x * 256 + threadIdx.x;   // one 8-elem chunk per thread
    int perRow = Kc >> 3;
    int row = idx / perRow, c8 = idx - row * perRow;
    const float* src = in + (long)row * Kc + c8 * 8;
    f32x4 x0 = *(const f32x4*)&src[0];
    f32x4 x1 = *(const f32x4*)&src[4];
    u16x8 hi, lsc, hsc;
    #pragma unroll
    for (int e = 0; e < 8; ++e) {
        float xv = (e < 4) ? x0[e] : x1[e - 4];
        _Float16 h = (_Float16)xv;
        float hf = (float)h;
        float l = xv - hf;
        hi[e]  = __builtin_bit_cast(unsigned short, h);
        lsc[e] = ff16(l * 64.f);
        hsc[e] = ff16(hf * 0.015625f);
    }
    long base = (long)row * (3 * Kc) + c8 * 8;
    *(u16x8*)&out[base] = hi;
    *(u16x8*)&out[base + Kc]     = (LO_SLOT == 1) ? lsc : hsc;
    *(u16x8*)&out[base + 2 * Kc] = (LO_SLOT == 1) ? hsc : lsc;
}

// C[m][n] = epilogue( sum_k A[m][k]*B[n][k] ), A:[M][Kd] f16, B:[N][Kd] f16, NT.
// MODE 0: +bias[n];  MODE 1: relu(+bias[n]);  MODE 2: rm[m]+rn[n]-2*acc
template<int MODE>
__global__ __launch_bounds__(256)
void gemm_mfma(const unsigned short* __restrict__ A, const unsigned short* __restrict__ B,
               const float* __restrict__ bias,
               const float* __restrict__ rm, const float* __restrict__ rn,
               float* __restrict__ C,
               int M, int N, int Kd,
               long sA, long sB, long sC, long sR)
{
    int z = blockIdx.z;
    A += (long)z * sA;
    B += (long)z * sB;
    C += (long)z * sC;
    const float* rmz = (MODE == 2) ? rm + (long)z * sR : nullptr;
    const float* rnz = (MODE == 2) ? rn + (long)z * sR : nullptr;

    __shared__ __align__(16) unsigned short Asm[128 * 64];  // [row][64k], 16B chunks XOR-swizzled
    __shared__ __align__(16) unsigned short Bsm[128 * 64];

    const int tid = threadIdx.x;
    const int lane = tid & 63;
    const int wave = tid >> 6;
    const int wm = wave >> 1, wn = wave & 1;
    const int m0 = blockIdx.y * 128, n0 = blockIdx.x * 128;
    const int r15 = lane & 15;
    const int g4 = lane >> 4;

    f32x4 acc[4][4] = {};

    // staging: linear LDS dest, XOR-swizzled global source chunk (involution matches read)
    long aByte[4], bByte[4];
    int ldsOff[4];
    #pragma unroll
    for (int i = 0; i < 4; ++i) {
        int L = i * 256 + tid;
        int row = L >> 3, ch = L & 7;
        int chs = ch ^ (row & 7);
        aByte[i] = (long)(m0 + row) * Kd * 2 + chs * 16;
        bByte[i] = (long)(n0 + row) * Kd * 2 + chs * 16;
        ldsOff[i] = L * 8;
    }

    for (int k0 = 0; k0 < Kd; k0 += 64) {
        long kb = (long)k0 * 2;
        #pragma unroll
        for (int i = 0; i < 4; ++i)
            gload_lds16((const char*)A + aByte[i] + kb, &Asm[ldsOff[i]]);
        #pragma unroll
        for (int i = 0; i < 4; ++i)
            gload_lds16((const char*)B + bByte[i] + kb, &Bsm[ldsOff[i]]);
        __syncthreads();

        #pragma unroll
        for (int ks = 0; ks < 2; ++ks) {
            f16x8 af[4], bfr[4];
            #pragma unroll
            for (int i = 0; i < 4; ++i) {
                int row = wm * 64 + i * 16 + r15;
                int chs = (ks * 4 + g4) ^ (r15 & 7);
                af[i] = *(const f16x8*)&Asm[row * 64 + chs * 8];
            }
            #pragma unroll
            for (int j = 0; j < 4; ++j) {
                int row = wn * 64 + j * 16 + r15;
                int chs = (ks * 4 + g4) ^ (r15 & 7);
                bfr[j] = *(const f16x8*)&Bsm[row * 64 + chs * 8];
            }
            #pragma unroll
            for (int i = 0; i < 4; ++i)
                #pragma unroll
                for (int j = 0; j < 4; ++j)
                    acc[i][j] = __builtin_amdgcn_mfma_f32_16x16x32_f16(
                        af[i], bfr[j], acc[i][j], 0, 0, 0);
        }
        __syncthreads();
    }

    // epilogue: C/D layout col=lane&15, row=(lane>>4)*4+reg
    float bj[4];
    #pragma unroll
    for (int j = 0; j < 4; ++j) {
        int n = n0 + wn * 64 + j * 16 + r15;
        bj[j] = (MODE == 2) ? rnz[n] : bias[n];
    }
    #pragma unroll
    for (int i = 0; i < 4; ++i) {
        #pragma unroll
        for (int r = 0; r < 4; ++r) {
            int m = m0 + wm * 64 + i * 16 + g4 * 4 + r;
            float rmv = (MODE == 2) ? rmz[m] : 0.f;
            #pragma unroll
            for (int j = 0; j < 4; ++j) {
                int n = n0 + wn * 64 + j * 16 + r15;
                float val = acc[i][j][r];
                if (MODE == 0) val += bj[j];
                if (MODE == 1) { val += bj[j]; val = fmaxf(val, 0.f); }
                if (MODE == 2) val = rmv + bj[j] - 2.f * val;
                C[(long)m * N + n] = val;
            }
        }
    }
}

// row squared-norms of q and k (fp32 sources)
__global__ __launch_bounds__(256)
void rownorm(const float* __restrict__ q, const float* __restrict__ k,
             float* __restrict__ qn, float* __restrict__ kn)
{
    int row  = blockIdx.x * 4 + (threadIdx.x >> 6);
    int lane = threadIdx.x & 63;
    const float* src;
    float* dst;
    if (row < BSR) { src = q + (long)row * DD;         dst = qn + row; }
    else           { src = k + (long)(row - BSR) * DD; dst = kn + (row - BSR); }
    float s = 0.f;
    #pragma unroll
    for (int j = 0; j < DD / 64; ++j) {
        float x = src[lane + j * 64];
        s += x * x;
    }
    #pragma unroll
    for (int off = 32; off; off >>= 1) s += __shfl_down(s, off);
    if (lane == 0) *dst = s;
}

// One WAVE per query row: register-resident distances (32/lane), zero LDS,
// zero barriers. 33 keyed-argmin iterations (key = f32bits<<32 | index: min
// value, lowest-index tie-break = lax.top_k). Boundary-gap guard recomputes
// exact fp32 distances for the window and re-picks. Then gather-mean of v.
// Element j of the row lives at slot s, lane l: j = (s>>2)*256 + l*4 + (s&3)
__global__ __launch_bounds__(256)
void select_mean(const float* __restrict__ dist, const float* __restrict__ v,
                 const unsigned short* __restrict__ q_s, const unsigned short* __restrict__ k_s,
                 const float* __restrict__ qn, const float* __restrict__ kn,
                 float* __restrict__ topo)
{
    const int wv = threadIdx.x >> 6;
    const int lane = threadIdx.x & 63;
    const int g = blockIdx.x * 4 + wv;      // global row 0..8191
    const int b = g >> 11;
    const float* drow = dist + (long)b * SS * SS + (long)(g & (SS - 1)) * SS;
    const float* vb   = v    + (long)b * SS * DD;

    // load 32 values per lane, clamped at 0 like reference's max(sq,0)
    float d[32];
    const f32x4* dr4 = (const f32x4*)drow;
    #pragma unroll
    for (int c = 0; c < 8; ++c) {
        f32x4 tv = dr4[c * 64 + lane];
        #pragma unroll
        for (int i = 0; i < 4; ++i) d[c * 4 + i] = fmaxf(tv[i], 0.f);
    }

    unsigned sel = 0;                       // per-lane bitmask of selected slots
    float d32v = 0.f, d33v = 0.f;

    for (int t = 0; t < 33; ++t) {
        unsigned long long best = ~0ull;
        #pragma unroll
        for (int s = 0; s < 32; ++s) {
            if (!((sel >> s) & 1u)) {
                unsigned long long key =
                    ((unsigned long long)__builtin_bit_cast(unsigned, d[s]) << 32)
                    | (unsigned)((s >> 2) * 256 + lane * 4 + (s & 3));
                best = key < best ? key : best;
            }
        }
        #pragma unroll
        for (int off = 32; off; off >>= 1) {
            unsigned long long o = __shfl_xor(best, off);
            best = o < best ? o : best;
        }
        if (t < 32) {
            int j = (int)(unsigned)best;
            if (lane == ((j >> 2) & 63)) sel |= 1u << (((j >> 8) << 2) | (j & 3));
            if (t == 31) d32v = __builtin_bit_cast(float, (unsigned)(best >> 32));
        } else {
            d33v = __builtin_bit_cast(float, (unsigned)(best >> 32));
        }
    }

    // boundary-gap guard (wave-uniform): exact fp32 recompute for the window
    if (d33v - d32v < MARGIN) {
        float lo = d32v - MARGIN, hi = d33v + MARGIN;
        unsigned cand = 0;
        #pragma unroll
        for (int s = 0; s < 32; ++s)
            if (d[s] >= lo && d[s] <= hi) cand |= 1u << s;

        const unsigned short* qrow = q_s + (long)g * K2;
        #pragma unroll
        for (int s = 0; s < 32; ++s) {
            unsigned long long m = __ballot((cand >> s) & 1u);
            while (m) {
                int l2 = __ffsll(m) - 1;
                m &= m - 1;
                int j = (s >> 2) * 256 + l2 * 4 + (s & 3);
                const unsigned short* krow = k_s + ((long)b * SS + j) * K2;
                float part = 0.f;
                #pragma unroll
                for (int i = 0; i < 12; ++i) {
                    int e = i * 64 + lane;
                    float qv = f16f(qrow[e]) + f16f(qrow[DD + e]) * 0.015625f;      // A: slot1=l*2^6
                    float kv = f16f(krow[e]) + f16f(krow[2 * DD + e]) * 0.015625f;  // B: slot2=l*2^6
                    part = fmaf(qv, kv, part);
                }
                #pragma unroll
                for (int off = 32; off; off >>= 1) part += __shfl_xor(part, off);
                float dd = qn[g] + kn[(long)b * SS + j] - 2.f * part;
                dd = fmaxf(dd, 0.f);
                if (lane == l2) d[s] = dd;    // s compile-time (outer unroll) — stays in regs
            }
        }

        // certain members: selected and strictly below window
        sel &= ~cand;
        int C = 0;
        #pragma unroll
        for (int s = 0; s < 32; ++s) C += (int)__popcll(__ballot((sel >> s) & 1u));
        int need = KNEI - C;
        for (int t = 0; t < need; ++t) {
            unsigned long long best = ~0ull;
            #pragma unroll
            for (int s = 0; s < 32; ++s) {
                if (((cand >> s) & 1u) && !((sel >> s) & 1u)) {
                    unsigned long long key =
                        ((unsigned long long)__builtin_bit_cast(unsigned, d[s]) << 32)
                        | (unsigned)((s >> 2) * 256 + lane * 4 + (s & 3));
                    best = key < best ? key : best;
                }
            }
            #pragma unroll
            for (int off = 32; off; off >>= 1) {
                unsigned long long o = __shfl_xor(best, off);
                best = o < best ? o : best;
            }
            if (best != ~0ull) {
                int j = (int)(unsigned)best;
                if (lane == ((j >> 2) & 63)) sel |= 1u << (((j >> 8) << 2) | (j & 3));
            }
        }
    }

    // gather-mean of v over the selected 32 rows (set membership is what matters)
    f32x4 a0 = {0.f, 0.f, 0.f, 0.f}, a1 = a0, a2 = a0;
    #pragma unroll
    for (int s = 0; s < 32; ++s) {
        unsigned long long m = __ballot((sel >> s) & 1u);
        while (m) {
            int l2 = __ffsll(m) - 1;
            m &= m - 1;
            int j = (s >> 2) * 256 + l2 * 4 + (s & 3);
            const f32x4* vr = (const f32x4*)(vb + (long)j * DD);
            a0 += vr[lane];
            a1 += vr[lane + 64];
            a2 += vr[lane + 128];
        }
    }
    const float sc = 1.0f / 32.0f;
    f32x4* tr = (f32x4*)(topo + (long)g * DD);
    tr[lane]       = a0 * sc;
    tr[lane + 64]  = a1 * sc;
    tr[lane + 128] = a2 * sc;
}

extern "C" void kernel_launch(void* const* d_in, const int* in_sizes, int n_in,
                              void* d_out, int out_size, void* d_ws, size_t ws_size,
                              hipStream_t stream)
{
    const float* hs = (const float*)d_in[0];
    const float* Wq = (const float*)d_in[1];
    const float* bq = (const float*)d_in[2];
    const float* Wk = (const float*)d_in[3];
    const float* bk = (const float*)d_in[4];
    const float* Wv = (const float*)d_in[5];
    const float* bv = (const float*)d_in[6];
    const float* W1 = (const float*)d_in[7];
    const float* b1 = (const float*)d_in[8];
    const float* W2 = (const float*)d_in[9];
    const float* b2 = (const float*)d_in[10];
    float* out = (float*)d_out;

    // ---- workspace layout (peak ~211 MB), time-overlaid ----
    char* w = (char*)d_ws;
    const long QKB   = (long)BSR * DD * 4;            // 25165824 B
    const long DISTB = (long)BB * SS * SS * 4;        // 67108864 B
    float* q    = (float*)w;                          // dead after split
    float* k    = (float*)(w + QKB);                  // dead after split
    float* dist = (float*)w;                          // overlays dead q,k
    float* v    = (float*)(w + DISTB);
    float* topo = (float*)(w + DISTB + QKB);
    float* h    = q;                                  // reuses [0,25.2M) after dist dead
    float* qn   = (float*)(w + DISTB + 2 * QKB);
    float* kn   = qn + BSR;
    unsigned short* Ws   = (unsigned short*)(w + DISTB + 2 * QKB + 65536);
    const long WSPLIT = (long)DD * K2;
    unsigned short* Wq_s = Ws;
    unsigned short* Wk_s = Ws + WSPLIT;
    unsigned short* Wv_s = Ws + 2 * WSPLIT;
    unsigned short* W1_s = Ws + 3 * WSPLIT;
    unsigned short* W2_s = Ws + 4 * WSPLIT;
    unsigned short* hs_s = Ws + 5 * WSPLIT;
    unsigned short* q_s  = hs_s;                      // overlays hs_s (dead after projections)
    unsigned short* k_s  = hs_s + (long)BSR * K2;     // fresh region
    unsigned short* topo_s = k_s;                     // overlays k_s (dead after select)
    unsigned short* h_s    = hs_s;                    // overlays q_s (dead after select)

    dim3 blk(256);
    const int convW  = (DD * (DD / 8)) / 256;         // 288 blocks per weight
    const int convHS = (BSR * (DD / 8)) / 256;        // 3072 blocks

    split_f16<2><<<convW, blk, 0, stream>>>(Wq, Wq_s, DD);
    split_f16<2><<<convW, blk, 0, stream>>>(Wk, Wk_s, DD);
    split_f16<2><<<convW, blk, 0, stream>>>(Wv, Wv_s, DD);
    split_f16<2><<<convW, blk, 0, stream>>>(W1, W1_s, DD);
    split_f16<2><<<convW, blk, 0, stream>>>(W2, W2_s, DD);
    split_f16<1><<<convHS, blk, 0, stream>>>(hs, hs_s, DD);

    gemm_mfma<0><<<dim3(DD / 128, BSR / 128, 1), blk, 0, stream>>>(
        hs_s, Wq_s, bq, nullptr, nullptr, q, BSR, DD, K2, 0, 0, 0, 0);
    gemm_mfma<0><<<dim3(DD / 128, BSR / 128, 1), blk, 0, stream>>>(
        hs_s, Wk_s, bk, nullptr, nullptr, k, BSR, DD, K2, 0, 0, 0, 0);
    gemm_mfma<0><<<dim3(DD / 128, BSR / 128, 1), blk, 0, stream>>>(
        hs_s, Wv_s, bv, nullptr, nullptr, v, BSR, DD, K2, 0, 0, 0, 0);

    rownorm<<<(2 * BSR) / 4, blk, 0, stream>>>(q, k, qn, kn);

    split_f16<1><<<convHS, blk, 0, stream>>>(q, q_s, DD);
    split_f16<2><<<convHS, blk, 0, stream>>>(k, k_s, DD);

    gemm_mfma<2><<<dim3(SS / 128, SS / 128, BB), blk, 0, stream>>>(
        q_s, k_s, nullptr, qn, kn, dist, SS, SS, K2,
        (long)SS * K2, (long)SS * K2, (long)SS * SS, SS);

    select_mean<<<BSR / 4, blk, 0, stream>>>(dist, v, q_s, k_s, qn, kn, topo);

    split_f16<1><<<convHS, blk, 0, stream>>>(topo, topo_s, DD);
    gemm_mfma<1><<<dim3(DD / 128, BSR / 128, 1), blk, 0, stream>>>(
        topo_s, W1_s, b1, nullptr, nullptr, h, BSR, DD, K2, 0, 0, 0, 0);
    split_f16<1><<<convHS, blk, 0, stream>>>(h, h_s, DD);
    gemm_mfma<0><<<dim3(DD / 128, BSR / 128, 1), blk, 0, stream>>>(
        h_s, W2_s, b2, nullptr, nullptr, out, BSR, DD, K2, 0, 0, 0, 0);
}

// Round 6
// 510.712 us; speedup vs baseline: 2.4525x; 1.0965x over previous
//
#include <hip/hip_runtime.h>
#include <float.h>

#define DD 768
#define SS 2048
#define BB 4
#define BSR (BB*SS)   // 8192 total rows
#define KNEI 32
#define K2 (3*DD)     // 2304: [hi | x | y] split concat along K
#define MARGIN 5e-4f

typedef __attribute__((ext_vector_type(8))) _Float16 f16x8;
typedef __attribute__((ext_vector_type(4))) float f32x4;
typedef __attribute__((ext_vector_type(8))) unsigned short u16x8;
typedef __attribute__((ext_vector_type(4))) unsigned short u16x4;

__device__ __forceinline__ float f16f(unsigned short u) {
    return (float)__builtin_bit_cast(_Float16, u);
}
__device__ __forceinline__ unsigned short ff16(float x) {
    return __builtin_bit_cast(unsigned short, (_Float16)x);
}

__device__ __forceinline__ void gload_lds16(const void* g, void* l) {
    __builtin_amdgcn_global_load_lds(
        (const __attribute__((address_space(1))) unsigned int*)g,
        (__attribute__((address_space(3))) unsigned int*)l, 16, 0, 0);
}

// fp32 -> 3-slot f16 split with power-of-2 rebalanced correction slots.
// A-layout (LO_SLOT=1): [h, l*2^6, h*2^-6];  B-layout (LO_SLOT=2): [h, h*2^-6, l*2^6]
// Paired products: h*h + (l_a*2^6)(h_b*2^-6) + (h_a*2^-6)(l_b*2^6) = h_a h_b + l_a h_b + h_a l_b
template<int LO_SLOT>
__global__ __launch_bounds__(256)
void split_f16(const float* __restrict__ in, unsigned short* __restrict__ out, int Kc)
{
    int idx = blockIdx.x * 256 + threadIdx.x;   // one 8-elem chunk per thread
    int perRow = Kc >> 3;
    int row = idx / perRow, c8 = idx - row * perRow;
    const float* src = in + (long)row * Kc + c8 * 8;
    f32x4 x0 = *(const f32x4*)&src[0];
    f32x4 x1 = *(const f32x4*)&src[4];
    u16x8 hi, lsc, hsc;
    #pragma unroll
    for (int e = 0; e < 8; ++e) {
        float xv = (e < 4) ? x0[e] : x1[e - 4];
        _Float16 h = (_Float16)xv;
        float hf = (float)h;
        float l = xv - hf;
        hi[e]  = __builtin_bit_cast(unsigned short, h);
        lsc[e] = ff16(l * 64.f);
        hsc[e] = ff16(hf * 0.015625f);
    }
    long base = (long)row * (3 * Kc) + c8 * 8;
    *(u16x8*)&out[base] = hi;
    *(u16x8*)&out[base + Kc]     = (LO_SLOT == 1) ? lsc : hsc;
    *(u16x8*)&out[base + 2 * Kc] = (LO_SLOT == 1) ? hsc : lsc;
}

// C[m][n] = epilogue( sum_k A[m][k]*B[n][k] ), A:[M][Kd] f16, B:[N][Kd] f16, NT.
// MODE 0: +bias[n];  MODE 1: relu(+bias[n]);  MODE 2: rm[m]+rn[n]-2*acc
template<int MODE>
__global__ __launch_bounds__(256)
void gemm_mfma(const unsigned short* __restrict__ A, const unsigned short* __restrict__ B,
               const float* __restrict__ bias,
               const float* __restrict__ rm, const float* __restrict__ rn,
               float* __restrict__ C,
               int M, int N, int Kd,
               long sA, long sB, long sC, long sR)
{
    int z = blockIdx.z;
    A += (long)z * sA;
    B += (long)z * sB;
    C += (long)z * sC;
    const float* rmz = (MODE == 2) ? rm + (long)z * sR : nullptr;
    const float* rnz = (MODE == 2) ? rn + (long)z * sR : nullptr;

    __shared__ __align__(16) unsigned short Asm[128 * 64];  // [row][64k], 16B chunks XOR-swizzled
    __shared__ __align__(16) unsigned short Bsm[128 * 64];

    const int tid = threadIdx.x;
    const int lane = tid & 63;
    const int wave = tid >> 6;
    const int wm = wave >> 1, wn = wave & 1;
    const int m0 = blockIdx.y * 128, n0 = blockIdx.x * 128;
    const int r15 = lane & 15;
    const int g4 = lane >> 4;

    f32x4 acc[4][4] = {};

    // staging: linear LDS dest, XOR-swizzled global source chunk (involution matches read)
    long aByte[4], bByte[4];
    int ldsOff[4];
    #pragma unroll
    for (int i = 0; i < 4; ++i) {
        int L = i * 256 + tid;
        int row = L >> 3, ch = L & 7;
        int chs = ch ^ (row & 7);
        aByte[i] = (long)(m0 + row) * Kd * 2 + chs * 16;
        bByte[i] = (long)(n0 + row) * Kd * 2 + chs * 16;
        ldsOff[i] = L * 8;
    }

    for (int k0 = 0; k0 < Kd; k0 += 64) {
        long kb = (long)k0 * 2;
        #pragma unroll
        for (int i = 0; i < 4; ++i)
            gload_lds16((const char*)A + aByte[i] + kb, &Asm[ldsOff[i]]);
        #pragma unroll
        for (int i = 0; i < 4; ++i)
            gload_lds16((const char*)B + bByte[i] + kb, &Bsm[ldsOff[i]]);
        __syncthreads();

        #pragma unroll
        for (int ks = 0; ks < 2; ++ks) {
            f16x8 af[4], bfr[4];
            #pragma unroll
            for (int i = 0; i < 4; ++i) {
                int row = wm * 64 + i * 16 + r15;
                int chs = (ks * 4 + g4) ^ (r15 & 7);
                af[i] = *(const f16x8*)&Asm[row * 64 + chs * 8];
            }
            #pragma unroll
            for (int j = 0; j < 4; ++j) {
                int row = wn * 64 + j * 16 + r15;
                int chs = (ks * 4 + g4) ^ (r15 & 7);
                bfr[j] = *(const f16x8*)&Bsm[row * 64 + chs * 8];
            }
            #pragma unroll
            for (int i = 0; i < 4; ++i)
                #pragma unroll
                for (int j = 0; j < 4; ++j)
                    acc[i][j] = __builtin_amdgcn_mfma_f32_16x16x32_f16(
                        af[i], bfr[j], acc[i][j], 0, 0, 0);
        }
        __syncthreads();
    }

    // epilogue: C/D layout col=lane&15, row=(lane>>4)*4+reg
    float bj[4];
    #pragma unroll
    for (int j = 0; j < 4; ++j) {
        int n = n0 + wn * 64 + j * 16 + r15;
        bj[j] = (MODE == 2) ? rnz[n] : bias[n];
    }
    #pragma unroll
    for (int i = 0; i < 4; ++i) {
        #pragma unroll
        for (int r = 0; r < 4; ++r) {
            int m = m0 + wm * 64 + i * 16 + g4 * 4 + r;
            float rmv = (MODE == 2) ? rmz[m] : 0.f;
            #pragma unroll
            for (int j = 0; j < 4; ++j) {
                int n = n0 + wn * 64 + j * 16 + r15;
                float val = acc[i][j][r];
                if (MODE == 0) val += bj[j];
                if (MODE == 1) { val += bj[j]; val = fmaxf(val, 0.f); }
                if (MODE == 2) val = rmv + bj[j] - 2.f * val;
                C[(long)m * N + n] = val;
            }
        }
    }
}

// row squared-norms of q and k (fp32 sources)
__global__ __launch_bounds__(256)
void rownorm(const float* __restrict__ q, const float* __restrict__ k,
             float* __restrict__ qn, float* __restrict__ kn)
{
    int row  = blockIdx.x * 4 + (threadIdx.x >> 6);
    int lane = threadIdx.x & 63;
    const float* src;
    float* dst;
    if (row < BSR) { src = q + (long)row * DD;         dst = qn + row; }
    else           { src = k + (long)(row - BSR) * DD; dst = kn + (row - BSR); }
    float s = 0.f;
    #pragma unroll
    for (int j = 0; j < DD / 64; ++j) {
        float x = src[lane + j * 64];
        s += x * x;
    }
    #pragma unroll
    for (int off = 32; off; off >>= 1) s += __shfl_down(s, off);
    if (lane == 0) *dst = s;
}

// One WAVE per query row, zero LDS, zero barriers.
// Phase 1: each lane extracts its 8 smallest (sorted) as u64 keys (val<<32|j).
// Phase 2: 33 global iterations = 6-step butterfly min over lane heads + O(1)
//          predicated head advance. Exhaustion (lane wins >8) handled exactly
//          by lane-local rescan fallback (expected never).
// Phase 3: boundary-gap guard (exact fp32 recompute) as in round 5.
// Phase 4: gather-mean of v; epilogue writes SPLIT topo (A-layout) directly.
// Element j of the row lives at slot s, lane l: j = (s>>2)*256 + l*4 + (s&3)
// (j strictly increasing in s per lane -> lane-local strict < keeps lowest j)
__global__ __launch_bounds__(256)
void select_mean(const float* __restrict__ dist, const float* __restrict__ v,
                 const unsigned short* __restrict__ q_s, const unsigned short* __restrict__ k_s,
                 const float* __restrict__ qn, const float* __restrict__ kn,
                 unsigned short* __restrict__ topo_s)
{
    const int wv = threadIdx.x >> 6;
    const int lane = threadIdx.x & 63;
    const int g = blockIdx.x * 4 + wv;      // global row 0..8191
    const int b = g >> 11;
    const float* drow = dist + (long)b * SS * SS + (long)(g & (SS - 1)) * SS;
    const float* vb   = v    + (long)b * SS * DD;

    // load 32 values per lane, clamped at 0 like reference's max(sq,0)
    float d[32];
    const f32x4* dr4 = (const f32x4*)drow;
    #pragma unroll
    for (int c = 0; c < 8; ++c) {
        f32x4 tv = dr4[c * 64 + lane];
        #pragma unroll
        for (int i = 0; i < 4; ++i) d[c * 4 + i] = fmaxf(tv[i], 0.f);
    }

    // ---- Phase 1: per-lane 8 smallest, ascending, as sorted u64 keys ----
    unsigned long long h0, h1, h2, h3, h4, h5, h6, h7;
    {
        unsigned lsel = 0;
        unsigned long long hh[8];
        #pragma unroll
        for (int t = 0; t < 8; ++t) {
            float bv = FLT_MAX; int bs = 0;
            #pragma unroll
            for (int s = 0; s < 32; ++s) {
                bool lt = !((lsel >> s) & 1u) && (d[s] < bv);
                bv = lt ? d[s] : bv;
                bs = lt ? s : bs;
            }
            lsel |= 1u << bs;
            hh[t] = ((unsigned long long)__builtin_bit_cast(unsigned, bv) << 32)
                  | (unsigned)((bs >> 2) * 256 + lane * 4 + (bs & 3));
        }
        h0 = hh[0]; h1 = hh[1]; h2 = hh[2]; h3 = hh[3];
        h4 = hh[4]; h5 = hh[5]; h6 = hh[6]; h7 = hh[7];
    }

    // ---- Phase 2: 33 global argmin iterations ----
    unsigned sel = 0;                       // per-lane bitmask of SELECTED slots
    int cnt = 0;                            // heads consumed by this lane
    float d32v = 0.f, d33v = 0.f;

    for (int t = 0; t < 33; ++t) {
        unsigned long long best = h0;
        #pragma unroll
        for (int off = 32; off; off >>= 1) {
            unsigned long long o = __shfl_xor(best, off);
            best = o < best ? o : best;
        }
        if (t == 32) {
            d33v = __builtin_bit_cast(float, (unsigned)(best >> 32));
            break;
        }
        int j = (int)(unsigned)best;
        bool won = (lane == ((j >> 2) & 63));
        if (won) sel |= 1u << (((j >> 8) << 2) | (j & 3));
        if (t == 31) d32v = __builtin_bit_cast(float, (unsigned)(best >> 32));

        if (won) cnt++;
        bool needScan = won && (cnt >= 8);
        bool adv = won && (cnt < 8);
        h0 = adv ? h1 : h0;  h1 = adv ? h2 : h1;  h2 = adv ? h3 : h2;
        h3 = adv ? h4 : h3;  h4 = adv ? h5 : h4;  h5 = adv ? h6 : h5;
        h6 = adv ? h7 : h6;  h7 = adv ? ~0ull : h7;
        if (__any(needScan)) {              // expected never taken
            if (needScan) {
                float bv = FLT_MAX; int bs = 0; bool found = false;
                #pragma unroll
                for (int s = 0; s < 32; ++s) {
                    bool ok = !((sel >> s) & 1u);
                    bool lt = ok && (d[s] < bv);
                    bv = lt ? d[s] : bv; bs = lt ? s : bs; found |= ok;
                }
                h0 = found
                   ? (((unsigned long long)__builtin_bit_cast(unsigned, bv) << 32)
                      | (unsigned)((bs >> 2) * 256 + lane * 4 + (bs & 3)))
                   : ~0ull;
            }
        }
    }

    // ---- Phase 3: boundary-gap guard (exact fp32 recompute for the window) ----
    if (d33v - d32v < MARGIN) {
        float lo = d32v - MARGIN, hi = d33v + MARGIN;
        unsigned cand = 0;
        #pragma unroll
        for (int s = 0; s < 32; ++s)
            if (d[s] >= lo && d[s] <= hi) cand |= 1u << s;

        const unsigned short* qrow = q_s + (long)g * K2;
        #pragma unroll
        for (int s = 0; s < 32; ++s) {
            unsigned long long m = __ballot((cand >> s) & 1u);
            while (m) {
                int l2 = __ffsll(m) - 1;
                m &= m - 1;
                int j = (s >> 2) * 256 + l2 * 4 + (s & 3);
                const unsigned short* krow = k_s + ((long)b * SS + j) * K2;
                float part = 0.f;
                #pragma unroll
                for (int i = 0; i < 12; ++i) {
                    int e = i * 64 + lane;
                    float qv = f16f(qrow[e]) + f16f(qrow[DD + e]) * 0.015625f;      // A: slot1=l*2^6
                    float kv = f16f(krow[e]) + f16f(krow[2 * DD + e]) * 0.015625f;  // B: slot2=l*2^6
                    part = fmaf(qv, kv, part);
                }
                #pragma unroll
                for (int off = 32; off; off >>= 1) part += __shfl_xor(part, off);
                float dd = qn[g] + kn[(long)b * SS + j] - 2.f * part;
                dd = fmaxf(dd, 0.f);
                if (lane == l2) d[s] = dd;    // s compile-time (outer unroll) — stays in regs
            }
        }

        // certain members: selected and strictly below window
        sel &= ~cand;
        int C = 0;
        #pragma unroll
        for (int s = 0; s < 32; ++s) C += (int)__popcll(__ballot((sel >> s) & 1u));
        int need = KNEI - C;
        for (int t = 0; t < need; ++t) {
            unsigned long long best = ~0ull;
            #pragma unroll
            for (int s = 0; s < 32; ++s) {
                if (((cand >> s) & 1u) && !((sel >> s) & 1u)) {
                    unsigned long long key =
                        ((unsigned long long)__builtin_bit_cast(unsigned, d[s]) << 32)
                        | (unsigned)((s >> 2) * 256 + lane * 4 + (s & 3));
                    best = key < best ? key : best;
                }
            }
            #pragma unroll
            for (int off = 32; off; off >>= 1) {
                unsigned long long o = __shfl_xor(best, off);
                best = o < best ? o : best;
            }
            if (best != ~0ull) {
                int j = (int)(unsigned)best;
                if (lane == ((j >> 2) & 63)) sel |= 1u << (((j >> 8) << 2) | (j & 3));
            }
        }
    }

    // ---- Phase 4: gather-mean of v, write split topo (A-layout) directly ----
    f32x4 a0 = {0.f, 0.f, 0.f, 0.f}, a1 = a0, a2 = a0;
    #pragma unroll
    for (int s = 0; s < 32; ++s) {
        unsigned long long m = __ballot((sel >> s) & 1u);
        while (m) {
            int l2 = __ffsll(m) - 1;
            m &= m - 1;
            int j = (s >> 2) * 256 + l2 * 4 + (s & 3);
            const f32x4* vr = (const f32x4*)(vb + (long)j * DD);
            a0 += vr[lane];
            a1 += vr[lane + 64];
            a2 += vr[lane + 128];
        }
    }
    const float sc = 1.0f / 32.0f;
    unsigned short* trow = topo_s + (long)g * K2;
    #pragma unroll
    for (int c = 0; c < 3; ++c) {
        f32x4 x = (c == 0) ? a0 : (c == 1) ? a1 : a2;
        u16x4 hi, ls, hs2;
        #pragma unroll
        for (int e = 0; e < 4; ++e) {
            float xv = x[e] * sc;
            _Float16 hh = (_Float16)xv;
            float hf = (float)hh;
            float l = xv - hf;
            hi[e]  = __builtin_bit_cast(unsigned short, hh);
            ls[e]  = ff16(l * 64.f);
            hs2[e] = ff16(hf * 0.015625f);
        }
        *(u16x4*)&trow[c * 256 + lane * 4]            = hi;
        *(u16x4*)&trow[DD + c * 256 + lane * 4]       = ls;
        *(u16x4*)&trow[2 * DD + c * 256 + lane * 4]   = hs2;
    }
}

extern "C" void kernel_launch(void* const* d_in, const int* in_sizes, int n_in,
                              void* d_out, int out_size, void* d_ws, size_t ws_size,
                              hipStream_t stream)
{
    const float* hs = (const float*)d_in[0];
    const float* Wq = (const float*)d_in[1];
    const float* bq = (const float*)d_in[2];
    const float* Wk = (const float*)d_in[3];
    const float* bk = (const float*)d_in[4];
    const float* Wv = (const float*)d_in[5];
    const float* bv = (const float*)d_in[6];
    const float* W1 = (const float*)d_in[7];
    const float* b1 = (const float*)d_in[8];
    const float* W2 = (const float*)d_in[9];
    const float* b2 = (const float*)d_in[10];
    float* out = (float*)d_out;

    // ---- workspace layout (peak ~212.7 MB), time-overlaid ----
    char* w = (char*)d_ws;
    const long QKB   = (long)BSR * DD * 4;            // 25165824 B
    const long DISTB = (long)BB * SS * SS * 4;        // 67108864 B
    const long SPLB  = (long)BSR * K2 * 2;            // 37748736 B (split activations)
    const long WSPL  = (long)DD * K2;                 // elems per split weight (3538944 B)

    float* q    = (float*)w;                          // dead after split
    float* k    = (float*)(w + QKB);                  // dead after split
    float* dist = (float*)w;                          // overlays dead q,k
    float* v    = (float*)(w + DISTB);
    float* h    = q;                                  // reuses [0,25.2M) after dist dead
    float* qn   = (float*)(w + DISTB + QKB);
    float* kn   = qn + BSR;
    unsigned short* W1_s = (unsigned short*)(w + DISTB + QKB + 65536);
    unsigned short* W2_s = W1_s + WSPL;
    unsigned short* hs_s = W2_s + WSPL;               // [*, +37.7MB)
    unsigned short* q_s  = hs_s;                      // overlays hs_s (dead after projections)
    unsigned short* h_s  = hs_s;                      // overlays q_s (dead after select)
    unsigned short* k_s  = hs_s + SPLB / 2;           // fresh 37.7 MB
    unsigned short* Wq_s = k_s + SPLB / 2;            // QKV weight splits (dead after projections)
    unsigned short* Wk_s = Wq_s + WSPL;
    unsigned short* Wv_s = Wk_s + WSPL;
    unsigned short* topo_s = Wq_s;                    // overlays dead Wq/Wk/Wv_s (+37.7MB)

    dim3 blk(256);
    const int convW  = (DD * (DD / 8)) / 256;         // 288 blocks per weight
    const int convHS = (BSR * (DD / 8)) / 256;        // 3072 blocks

    split_f16<2><<<convW, blk, 0, stream>>>(Wq, Wq_s, DD);
    split_f16<2><<<convW, blk, 0, stream>>>(Wk, Wk_s, DD);
    split_f16<2><<<convW, blk, 0, stream>>>(Wv, Wv_s, DD);
    split_f16<2><<<convW, blk, 0, stream>>>(W1, W1_s, DD);
    split_f16<2><<<convW, blk, 0, stream>>>(W2, W2_s, DD);
    split_f16<1><<<convHS, blk, 0, stream>>>(hs, hs_s, DD);

    gemm_mfma<0><<<dim3(DD / 128, BSR / 128, 1), blk, 0, stream>>>(
        hs_s, Wq_s, bq, nullptr, nullptr, q, BSR, DD, K2, 0, 0, 0, 0);
    gemm_mfma<0><<<dim3(DD / 128, BSR / 128, 1), blk, 0, stream>>>(
        hs_s, Wk_s, bk, nullptr, nullptr, k, BSR, DD, K2, 0, 0, 0, 0);
    gemm_mfma<0><<<dim3(DD / 128, BSR / 128, 1), blk, 0, stream>>>(
        hs_s, Wv_s, bv, nullptr, nullptr, v, BSR, DD, K2, 0, 0, 0, 0);

    rownorm<<<(2 * BSR) / 4, blk, 0, stream>>>(q, k, qn, kn);

    split_f16<1><<<convHS, blk, 0, stream>>>(q, q_s, DD);
    split_f16<2><<<convHS, blk, 0, stream>>>(k, k_s, DD);

    gemm_mfma<2><<<dim3(SS / 128, SS / 128, BB), blk, 0, stream>>>(
        q_s, k_s, nullptr, qn, kn, dist, SS, SS, K2,
        (long)SS * K2, (long)SS * K2, (long)SS * SS, SS);

    select_mean<<<BSR / 4, blk, 0, stream>>>(dist, v, q_s, k_s, qn, kn, topo_s);

    gemm_mfma<1><<<dim3(DD / 128, BSR / 128, 1), blk, 0, stream>>>(
        topo_s, W1_s, b1, nullptr, nullptr, h, BSR, DD, K2, 0, 0, 0, 0);
    split_f16<1><<<convHS, blk, 0, stream>>>(h, h_s, DD);
    gemm_mfma<0><<<dim3(DD / 128, BSR / 128, 1), blk, 0, stream>>>(
        h_s, W2_s, b2, nullptr, nullptr, out, BSR, DD, K2, 0, 0, 0, 0);
}

// Round 7
// 445.274 us; speedup vs baseline: 2.8129x; 1.1470x over previous
//
#include <hip/hip_runtime.h>
#include <float.h>

#define DD 768
#define SS 2048
#define BB 4
#define BSR (BB*SS)   // 8192 total rows
#define KNEI 32
#define K2 (3*DD)     // 2304: [hi | x | y] split concat along K
#define MARGIN 5e-4f

typedef __attribute__((ext_vector_type(8))) _Float16 f16x8;
typedef __attribute__((ext_vector_type(4))) float f32x4;
typedef __attribute__((ext_vector_type(8))) unsigned short u16x8;
typedef __attribute__((ext_vector_type(4))) unsigned short u16x4;

__device__ __forceinline__ float f16f(unsigned short u) {
    return (float)__builtin_bit_cast(_Float16, u);
}
__device__ __forceinline__ unsigned short ff16(float x) {
    return __builtin_bit_cast(unsigned short, (_Float16)x);
}
__device__ __forceinline__ unsigned short rne_bf16(float x) {
    unsigned u = __builtin_bit_cast(unsigned, x);
    unsigned r = u + 0x7FFFu + ((u >> 16) & 1u);
    return (unsigned short)(r >> 16);
}
__device__ __forceinline__ float bf16f(unsigned short h) {
    return __builtin_bit_cast(float, (unsigned)h << 16);
}

__device__ __forceinline__ void gload_lds16(const void* g, void* l) {
    __builtin_amdgcn_global_load_lds(
        (const __attribute__((address_space(1))) unsigned int*)g,
        (__attribute__((address_space(3))) unsigned int*)l, 16, 0, 0);
}

// fp32 -> 3-slot f16 split with power-of-2 rebalanced correction slots.
// A-layout (LO_SLOT=1): [h, l*2^6, h*2^-6];  B-layout (LO_SLOT=2): [h, h*2^-6, l*2^6]
// Paired products: h*h + (l_a*2^6)(h_b*2^-6) + (h_a*2^-6)(l_b*2^6) = h_a h_b + l_a h_b + h_a l_b
template<int LO_SLOT>
__global__ __launch_bounds__(256)
void split_f16(const float* __restrict__ in, unsigned short* __restrict__ out, int Kc)
{
    int idx = blockIdx.x * 256 + threadIdx.x;   // one 8-elem chunk per thread
    int perRow = Kc >> 3;
    int row = idx / perRow, c8 = idx - row * perRow;
    const float* src = in + (long)row * Kc + c8 * 8;
    f32x4 x0 = *(const f32x4*)&src[0];
    f32x4 x1 = *(const f32x4*)&src[4];
    u16x8 hi, lsc, hsc;
    #pragma unroll
    for (int e = 0; e < 8; ++e) {
        float xv = (e < 4) ? x0[e] : x1[e - 4];
        _Float16 h = (_Float16)xv;
        float hf = (float)h;
        float l = xv - hf;
        hi[e]  = __builtin_bit_cast(unsigned short, h);
        lsc[e] = ff16(l * 64.f);
        hsc[e] = ff16(hf * 0.015625f);
    }
    long base = (long)row * (3 * Kc) + c8 * 8;
    *(u16x8*)&out[base] = hi;
    *(u16x8*)&out[base + Kc]     = (LO_SLOT == 1) ? lsc : hsc;
    *(u16x8*)&out[base + 2 * Kc] = (LO_SLOT == 1) ? hsc : lsc;
}

__global__ __launch_bounds__(256)
void concat_bias(const float* __restrict__ bq, const float* __restrict__ bk,
                 const float* __restrict__ bv, float* __restrict__ bqkv)
{
    int i = blockIdx.x * 256 + threadIdx.x;
    if (i < 768) bqkv[i] = bq[i];
    else if (i < 1536) bqkv[i] = bk[i - 768];
    else if (i < 2304) bqkv[i] = bv[i - 1536];
}

// pn rows: qnp[8192][12] then knp[8192][12] contiguous; fixed-order sum.
__global__ __launch_bounds__(256)
void finish_norms(const float* __restrict__ pn, float* __restrict__ qn, float* __restrict__ kn)
{
    int row = blockIdx.x * 256 + threadIdx.x;   // 0..16383
    const float* p = pn + (long)row * 12;
    float s = 0.f;
    #pragma unroll
    for (int c = 0; c < 12; ++c) s += p[c];
    if (row < BSR) qn[row] = s; else kn[row - BSR] = s;
}

// C[m][n] = epilogue( sum_k A[m][k]*B[n][k] ), A:[M][Kd] f16, B:[N][Kd] f16, NT.
// MODE 0: +bias[n] -> f32 C
// MODE 2: rm[m]+rn[n]-2*acc -> f32 C (distance)
// MODE 3: relu(+bias[n]) -> split-A u16 oQ (h_s)
// MODE 4: combined QKV: seg=n0/768: 0 -> split-A oQ + qnp; 1 -> split-B oK + knp; 2 -> bf16 oV
template<int MODE>
__global__ __launch_bounds__(256)
void gemm_mfma(const unsigned short* __restrict__ A, const unsigned short* __restrict__ B,
               const float* __restrict__ bias,
               const float* __restrict__ rm, const float* __restrict__ rn,
               float* __restrict__ C,
               int M, int N, int Kd,
               long sA, long sB, long sC, long sR,
               unsigned short* __restrict__ oQ, unsigned short* __restrict__ oK,
               unsigned short* __restrict__ oV, float* __restrict__ pn)
{
    int z = blockIdx.z;
    A += (long)z * sA;
    B += (long)z * sB;
    C += (long)z * sC;
    const float* rmz = (MODE == 2) ? rm + (long)z * sR : nullptr;
    const float* rnz = (MODE == 2) ? rn + (long)z * sR : nullptr;

    __shared__ __align__(16) unsigned short Asm[128 * 64];  // [row][64k], 16B chunks XOR-swizzled
    __shared__ __align__(16) unsigned short Bsm[128 * 64];

    const int tid = threadIdx.x;
    const int lane = tid & 63;
    const int wave = tid >> 6;
    const int wm = wave >> 1, wn = wave & 1;
    const int m0 = blockIdx.y * 128, n0 = blockIdx.x * 128;
    const int r15 = lane & 15;
    const int g4 = lane >> 4;

    f32x4 acc[4][4] = {};

    // staging: linear LDS dest, XOR-swizzled global source chunk (involution matches read)
    long aByte[4], bByte[4];
    int ldsOff[4];
    #pragma unroll
    for (int i = 0; i < 4; ++i) {
        int L = i * 256 + tid;
        int row = L >> 3, ch = L & 7;
        int chs = ch ^ (row & 7);
        aByte[i] = (long)(m0 + row) * Kd * 2 + chs * 16;
        bByte[i] = (long)(n0 + row) * Kd * 2 + chs * 16;
        ldsOff[i] = L * 8;
    }

    for (int k0 = 0; k0 < Kd; k0 += 64) {
        long kb = (long)k0 * 2;
        #pragma unroll
        for (int i = 0; i < 4; ++i)
            gload_lds16((const char*)A + aByte[i] + kb, &Asm[ldsOff[i]]);
        #pragma unroll
        for (int i = 0; i < 4; ++i)
            gload_lds16((const char*)B + bByte[i] + kb, &Bsm[ldsOff[i]]);
        __syncthreads();

        #pragma unroll
        for (int ks = 0; ks < 2; ++ks) {
            f16x8 af[4], bfr[4];
            #pragma unroll
            for (int i = 0; i < 4; ++i) {
                int row = wm * 64 + i * 16 + r15;
                int chs = (ks * 4 + g4) ^ (r15 & 7);
                af[i] = *(const f16x8*)&Asm[row * 64 + chs * 8];
            }
            #pragma unroll
            for (int j = 0; j < 4; ++j) {
                int row = wn * 64 + j * 16 + r15;
                int chs = (ks * 4 + g4) ^ (r15 & 7);
                bfr[j] = *(const f16x8*)&Bsm[row * 64 + chs * 8];
            }
            #pragma unroll
            for (int i = 0; i < 4; ++i)
                #pragma unroll
                for (int j = 0; j < 4; ++j)
                    acc[i][j] = __builtin_amdgcn_mfma_f32_16x16x32_f16(
                        af[i], bfr[j], acc[i][j], 0, 0, 0);
        }
        __syncthreads();
    }

    // epilogue: C/D layout col=lane&15, row=(lane>>4)*4+reg
    float bj[4];
    #pragma unroll
    for (int j = 0; j < 4; ++j) {
        int n = n0 + wn * 64 + j * 16 + r15;
        bj[j] = (MODE == 2) ? rnz[n] : bias[n];
    }

    if (MODE == 0 || MODE == 2) {
        #pragma unroll
        for (int i = 0; i < 4; ++i) {
            #pragma unroll
            for (int r = 0; r < 4; ++r) {
                int m = m0 + wm * 64 + i * 16 + g4 * 4 + r;
                float rmv = (MODE == 2) ? rmz[m] : 0.f;
                #pragma unroll
                for (int j = 0; j < 4; ++j) {
                    int n = n0 + wn * 64 + j * 16 + r15;
                    float val = acc[i][j][r];
                    if (MODE == 0) val += bj[j];
                    if (MODE == 2) val = rmv + bj[j] - 2.f * val;
                    C[(long)m * N + n] = val;
                }
            }
        }
    }

    if (MODE == 3) {
        #pragma unroll
        for (int i = 0; i < 4; ++i) {
            #pragma unroll
            for (int r = 0; r < 4; ++r) {
                int m = m0 + wm * 64 + i * 16 + g4 * 4 + r;
                #pragma unroll
                for (int j = 0; j < 4; ++j) {
                    int e = n0 + wn * 64 + j * 16 + r15;
                    float xv = fmaxf(acc[i][j][r] + bj[j], 0.f);
                    _Float16 hh = (_Float16)xv;
                    float hf = (float)hh;
                    float l = xv - hf;
                    long base = (long)m * K2 + e;
                    oQ[base]          = __builtin_bit_cast(unsigned short, hh);
                    oQ[base + DD]     = ff16(l * 64.f);
                    oQ[base + 2 * DD] = ff16(hf * 0.015625f);
                }
            }
        }
    }

    if (MODE == 4) {
        const int seg = n0 / 768;                       // block-uniform: 0=q 1=k 2=v
        const int e0 = n0 - seg * 768 + wn * 64;
        const int chunk = (blockIdx.x - seg * 6) * 2 + wn;   // 0..11 within segment
        #pragma unroll
        for (int i = 0; i < 4; ++i) {
            #pragma unroll
            for (int r = 0; r < 4; ++r) {
                int m = m0 + wm * 64 + i * 16 + g4 * 4 + r;
                float vals[4];
                #pragma unroll
                for (int j = 0; j < 4; ++j) vals[j] = acc[i][j][r] + bj[j];
                if (seg == 2) {
                    #pragma unroll
                    for (int j = 0; j < 4; ++j)
                        oV[(long)m * DD + e0 + j * 16 + r15] = rne_bf16(vals[j]);
                } else {
                    unsigned short* os = (seg == 0) ? oQ : oK;
                    #pragma unroll
                    for (int j = 0; j < 4; ++j) {
                        float xv = vals[j];
                        _Float16 hh = (_Float16)xv;
                        float hf = (float)hh;
                        float l = xv - hf;
                        long base = (long)m * K2 + e0 + j * 16 + r15;
                        os[base] = __builtin_bit_cast(unsigned short, hh);
                        os[base + ((seg == 0) ? DD : 2 * DD)] = ff16(l * 64.f);
                        os[base + ((seg == 0) ? 2 * DD : DD)] = ff16(hf * 0.015625f);
                    }
                    float s = vals[0]*vals[0] + vals[1]*vals[1]
                            + vals[2]*vals[2] + vals[3]*vals[3];
                    s += __shfl_xor(s, 1); s += __shfl_xor(s, 2);
                    s += __shfl_xor(s, 4); s += __shfl_xor(s, 8);
                    if (r15 == 0)
                        pn[(seg ? (long)BSR * 12 : 0) + (long)m * 12 + chunk] = s;
                }
            }
        }
    }
}

// One WAVE per query row, zero LDS, zero barriers. (v is bf16 now.)
// Phase 1: per-lane 8 smallest (sorted) as u64 keys (val<<32|j).
// Phase 2: 33 global iterations = butterfly min over lane heads + O(1) advance;
//          lane exhaustion handled exactly by lane-local rescan (expected never).
// Phase 3: boundary-gap guard (exact fp32 recompute from splits).
// Phase 4: gather-mean of v (bf16), write SPLIT topo (A-layout) directly.
// Element j of the row lives at slot s, lane l: j = (s>>2)*256 + l*4 + (s&3)
__global__ __launch_bounds__(256)
void select_mean(const float* __restrict__ dist, const unsigned short* __restrict__ v,
                 const unsigned short* __restrict__ q_s, const unsigned short* __restrict__ k_s,
                 const float* __restrict__ qn, const float* __restrict__ kn,
                 unsigned short* __restrict__ topo_s)
{
    const int wv = threadIdx.x >> 6;
    const int lane = threadIdx.x & 63;
    const int g = blockIdx.x * 4 + wv;      // global row 0..8191
    const int b = g >> 11;
    const float* drow = dist + (long)b * SS * SS + (long)(g & (SS - 1)) * SS;
    const unsigned short* vb = v + (long)b * SS * DD;

    float d[32];
    const f32x4* dr4 = (const f32x4*)drow;
    #pragma unroll
    for (int c = 0; c < 8; ++c) {
        f32x4 tv = dr4[c * 64 + lane];
        #pragma unroll
        for (int i = 0; i < 4; ++i) d[c * 4 + i] = fmaxf(tv[i], 0.f);
    }

    // ---- Phase 1: per-lane 8 smallest, ascending, as sorted u64 keys ----
    unsigned long long h0, h1, h2, h3, h4, h5, h6, h7;
    {
        unsigned lsel = 0;
        unsigned long long hh[8];
        #pragma unroll
        for (int t = 0; t < 8; ++t) {
            float bv = FLT_MAX; int bs = 0;
            #pragma unroll
            for (int s = 0; s < 32; ++s) {
                bool lt = !((lsel >> s) & 1u) && (d[s] < bv);
                bv = lt ? d[s] : bv;
                bs = lt ? s : bs;
            }
            lsel |= 1u << bs;
            hh[t] = ((unsigned long long)__builtin_bit_cast(unsigned, bv) << 32)
                  | (unsigned)((bs >> 2) * 256 + lane * 4 + (bs & 3));
        }
        h0 = hh[0]; h1 = hh[1]; h2 = hh[2]; h3 = hh[3];
        h4 = hh[4]; h5 = hh[5]; h6 = hh[6]; h7 = hh[7];
    }

    // ---- Phase 2: 33 global argmin iterations ----
    unsigned sel = 0;
    int cnt = 0;
    float d32v = 0.f, d33v = 0.f;

    for (int t = 0; t < 33; ++t) {
        unsigned long long best = h0;
        #pragma unroll
        for (int off = 32; off; off >>= 1) {
            unsigned long long o = __shfl_xor(best, off);
            best = o < best ? o : best;
        }
        if (t == 32) {
            d33v = __builtin_bit_cast(float, (unsigned)(best >> 32));
            break;
        }
        int j = (int)(unsigned)best;
        bool won = (lane == ((j >> 2) & 63));
        if (won) sel |= 1u << (((j >> 8) << 2) | (j & 3));
        if (t == 31) d32v = __builtin_bit_cast(float, (unsigned)(best >> 32));

        if (won) cnt++;
        bool needScan = won && (cnt >= 8);
        bool adv = won && (cnt < 8);
        h0 = adv ? h1 : h0;  h1 = adv ? h2 : h1;  h2 = adv ? h3 : h2;
        h3 = adv ? h4 : h3;  h4 = adv ? h5 : h4;  h5 = adv ? h6 : h5;
        h6 = adv ? h7 : h6;  h7 = adv ? ~0ull : h7;
        if (__any(needScan)) {              // expected never taken
            if (needScan) {
                float bv = FLT_MAX; int bs = 0; bool found = false;
                #pragma unroll
                for (int s = 0; s < 32; ++s) {
                    bool ok = !((sel >> s) & 1u);
                    bool lt = ok && (d[s] < bv);
                    bv = lt ? d[s] : bv; bs = lt ? s : bs; found |= ok;
                }
                h0 = found
                   ? (((unsigned long long)__builtin_bit_cast(unsigned, bv) << 32)
                      | (unsigned)((bs >> 2) * 256 + lane * 4 + (bs & 3)))
                   : ~0ull;
            }
        }
    }

    // ---- Phase 3: boundary-gap guard (exact fp32 recompute for the window) ----
    if (d33v - d32v < MARGIN) {
        float lo = d32v - MARGIN, hi = d33v + MARGIN;
        unsigned cand = 0;
        #pragma unroll
        for (int s = 0; s < 32; ++s)
            if (d[s] >= lo && d[s] <= hi) cand |= 1u << s;

        const unsigned short* qrow = q_s + (long)g * K2;
        #pragma unroll
        for (int s = 0; s < 32; ++s) {
            unsigned long long m = __ballot((cand >> s) & 1u);
            while (m) {
                int l2 = __ffsll(m) - 1;
                m &= m - 1;
                int j = (s >> 2) * 256 + l2 * 4 + (s & 3);
                const unsigned short* krow = k_s + ((long)b * SS + j) * K2;
                float part = 0.f;
                #pragma unroll
                for (int i = 0; i < 12; ++i) {
                    int e = i * 64 + lane;
                    float qv = f16f(qrow[e]) + f16f(qrow[DD + e]) * 0.015625f;
                    float kv = f16f(krow[e]) + f16f(krow[2 * DD + e]) * 0.015625f;
                    part = fmaf(qv, kv, part);
                }
                #pragma unroll
                for (int off = 32; off; off >>= 1) part += __shfl_xor(part, off);
                float dd = qn[g] + kn[(long)b * SS + j] - 2.f * part;
                dd = fmaxf(dd, 0.f);
                if (lane == l2) d[s] = dd;
            }
        }

        sel &= ~cand;
        int C = 0;
        #pragma unroll
        for (int s = 0; s < 32; ++s) C += (int)__popcll(__ballot((sel >> s) & 1u));
        int need = KNEI - C;
        for (int t = 0; t < need; ++t) {
            unsigned long long best = ~0ull;
            #pragma unroll
            for (int s = 0; s < 32; ++s) {
                if (((cand >> s) & 1u) && !((sel >> s) & 1u)) {
                    unsigned long long key =
                        ((unsigned long long)__builtin_bit_cast(unsigned, d[s]) << 32)
                        | (unsigned)((s >> 2) * 256 + lane * 4 + (s & 3));
                    best = key < best ? key : best;
                }
            }
            #pragma unroll
            for (int off = 32; off; off >>= 1) {
                unsigned long long o = __shfl_xor(best, off);
                best = o < best ? o : best;
            }
            if (best != ~0ull) {
                int j = (int)(unsigned)best;
                if (lane == ((j >> 2) & 63)) sel |= 1u << (((j >> 8) << 2) | (j & 3));
            }
        }
    }

    // ---- Phase 4: gather-mean of bf16 v, write split topo (A-layout) ----
    f32x4 a0 = {0.f, 0.f, 0.f, 0.f}, a1 = a0, a2 = a0;
    #pragma unroll
    for (int s = 0; s < 32; ++s) {
        unsigned long long m = __ballot((sel >> s) & 1u);
        while (m) {
            int l2 = __ffsll(m) - 1;
            m &= m - 1;
            int j = (s >> 2) * 256 + l2 * 4 + (s & 3);
            const u16x4* vr = (const u16x4*)(vb + (long)j * DD);
            u16x4 r0 = vr[lane], r1 = vr[lane + 64], r2 = vr[lane + 128];
            #pragma unroll
            for (int e = 0; e < 4; ++e) {
                a0[e] += bf16f(r0[e]);
                a1[e] += bf16f(r1[e]);
                a2[e] += bf16f(r2[e]);
            }
        }
    }
    const float sc = 1.0f / 32.0f;
    unsigned short* trow = topo_s + (long)g * K2;
    #pragma unroll
    for (int c = 0; c < 3; ++c) {
        f32x4 x = (c == 0) ? a0 : (c == 1) ? a1 : a2;
        u16x4 hi, ls, hs2;
        #pragma unroll
        for (int e = 0; e < 4; ++e) {
            float xv = x[e] * sc;
            _Float16 hh = (_Float16)xv;
            float hf = (float)hh;
            float l = xv - hf;
            hi[e]  = __builtin_bit_cast(unsigned short, hh);
            ls[e]  = ff16(l * 64.f);
            hs2[e] = ff16(hf * 0.015625f);
        }
        *(u16x4*)&trow[c * 256 + lane * 4]            = hi;
        *(u16x4*)&trow[DD + c * 256 + lane * 4]       = ls;
        *(u16x4*)&trow[2 * DD + c * 256 + lane * 4]   = hs2;
    }
}

extern "C" void kernel_launch(void* const* d_in, const int* in_sizes, int n_in,
                              void* d_out, int out_size, void* d_ws, size_t ws_size,
                              hipStream_t stream)
{
    const float* hs = (const float*)d_in[0];
    const float* Wq = (const float*)d_in[1];
    const float* bq = (const float*)d_in[2];
    const float* Wk = (const float*)d_in[3];
    const float* bk = (const float*)d_in[4];
    const float* Wv = (const float*)d_in[5];
    const float* bv = (const float*)d_in[6];
    const float* W1 = (const float*)d_in[7];
    const float* b1 = (const float*)d_in[8];
    const float* W2 = (const float*)d_in[9];
    const float* b2 = (const float*)d_in[10];
    float* out = (float*)d_out;

    // ---- workspace layout (peak ~204 MB), time-overlaid ----
    char* w = (char*)d_ws;
    const long DISTB = (long)BB * SS * SS * 4;        // 67,108,864
    const long VB    = (long)BSR * DD * 2;            // 12,582,912 (bf16 v)
    const long SPLB  = (long)BSR * K2 * 2;            // 37,748,736
    const long WSPL  = (long)DD * K2;                 // elems per split weight

    float*          dist   = (float*)w;                               // [0, 67.1M)
    unsigned short* h_s    = (unsigned short*)w;                      // overlays dead dist
    unsigned short* v      = (unsigned short*)(w + DISTB);            // bf16 v
    unsigned short* q_s    = (unsigned short*)(w + DISTB + VB);
    unsigned short* k_s    = q_s + SPLB / 2;
    unsigned short* hs_s   = k_s + SPLB / 2;
    unsigned short* topo_s = hs_s;                                    // overlays dead hs_s
    unsigned short* Wqkv_s = hs_s + SPLB / 2;                         // 3 weight splits adjacent
    unsigned short* W1_s   = Wqkv_s;                                  // overlays dead Wqkv after qkv gemm
    unsigned short* W2_s   = Wqkv_s + WSPL;
    char* tail  = (char*)(Wqkv_s + 3 * WSPL);
    float* qn   = (float*)tail;                        // 8192
    float* kn   = qn + BSR;                            // 8192
    float* pn   = kn + BSR;                            // qnp[8192][12] + knp[8192][12]
    float* bqkv = pn + (long)2 * BSR * 12;             // 2304

    dim3 blk(256);
    const int convW  = (DD * (DD / 8)) / 256;          // 288 blocks per weight
    const int convHS = (BSR * (DD / 8)) / 256;         // 3072 blocks

    concat_bias<<<9, blk, 0, stream>>>(bq, bk, bv, bqkv);
    split_f16<2><<<convW, blk, 0, stream>>>(Wq, Wqkv_s, DD);
    split_f16<2><<<convW, blk, 0, stream>>>(Wk, Wqkv_s + WSPL, DD);
    split_f16<2><<<convW, blk, 0, stream>>>(Wv, Wqkv_s + 2 * WSPL, DD);
    split_f16<1><<<convHS, blk, 0, stream>>>(hs, hs_s, DD);

    // fused QKV gemm: q->split-A + norms, k->split-B + norms, v->bf16
    gemm_mfma<4><<<dim3(2304 / 128, BSR / 128, 1), blk, 0, stream>>>(
        hs_s, Wqkv_s, bqkv, nullptr, nullptr, nullptr, BSR, 2304, K2, 0, 0, 0, 0,
        q_s, k_s, v, pn);

    // W1/W2 splits into dead Wqkv region
    split_f16<2><<<convW, blk, 0, stream>>>(W1, W1_s, DD);
    split_f16<2><<<convW, blk, 0, stream>>>(W2, W2_s, DD);
    finish_norms<<<(2 * BSR) / 256, blk, 0, stream>>>(pn, qn, kn);

    // squared distance matrix per batch
    gemm_mfma<2><<<dim3(SS / 128, SS / 128, BB), blk, 0, stream>>>(
        q_s, k_s, nullptr, qn, kn, dist, SS, SS, K2,
        (long)SS * K2, (long)SS * K2, (long)SS * SS, SS,
        nullptr, nullptr, nullptr, nullptr);

    select_mean<<<BSR / 4, blk, 0, stream>>>(dist, v, q_s, k_s, qn, kn, topo_s);

    // MLP: gemm1 writes split-A h_s directly (relu fused)
    gemm_mfma<3><<<dim3(DD / 128, BSR / 128, 1), blk, 0, stream>>>(
        topo_s, W1_s, b1, nullptr, nullptr, nullptr, BSR, DD, K2, 0, 0, 0, 0,
        h_s, nullptr, nullptr, nullptr);
    gemm_mfma<0><<<dim3(DD / 128, BSR / 128, 1), blk, 0, stream>>>(
        h_s, W2_s, b2, nullptr, nullptr, out, BSR, DD, K2, 0, 0, 0, 0,
        nullptr, nullptr, nullptr, nullptr);
}

// Round 8
// 441.993 us; speedup vs baseline: 2.8338x; 1.0074x over previous
//
#include <hip/hip_runtime.h>
#include <float.h>

#define DD 768
#define SS 2048
#define BB 4
#define BSR (BB*SS)   // 8192 total rows
#define KNEI 32
#define K2 (3*DD)     // 2304: [hi | x | y] split concat along K
#define MARGIN 5e-4f

typedef __attribute__((ext_vector_type(8))) _Float16 f16x8;
typedef __attribute__((ext_vector_type(4))) float f32x4;
typedef __attribute__((ext_vector_type(8))) unsigned short u16x8;
typedef __attribute__((ext_vector_type(4))) unsigned short u16x4;

__device__ __forceinline__ float f16f(unsigned short u) {
    return (float)__builtin_bit_cast(_Float16, u);
}
__device__ __forceinline__ unsigned short ff16(float x) {
    return __builtin_bit_cast(unsigned short, (_Float16)x);
}
__device__ __forceinline__ unsigned short rne_bf16(float x) {
    unsigned u = __builtin_bit_cast(unsigned, x);
    unsigned r = u + 0x7FFFu + ((u >> 16) & 1u);
    return (unsigned short)(r >> 16);
}
__device__ __forceinline__ float bf16f(unsigned short h) {
    return __builtin_bit_cast(float, (unsigned)h << 16);
}

__device__ __forceinline__ void gload_lds16(const void* g, void* l) {
    __builtin_amdgcn_global_load_lds(
        (const __attribute__((address_space(1))) unsigned int*)g,
        (__attribute__((address_space(3))) unsigned int*)l, 16, 0, 0);
}

// fp32 -> 3-slot f16 split with power-of-2 rebalanced correction slots.
// A-layout (LO_SLOT=1): [h, l*2^6, h*2^-6];  B-layout (LO_SLOT=2): [h, h*2^-6, l*2^6]
template<int LO_SLOT>
__global__ __launch_bounds__(256)
void split_f16(const float* __restrict__ in, unsigned short* __restrict__ out, int Kc)
{
    int idx = blockIdx.x * 256 + threadIdx.x;
    int perRow = Kc >> 3;
    int row = idx / perRow, c8 = idx - row * perRow;
    const float* src = in + (long)row * Kc + c8 * 8;
    f32x4 x0 = *(const f32x4*)&src[0];
    f32x4 x1 = *(const f32x4*)&src[4];
    u16x8 hi, lsc, hsc;
    #pragma unroll
    for (int e = 0; e < 8; ++e) {
        float xv = (e < 4) ? x0[e] : x1[e - 4];
        _Float16 h = (_Float16)xv;
        float hf = (float)h;
        float l = xv - hf;
        hi[e]  = __builtin_bit_cast(unsigned short, h);
        lsc[e] = ff16(l * 64.f);
        hsc[e] = ff16(hf * 0.015625f);
    }
    long base = (long)row * (3 * Kc) + c8 * 8;
    *(u16x8*)&out[base] = hi;
    *(u16x8*)&out[base + Kc]     = (LO_SLOT == 1) ? lsc : hsc;
    *(u16x8*)&out[base + 2 * Kc] = (LO_SLOT == 1) ? hsc : lsc;
}

__global__ __launch_bounds__(256)
void concat_bias(const float* __restrict__ bq, const float* __restrict__ bk,
                 const float* __restrict__ bv, float* __restrict__ bqkv)
{
    int i = blockIdx.x * 256 + threadIdx.x;
    if (i < 768) bqkv[i] = bq[i];
    else if (i < 1536) bqkv[i] = bk[i - 768];
    else if (i < 2304) bqkv[i] = bv[i - 1536];
}

// pn rows: qnp[8192][12] then knp[8192][12] contiguous; fixed-order sum.
__global__ __launch_bounds__(256)
void finish_norms(const float* __restrict__ pn, float* __restrict__ qn, float* __restrict__ kn)
{
    int row = blockIdx.x * 256 + threadIdx.x;   // 0..16383
    const float* p = pn + (long)row * 12;
    float s = 0.f;
    #pragma unroll
    for (int c = 0; c < 12; ++c) s += p[c];
    if (row < BSR) qn[row] = s; else kn[row - BSR] = s;
}

// C[m][n] = epilogue( sum_k A[m][k]*B[n][k] ), NT, f16 3-term split inputs.
// MODE 0: +bias[n] -> f32 C
// MODE 2: rm[m]+rn[n]-2*acc -> f32 C (distance)
// MODE 3: relu(+bias[n]) -> split-A u16 oQ
// MODE 4: combined QKV: seg 0 -> split-A oQ + qnp; 1 -> split-B oK + knp; 2 -> bf16 oV
template<int MODE>
__global__ __launch_bounds__(256)
void gemm_mfma(const unsigned short* __restrict__ A, const unsigned short* __restrict__ B,
               const float* __restrict__ bias,
               const float* __restrict__ rm, const float* __restrict__ rn,
               float* __restrict__ C,
               int M, int N, int Kd,
               long sA, long sB, long sC, long sR,
               unsigned short* __restrict__ oQ, unsigned short* __restrict__ oK,
               unsigned short* __restrict__ oV, float* __restrict__ pn)
{
    int z = blockIdx.z;
    A += (long)z * sA;
    B += (long)z * sB;
    C += (long)z * sC;
    const float* rmz = (MODE == 2) ? rm + (long)z * sR : nullptr;
    const float* rnz = (MODE == 2) ? rn + (long)z * sR : nullptr;

    // ---- bijective XCD swizzle (T1/m204): panel-sharing blocks -> same XCD L2 ----
    const int nwgx = gridDim.x;
    const int nwg  = nwgx * gridDim.y;           // per-z; all our grids are %8==0
    int lid = blockIdx.y * nwgx + blockIdx.x;
    int qq = nwg >> 3, rr = nwg & 7;
    int xcd = lid & 7, pos = lid >> 3;
    int nlid = (xcd < rr ? xcd * (qq + 1) : rr * (qq + 1) + (xcd - rr) * qq) + pos;
    const int bx = nlid % nwgx;
    const int by = nlid / nwgx;

    __shared__ __align__(16) unsigned short Asm[128 * 64];  // [row][64k], 16B chunks XOR-swizzled
    __shared__ __align__(16) unsigned short Bsm[128 * 64];

    const int tid = threadIdx.x;
    const int lane = tid & 63;
    const int wave = tid >> 6;
    const int wm = wave >> 1, wn = wave & 1;
    const int m0 = by * 128, n0 = bx * 128;
    const int r15 = lane & 15;
    const int g4 = lane >> 4;

    f32x4 acc[4][4] = {};

    long aByte[4], bByte[4];
    int ldsOff[4];
    #pragma unroll
    for (int i = 0; i < 4; ++i) {
        int L = i * 256 + tid;
        int row = L >> 3, ch = L & 7;
        int chs = ch ^ (row & 7);
        aByte[i] = (long)(m0 + row) * Kd * 2 + chs * 16;
        bByte[i] = (long)(n0 + row) * Kd * 2 + chs * 16;
        ldsOff[i] = L * 8;
    }

    for (int k0 = 0; k0 < Kd; k0 += 64) {
        long kb = (long)k0 * 2;
        #pragma unroll
        for (int i = 0; i < 4; ++i)
            gload_lds16((const char*)A + aByte[i] + kb, &Asm[ldsOff[i]]);
        #pragma unroll
        for (int i = 0; i < 4; ++i)
            gload_lds16((const char*)B + bByte[i] + kb, &Bsm[ldsOff[i]]);
        __syncthreads();

        #pragma unroll
        for (int ks = 0; ks < 2; ++ks) {
            f16x8 af[4], bfr[4];
            #pragma unroll
            for (int i = 0; i < 4; ++i) {
                int row = wm * 64 + i * 16 + r15;
                int chs = (ks * 4 + g4) ^ (r15 & 7);
                af[i] = *(const f16x8*)&Asm[row * 64 + chs * 8];
            }
            #pragma unroll
            for (int j = 0; j < 4; ++j) {
                int row = wn * 64 + j * 16 + r15;
                int chs = (ks * 4 + g4) ^ (r15 & 7);
                bfr[j] = *(const f16x8*)&Bsm[row * 64 + chs * 8];
            }
            #pragma unroll
            for (int i = 0; i < 4; ++i)
                #pragma unroll
                for (int j = 0; j < 4; ++j)
                    acc[i][j] = __builtin_amdgcn_mfma_f32_16x16x32_f16(
                        af[i], bfr[j], acc[i][j], 0, 0, 0);
        }
        __syncthreads();
    }

    // epilogue: C/D layout col=lane&15, row=(lane>>4)*4+reg
    float bj[4];
    #pragma unroll
    for (int j = 0; j < 4; ++j) {
        int n = n0 + wn * 64 + j * 16 + r15;
        bj[j] = (MODE == 2) ? rnz[n] : bias[n];
    }

    if (MODE == 0 || MODE == 2) {
        #pragma unroll
        for (int i = 0; i < 4; ++i) {
            #pragma unroll
            for (int r = 0; r < 4; ++r) {
                int m = m0 + wm * 64 + i * 16 + g4 * 4 + r;
                float rmv = (MODE == 2) ? rmz[m] : 0.f;
                #pragma unroll
                for (int j = 0; j < 4; ++j) {
                    int n = n0 + wn * 64 + j * 16 + r15;
                    float val = acc[i][j][r];
                    if (MODE == 0) val += bj[j];
                    if (MODE == 2) val = rmv + bj[j] - 2.f * val;
                    C[(long)m * N + n] = val;
                }
            }
        }
    }

    if (MODE == 3) {
        #pragma unroll
        for (int i = 0; i < 4; ++i) {
            #pragma unroll
            for (int r = 0; r < 4; ++r) {
                int m = m0 + wm * 64 + i * 16 + g4 * 4 + r;
                #pragma unroll
                for (int j = 0; j < 4; ++j) {
                    int e = n0 + wn * 64 + j * 16 + r15;
                    float xv = fmaxf(acc[i][j][r] + bj[j], 0.f);
                    _Float16 hh = (_Float16)xv;
                    float hf = (float)hh;
                    float l = xv - hf;
                    long base = (long)m * K2 + e;
                    oQ[base]          = __builtin_bit_cast(unsigned short, hh);
                    oQ[base + DD]     = ff16(l * 64.f);
                    oQ[base + 2 * DD] = ff16(hf * 0.015625f);
                }
            }
        }
    }

    if (MODE == 4) {
        const int seg = n0 / 768;                       // block-uniform: 0=q 1=k 2=v
        const int e0 = n0 - seg * 768 + wn * 64;
        const int chunk = (bx - seg * 6) * 2 + wn;      // 0..11 within segment
        #pragma unroll
        for (int i = 0; i < 4; ++i) {
            #pragma unroll
            for (int r = 0; r < 4; ++r) {
                int m = m0 + wm * 64 + i * 16 + g4 * 4 + r;
                float vals[4];
                #pragma unroll
                for (int j = 0; j < 4; ++j) vals[j] = acc[i][j][r] + bj[j];
                if (seg == 2) {
                    #pragma unroll
                    for (int j = 0; j < 4; ++j)
                        oV[(long)m * DD + e0 + j * 16 + r15] = rne_bf16(vals[j]);
                } else {
                    unsigned short* os = (seg == 0) ? oQ : oK;
                    #pragma unroll
                    for (int j = 0; j < 4; ++j) {
                        float xv = vals[j];
                        _Float16 hh = (_Float16)xv;
                        float hf = (float)hh;
                        float l = xv - hf;
                        long base = (long)m * K2 + e0 + j * 16 + r15;
                        os[base] = __builtin_bit_cast(unsigned short, hh);
                        os[base + ((seg == 0) ? DD : 2 * DD)] = ff16(l * 64.f);
                        os[base + ((seg == 0) ? 2 * DD : DD)] = ff16(hf * 0.015625f);
                    }
                    float s = vals[0]*vals[0] + vals[1]*vals[1]
                            + vals[2]*vals[2] + vals[3]*vals[3];
                    s += __shfl_xor(s, 1); s += __shfl_xor(s, 2);
                    s += __shfl_xor(s, 4); s += __shfl_xor(s, 8);
                    if (r15 == 0)
                        pn[(seg ? (long)BSR * 12 : 0) + (long)m * 12 + chunk] = s;
                }
            }
        }
    }
}

// One WAVE per query row, zero LDS, zero barriers.
// Phase 1: streaming branchless insertion top-8 per lane (sorted u64 keys).
// Phase 2: 33 global iterations = butterfly min over lane heads + O(1) advance;
//          lane exhaustion handled exactly by lane-local rescan (expected never).
// Phase 3: boundary-gap guard (exact fp32 recompute from splits).
// Phase 4: gather-mean of v (bf16), write SPLIT topo (A-layout) directly.
// Element j of the row lives at slot s, lane l: j = (s>>2)*256 + l*4 + (s&3)
__global__ __launch_bounds__(256)
void select_mean(const float* __restrict__ dist, const unsigned short* __restrict__ v,
                 const unsigned short* __restrict__ q_s, const unsigned short* __restrict__ k_s,
                 const float* __restrict__ qn, const float* __restrict__ kn,
                 unsigned short* __restrict__ topo_s)
{
    const int wv = threadIdx.x >> 6;
    const int lane = threadIdx.x & 63;
    const int g = blockIdx.x * 4 + wv;      // global row 0..8191
    const int b = g >> 11;
    const float* drow = dist + (long)b * SS * SS + (long)(g & (SS - 1)) * SS;
    const unsigned short* vb = v + (long)b * SS * DD;

    float d[32];
    unsigned long long h0 = ~0ull, h1 = ~0ull, h2 = ~0ull, h3 = ~0ull,
                       h4 = ~0ull, h5 = ~0ull, h6 = ~0ull, h7 = ~0ull;
    const f32x4* dr4 = (const f32x4*)drow;
    #pragma unroll
    for (int c = 0; c < 8; ++c) {
        f32x4 tv = dr4[c * 64 + lane];
        #pragma unroll
        for (int i = 0; i < 4; ++i) {
            float x = fmaxf(tv[i], 0.f);
            d[c * 4 + i] = x;
            unsigned long long kk =
                ((unsigned long long)__builtin_bit_cast(unsigned, x) << 32)
                | (unsigned)(c * 256 + lane * 4 + i);
            if (kk < h7) {                  // branchless sorted insert
                bool l6 = kk < h6, l5 = kk < h5, l4 = kk < h4, l3 = kk < h3,
                     l2 = kk < h2, l1 = kk < h1, l0 = kk < h0;
                h7 = l6 ? h6 : kk;
                h6 = l6 ? (l5 ? h5 : kk) : h6;
                h5 = l5 ? (l4 ? h4 : kk) : h5;
                h4 = l4 ? (l3 ? h3 : kk) : h4;
                h3 = l3 ? (l2 ? h2 : kk) : h3;
                h2 = l2 ? (l1 ? h1 : kk) : h2;
                h1 = l1 ? (l0 ? h0 : kk) : h1;
                h0 = l0 ? kk : h0;
            }
        }
    }

    // ---- Phase 2: 33 global argmin iterations ----
    unsigned sel = 0;
    int cnt = 0;
    float d32v = 0.f, d33v = 0.f;

    for (int t = 0; t < 33; ++t) {
        unsigned long long best = h0;
        #pragma unroll
        for (int off = 32; off; off >>= 1) {
            unsigned long long o = __shfl_xor(best, off);
            best = o < best ? o : best;
        }
        if (t == 32) {
            d33v = __builtin_bit_cast(float, (unsigned)(best >> 32));
            break;
        }
        int j = (int)(unsigned)best;
        bool won = (lane == ((j >> 2) & 63));
        if (won) sel |= 1u << (((j >> 8) << 2) | (j & 3));
        if (t == 31) d32v = __builtin_bit_cast(float, (unsigned)(best >> 32));

        if (won) cnt++;
        bool needScan = won && (cnt >= 8);
        bool adv = won && (cnt < 8);
        h0 = adv ? h1 : h0;  h1 = adv ? h2 : h1;  h2 = adv ? h3 : h2;
        h3 = adv ? h4 : h3;  h4 = adv ? h5 : h4;  h5 = adv ? h6 : h5;
        h6 = adv ? h7 : h6;  h7 = adv ? ~0ull : h7;
        if (__any(needScan)) {              // expected never taken
            if (needScan) {
                float bv = FLT_MAX; int bs = 0; bool found = false;
                #pragma unroll
                for (int s = 0; s < 32; ++s) {
                    bool ok = !((sel >> s) & 1u);
                    bool lt = ok && (d[s] < bv);
                    bv = lt ? d[s] : bv; bs = lt ? s : bs; found |= ok;
                }
                h0 = found
                   ? (((unsigned long long)__builtin_bit_cast(unsigned, bv) << 32)
                      | (unsigned)((bs >> 2) * 256 + lane * 4 + (bs & 3)))
                   : ~0ull;
            }
        }
    }

    // ---- Phase 3: boundary-gap guard (exact fp32 recompute for the window) ----
    if (d33v - d32v < MARGIN) {
        float lo = d32v - MARGIN, hi = d33v + MARGIN;
        unsigned cand = 0;
        #pragma unroll
        for (int s = 0; s < 32; ++s)
            if (d[s] >= lo && d[s] <= hi) cand |= 1u << s;

        const unsigned short* qrow = q_s + (long)g * K2;
        #pragma unroll
        for (int s = 0; s < 32; ++s) {
            unsigned long long m = __ballot((cand >> s) & 1u);
            while (m) {
                int l2 = __ffsll(m) - 1;
                m &= m - 1;
                int j = (s >> 2) * 256 + l2 * 4 + (s & 3);
                const unsigned short* krow = k_s + ((long)b * SS + j) * K2;
                float part = 0.f;
                #pragma unroll
                for (int i = 0; i < 12; ++i) {
                    int e = i * 64 + lane;
                    float qv = f16f(qrow[e]) + f16f(qrow[DD + e]) * 0.015625f;
                    float kv = f16f(krow[e]) + f16f(krow[2 * DD + e]) * 0.015625f;
                    part = fmaf(qv, kv, part);
                }
                #pragma unroll
                for (int off = 32; off; off >>= 1) part += __shfl_xor(part, off);
                float dd = qn[g] + kn[(long)b * SS + j] - 2.f * part;
                dd = fmaxf(dd, 0.f);
                if (lane == l2) d[s] = dd;
            }
        }

        sel &= ~cand;
        int C = 0;
        #pragma unroll
        for (int s = 0; s < 32; ++s) C += (int)__popcll(__ballot((sel >> s) & 1u));
        int need = KNEI - C;
        for (int t = 0; t < need; ++t) {
            unsigned long long best = ~0ull;
            #pragma unroll
            for (int s = 0; s < 32; ++s) {
                if (((cand >> s) & 1u) && !((sel >> s) & 1u)) {
                    unsigned long long key =
                        ((unsigned long long)__builtin_bit_cast(unsigned, d[s]) << 32)
                        | (unsigned)((s >> 2) * 256 + lane * 4 + (s & 3));
                    best = key < best ? key : best;
                }
            }
            #pragma unroll
            for (int off = 32; off; off >>= 1) {
                unsigned long long o = __shfl_xor(best, off);
                best = o < best ? o : best;
            }
            if (best != ~0ull) {
                int j = (int)(unsigned)best;
                if (lane == ((j >> 2) & 63)) sel |= 1u << (((j >> 8) << 2) | (j & 3));
            }
        }
    }

    // ---- Phase 4: gather-mean of bf16 v, write split topo (A-layout) ----
    f32x4 a0 = {0.f, 0.f, 0.f, 0.f}, a1 = a0, a2 = a0;
    #pragma unroll
    for (int s = 0; s < 32; ++s) {
        unsigned long long m = __ballot((sel >> s) & 1u);
        while (m) {
            int l2 = __ffsll(m) - 1;
            m &= m - 1;
            int j = (s >> 2) * 256 + l2 * 4 + (s & 3);
            const u16x4* vr = (const u16x4*)(vb + (long)j * DD);
            u16x4 r0 = vr[lane], r1 = vr[lane + 64], r2 = vr[lane + 128];
            #pragma unroll
            for (int e = 0; e < 4; ++e) {
                a0[e] += bf16f(r0[e]);
                a1[e] += bf16f(r1[e]);
                a2[e] += bf16f(r2[e]);
            }
        }
    }
    const float sc = 1.0f / 32.0f;
    unsigned short* trow = topo_s + (long)g * K2;
    #pragma unroll
    for (int c = 0; c < 3; ++c) {
        f32x4 x = (c == 0) ? a0 : (c == 1) ? a1 : a2;
        u16x4 hi, ls, hs2;
        #pragma unroll
        for (int e = 0; e < 4; ++e) {
            float xv = x[e] * sc;
            _Float16 hh = (_Float16)xv;
            float hf = (float)hh;
            float l = xv - hf;
            hi[e]  = __builtin_bit_cast(unsigned short, hh);
            ls[e]  = ff16(l * 64.f);
            hs2[e] = ff16(hf * 0.015625f);
        }
        *(u16x4*)&trow[c * 256 + lane * 4]            = hi;
        *(u16x4*)&trow[DD + c * 256 + lane * 4]       = ls;
        *(u16x4*)&trow[2 * DD + c * 256 + lane * 4]   = hs2;
    }
}

extern "C" void kernel_launch(void* const* d_in, const int* in_sizes, int n_in,
                              void* d_out, int out_size, void* d_ws, size_t ws_size,
                              hipStream_t stream)
{
    const float* hs = (const float*)d_in[0];
    const float* Wq = (const float*)d_in[1];
    const float* bq = (const float*)d_in[2];
    const float* Wk = (const float*)d_in[3];
    const float* bk = (const float*)d_in[4];
    const float* Wv = (const float*)d_in[5];
    const float* bv = (const float*)d_in[6];
    const float* W1 = (const float*)d_in[7];
    const float* b1 = (const float*)d_in[8];
    const float* W2 = (const float*)d_in[9];
    const float* b2 = (const float*)d_in[10];
    float* out = (float*)d_out;

    // ---- workspace layout (peak ~204 MB), time-overlaid ----
    char* w = (char*)d_ws;
    const long DISTB = (long)BB * SS * SS * 4;        // 67,108,864
    const long VB    = (long)BSR * DD * 2;            // 12,582,912 (bf16 v)
    const long SPLB  = (long)BSR * K2 * 2;            // 37,748,736
    const long WSPL  = (long)DD * K2;                 // elems per split weight

    float*          dist   = (float*)w;                               // [0, 67.1M)
    unsigned short* h_s    = (unsigned short*)w;                      // overlays dead dist
    unsigned short* v      = (unsigned short*)(w + DISTB);            // bf16 v
    unsigned short* q_s    = (unsigned short*)(w + DISTB + VB);
    unsigned short* k_s    = q_s + SPLB / 2;
    unsigned short* hs_s   = k_s + SPLB / 2;
    unsigned short* topo_s = hs_s;                                    // overlays dead hs_s
    unsigned short* Wqkv_s = hs_s + SPLB / 2;                         // 3 weight splits adjacent
    unsigned short* W1_s   = Wqkv_s;                                  // overlays dead Wqkv after qkv gemm
    unsigned short* W2_s   = Wqkv_s + WSPL;
    char* tail  = (char*)(Wqkv_s + 3 * WSPL);
    float* qn   = (float*)tail;                        // 8192
    float* kn   = qn + BSR;                            // 8192
    float* pn   = kn + BSR;                            // qnp[8192][12] + knp[8192][12]
    float* bqkv = pn + (long)2 * BSR * 12;             // 2304

    dim3 blk(256);
    const int convW  = (DD * (DD / 8)) / 256;          // 288 blocks per weight
    const int convHS = (BSR * (DD / 8)) / 256;         // 3072 blocks

    concat_bias<<<9, blk, 0, stream>>>(bq, bk, bv, bqkv);
    split_f16<2><<<convW, blk, 0, stream>>>(Wq, Wqkv_s, DD);
    split_f16<2><<<convW, blk, 0, stream>>>(Wk, Wqkv_s + WSPL, DD);
    split_f16<2><<<convW, blk, 0, stream>>>(Wv, Wqkv_s + 2 * WSPL, DD);
    split_f16<1><<<convHS, blk, 0, stream>>>(hs, hs_s, DD);

    // fused QKV gemm: q->split-A + norms, k->split-B + norms, v->bf16
    gemm_mfma<4><<<dim3(2304 / 128, BSR / 128, 1), blk, 0, stream>>>(
        hs_s, Wqkv_s, bqkv, nullptr, nullptr, nullptr, BSR, 2304, K2, 0, 0, 0, 0,
        q_s, k_s, v, pn);

    // W1/W2 splits into dead Wqkv region
    split_f16<2><<<convW, blk, 0, stream>>>(W1, W1_s, DD);
    split_f16<2><<<convW, blk, 0, stream>>>(W2, W2_s, DD);
    finish_norms<<<(2 * BSR) / 256, blk, 0, stream>>>(pn, qn, kn);

    // squared distance matrix per batch
    gemm_mfma<2><<<dim3(SS / 128, SS / 128, BB), blk, 0, stream>>>(
        q_s, k_s, nullptr, qn, kn, dist, SS, SS, K2,
        (long)SS * K2, (long)SS * K2, (long)SS * SS, SS,
        nullptr, nullptr, nullptr, nullptr);

    select_mean<<<BSR / 4, blk, 0, stream>>>(dist, v, q_s, k_s, qn, kn, topo_s);

    // MLP: gemm1 writes split-A h_s directly (relu fused)
    gemm_mfma<3><<<dim3(DD / 128, BSR / 128, 1), blk, 0, stream>>>(
        topo_s, W1_s, b1, nullptr, nullptr, nullptr, BSR, DD, K2, 0, 0, 0, 0,
        h_s, nullptr, nullptr, nullptr);
    gemm_mfma<0><<<dim3(DD / 128, BSR / 128, 1), blk, 0, stream>>>(
        h_s, W2_s, b2, nullptr, nullptr, out, BSR, DD, K2, 0, 0, 0, 0,
        nullptr, nullptr, nullptr, nullptr);
}

// Round 9
// 423.015 us; speedup vs baseline: 2.9609x; 1.0449x over previous
//
#include <hip/hip_runtime.h>
#include <float.h>

#define DD 768
#define SS 2048
#define BB 4
#define BSR (BB*SS)   // 8192 total rows
#define KNEI 32
#define K2 (3*DD)     // 2304: [hi | x | y] split concat along K
#define MARGIN 5e-4f

typedef __attribute__((ext_vector_type(8))) _Float16 f16x8;
typedef __attribute__((ext_vector_type(4))) float f32x4;
typedef __attribute__((ext_vector_type(8))) unsigned short u16x8;
typedef __attribute__((ext_vector_type(4))) unsigned short u16x4;

__device__ __forceinline__ float f16f(unsigned short u) {
    return (float)__builtin_bit_cast(_Float16, u);
}
__device__ __forceinline__ unsigned short ff16(float x) {
    return __builtin_bit_cast(unsigned short, (_Float16)x);
}
__device__ __forceinline__ unsigned short rne_bf16(float x) {
    unsigned u = __builtin_bit_cast(unsigned, x);
    unsigned r = u + 0x7FFFu + ((u >> 16) & 1u);
    return (unsigned short)(r >> 16);
}
__device__ __forceinline__ float bf16f(unsigned short h) {
    return __builtin_bit_cast(float, (unsigned)h << 16);
}

__device__ __forceinline__ void gload_lds16(const void* g, void* l) {
    __builtin_amdgcn_global_load_lds(
        (const __attribute__((address_space(1))) unsigned int*)g,
        (__attribute__((address_space(3))) unsigned int*)l, 16, 0, 0);
}

// fp32 -> 3-slot f16 split with power-of-2 rebalanced correction slots.
// A-layout (LO_SLOT=1): [h, l*2^6, h*2^-6];  B-layout (LO_SLOT=2): [h, h*2^-6, l*2^6]
template<int LO_SLOT>
__global__ __launch_bounds__(256)
void split_f16(const float* __restrict__ in, unsigned short* __restrict__ out, int Kc)
{
    int idx = blockIdx.x * 256 + threadIdx.x;
    int perRow = Kc >> 3;
    int row = idx / perRow, c8 = idx - row * perRow;
    const float* src = in + (long)row * Kc + c8 * 8;
    f32x4 x0 = *(const f32x4*)&src[0];
    f32x4 x1 = *(const f32x4*)&src[4];
    u16x8 hi, lsc, hsc;
    #pragma unroll
    for (int e = 0; e < 8; ++e) {
        float xv = (e < 4) ? x0[e] : x1[e - 4];
        _Float16 h = (_Float16)xv;
        float hf = (float)h;
        float l = xv - hf;
        hi[e]  = __builtin_bit_cast(unsigned short, h);
        lsc[e] = ff16(l * 64.f);
        hsc[e] = ff16(hf * 0.015625f);
    }
    long base = (long)row * (3 * Kc) + c8 * 8;
    *(u16x8*)&out[base] = hi;
    *(u16x8*)&out[base + Kc]     = (LO_SLOT == 1) ? lsc : hsc;
    *(u16x8*)&out[base + 2 * Kc] = (LO_SLOT == 1) ? hsc : lsc;
}

__global__ __launch_bounds__(256)
void concat_bias(const float* __restrict__ bq, const float* __restrict__ bk,
                 const float* __restrict__ bv, float* __restrict__ bqkv)
{
    int i = blockIdx.x * 256 + threadIdx.x;
    if (i < 768) bqkv[i] = bq[i];
    else if (i < 1536) bqkv[i] = bk[i - 768];
    else if (i < 2304) bqkv[i] = bv[i - 1536];
}

// pn rows: qnp[8192][12] then knp[8192][12] contiguous; fixed-order sum.
__global__ __launch_bounds__(256)
void finish_norms(const float* __restrict__ pn, float* __restrict__ qn, float* __restrict__ kn)
{
    int row = blockIdx.x * 256 + threadIdx.x;   // 0..16383
    const float* p = pn + (long)row * 12;
    float s = 0.f;
    #pragma unroll
    for (int c = 0; c < 12; ++c) s += p[c];
    if (row < BSR) qn[row] = s; else kn[row - BSR] = s;
}

// ---------------------------------------------------------------------------
// 256x256-tile pipelined distance GEMM (counted-vmcnt schedule, T3/T4 core).
// C[m][n] = rm[m] + rn[n] - 2 * sum_k A[m][k]*B[n][k], per batch z.
// 8 waves (2M x 4N), per-wave C 128x64 (acc[8][4]). LDS: 2 x 64KB K-tile bufs.
// Per iteration t: issue 8 prefetch loads (tile t+1 -> buf^1), then
// s_waitcnt vmcnt(8) (waits only tile t's loads, issued one full iteration
// earlier), raw s_barrier, compute (24 ds_read_b128 + 64 MFMA), s_barrier.
// Raw barriers avoid __syncthreads' forced vmcnt(0) drain.
// ---------------------------------------------------------------------------
__global__ __launch_bounds__(512)
void gemm256_dist(const unsigned short* __restrict__ A, const unsigned short* __restrict__ B,
                  const float* __restrict__ rm, const float* __restrict__ rn,
                  float* __restrict__ C,
                  int N, int Kd, long sA, long sB, long sC, long sR)
{
    const int z = blockIdx.z;
    A += (long)z * sA;
    B += (long)z * sB;
    C += (long)z * sC;
    const float* rmz = rm + (long)z * sR;
    const float* rnz = rn + (long)z * sR;

    // bijective XCD swizzle over the 64 blocks of this batch (nwg%8==0 -> q=8)
    int lid = blockIdx.y * gridDim.x + blockIdx.x;
    int xcd = lid & 7, pos = lid >> 3;
    int nlid = xcd * 8 + pos;
    const int bx = nlid & 7, by = nlid >> 3;

    __shared__ __align__(16) unsigned short lds[2 * 32768];  // 2 bufs x (A 16384 | B 16384) f16

    const int tid = threadIdx.x;
    const int lane = tid & 63;
    const int wave = tid >> 6;
    const int wm = wave >> 2, wn = wave & 3;   // 2 x 4 wave grid
    const int m0 = by * 256, n0 = bx * 256;
    const int r15 = lane & 15;
    const int g4 = lane >> 4;

    f32x4 acc[8][4] = {};

    // staging addresses: linear LDS dest, involution-swizzled global source chunk
    long aB[4], bB[4];
    int lof[4];
    #pragma unroll
    for (int i = 0; i < 4; ++i) {
        int L = i * 512 + tid;          // 0..2047 chunk id (16B chunks)
        int row = L >> 3, ch = L & 7;
        int chs = ch ^ (row & 7);
        aB[i] = (long)(m0 + row) * Kd * 2 + chs * 16;
        bB[i] = (long)(n0 + row) * Kd * 2 + chs * 16;
        lof[i] = L * 8;                 // f16-elem offset within a 32KB panel
    }

    const int NT = Kd >> 6;             // 36 K-tiles of 64

    // prologue: stage tile 0 into buf 0
    #pragma unroll
    for (int i = 0; i < 4; ++i) {
        gload_lds16((const char*)A + aB[i], &lds[lof[i]]);
        gload_lds16((const char*)B + bB[i], &lds[16384 + lof[i]]);
    }

    int cur = 0;
    for (int t = 0; t < NT; ++t) {
        if (t + 1 < NT) {
            long kb = (long)(t + 1) * 128;   // 64 f16 * 2B per row-chunk step
            int off = (cur ^ 1) * 32768;
            #pragma unroll
            for (int i = 0; i < 4; ++i) {
                gload_lds16((const char*)A + aB[i] + kb, &lds[off + lof[i]]);
                gload_lds16((const char*)B + bB[i] + kb, &lds[off + 16384 + lof[i]]);
            }
            asm volatile("s_waitcnt vmcnt(8)" ::: "memory");  // tile t's 8 loads done
        } else {
            asm volatile("s_waitcnt vmcnt(0)" ::: "memory");  // last tile: drain
        }
        __builtin_amdgcn_s_barrier();
        __builtin_amdgcn_sched_barrier(0);

        const unsigned short* bufA = &lds[cur * 32768];
        const unsigned short* bufB = bufA + 16384;
        #pragma unroll
        for (int ks = 0; ks < 2; ++ks) {
            f16x8 af[8], bfr[4];
            #pragma unroll
            for (int i = 0; i < 8; ++i) {
                int r = wm * 128 + i * 16 + r15;
                int g = ks * 4 + g4;
                af[i] = *(const f16x8*)&bufA[r * 64 + (g ^ (r & 7)) * 8];
            }
            #pragma unroll
            for (int j = 0; j < 4; ++j) {
                int c = wn * 64 + j * 16 + r15;
                int g = ks * 4 + g4;
                bfr[j] = *(const f16x8*)&bufB[c * 64 + (g ^ (c & 7)) * 8];
            }
            #pragma unroll
            for (int i = 0; i < 8; ++i)
                #pragma unroll
                for (int j = 0; j < 4; ++j)
                    acc[i][j] = __builtin_amdgcn_mfma_f32_16x16x32_f16(
                        af[i], bfr[j], acc[i][j], 0, 0, 0);
        }
        __builtin_amdgcn_sched_barrier(0);
        __builtin_amdgcn_s_barrier();
        cur ^= 1;
    }

    // epilogue: C/D layout col=lane&15, row=(lane>>4)*4+reg
    float rnv[4];
    #pragma unroll
    for (int j = 0; j < 4; ++j)
        rnv[j] = rnz[n0 + wn * 64 + j * 16 + r15];
    #pragma unroll
    for (int i = 0; i < 8; ++i) {
        #pragma unroll
        for (int r = 0; r < 4; ++r) {
            int m = m0 + wm * 128 + i * 16 + g4 * 4 + r;
            float rmv = rmz[m];
            #pragma unroll
            for (int j = 0; j < 4; ++j) {
                int n = n0 + wn * 64 + j * 16 + r15;
                C[(long)m * N + n] = rmv + rnv[j] - 2.f * acc[i][j][r];
            }
        }
    }
}

// C[m][n] = epilogue( sum_k A[m][k]*B[n][k] ), NT, f16 3-term split inputs.
// MODE 0: +bias[n] -> f32 C
// MODE 3: relu(+bias[n]) -> split-A u16 oQ
// MODE 4: combined QKV: seg 0 -> split-A oQ + qnp; 1 -> split-B oK + knp; 2 -> bf16 oV
template<int MODE>
__global__ __launch_bounds__(256)
void gemm_mfma(const unsigned short* __restrict__ A, const unsigned short* __restrict__ B,
               const float* __restrict__ bias,
               float* __restrict__ C,
               int M, int N, int Kd,
               unsigned short* __restrict__ oQ, unsigned short* __restrict__ oK,
               unsigned short* __restrict__ oV, float* __restrict__ pn)
{
    // ---- bijective XCD swizzle (T1/m204) ----
    const int nwgx = gridDim.x;
    const int nwg  = nwgx * gridDim.y;
    int lid = blockIdx.y * nwgx + blockIdx.x;
    int qq = nwg >> 3, rr = nwg & 7;
    int xcd = lid & 7, pos = lid >> 3;
    int nlid = (xcd < rr ? xcd * (qq + 1) : rr * (qq + 1) + (xcd - rr) * qq) + pos;
    const int bx = nlid % nwgx;
    const int by = nlid / nwgx;

    __shared__ __align__(16) unsigned short Asm[128 * 64];
    __shared__ __align__(16) unsigned short Bsm[128 * 64];

    const int tid = threadIdx.x;
    const int lane = tid & 63;
    const int wave = tid >> 6;
    const int wm = wave >> 1, wn = wave & 1;
    const int m0 = by * 128, n0 = bx * 128;
    const int r15 = lane & 15;
    const int g4 = lane >> 4;

    f32x4 acc[4][4] = {};

    long aByte[4], bByte[4];
    int ldsOff[4];
    #pragma unroll
    for (int i = 0; i < 4; ++i) {
        int L = i * 256 + tid;
        int row = L >> 3, ch = L & 7;
        int chs = ch ^ (row & 7);
        aByte[i] = (long)(m0 + row) * Kd * 2 + chs * 16;
        bByte[i] = (long)(n0 + row) * Kd * 2 + chs * 16;
        ldsOff[i] = L * 8;
    }

    for (int k0 = 0; k0 < Kd; k0 += 64) {
        long kb = (long)k0 * 2;
        #pragma unroll
        for (int i = 0; i < 4; ++i)
            gload_lds16((const char*)A + aByte[i] + kb, &Asm[ldsOff[i]]);
        #pragma unroll
        for (int i = 0; i < 4; ++i)
            gload_lds16((const char*)B + bByte[i] + kb, &Bsm[ldsOff[i]]);
        __syncthreads();

        #pragma unroll
        for (int ks = 0; ks < 2; ++ks) {
            f16x8 af[4], bfr[4];
            #pragma unroll
            for (int i = 0; i < 4; ++i) {
                int row = wm * 64 + i * 16 + r15;
                int chs = (ks * 4 + g4) ^ (r15 & 7);
                af[i] = *(const f16x8*)&Asm[row * 64 + chs * 8];
            }
            #pragma unroll
            for (int j = 0; j < 4; ++j) {
                int row = wn * 64 + j * 16 + r15;
                int chs = (ks * 4 + g4) ^ (r15 & 7);
                bfr[j] = *(const f16x8*)&Bsm[row * 64 + chs * 8];
            }
            #pragma unroll
            for (int i = 0; i < 4; ++i)
                #pragma unroll
                for (int j = 0; j < 4; ++j)
                    acc[i][j] = __builtin_amdgcn_mfma_f32_16x16x32_f16(
                        af[i], bfr[j], acc[i][j], 0, 0, 0);
        }
        __syncthreads();
    }

    float bj[4];
    #pragma unroll
    for (int j = 0; j < 4; ++j) {
        int n = n0 + wn * 64 + j * 16 + r15;
        bj[j] = bias[n];
    }

    if (MODE == 0) {
        #pragma unroll
        for (int i = 0; i < 4; ++i) {
            #pragma unroll
            for (int r = 0; r < 4; ++r) {
                int m = m0 + wm * 64 + i * 16 + g4 * 4 + r;
                #pragma unroll
                for (int j = 0; j < 4; ++j) {
                    int n = n0 + wn * 64 + j * 16 + r15;
                    C[(long)m * N + n] = acc[i][j][r] + bj[j];
                }
            }
        }
    }

    if (MODE == 3) {
        #pragma unroll
        for (int i = 0; i < 4; ++i) {
            #pragma unroll
            for (int r = 0; r < 4; ++r) {
                int m = m0 + wm * 64 + i * 16 + g4 * 4 + r;
                #pragma unroll
                for (int j = 0; j < 4; ++j) {
                    int e = n0 + wn * 64 + j * 16 + r15;
                    float xv = fmaxf(acc[i][j][r] + bj[j], 0.f);
                    _Float16 hh = (_Float16)xv;
                    float hf = (float)hh;
                    float l = xv - hf;
                    long base = (long)m * K2 + e;
                    oQ[base]          = __builtin_bit_cast(unsigned short, hh);
                    oQ[base + DD]     = ff16(l * 64.f);
                    oQ[base + 2 * DD] = ff16(hf * 0.015625f);
                }
            }
        }
    }

    if (MODE == 4) {
        const int seg = n0 / 768;                       // block-uniform: 0=q 1=k 2=v
        const int e0 = n0 - seg * 768 + wn * 64;
        const int chunk = (bx - seg * 6) * 2 + wn;      // 0..11 within segment
        #pragma unroll
        for (int i = 0; i < 4; ++i) {
            #pragma unroll
            for (int r = 0; r < 4; ++r) {
                int m = m0 + wm * 64 + i * 16 + g4 * 4 + r;
                float vals[4];
                #pragma unroll
                for (int j = 0; j < 4; ++j) vals[j] = acc[i][j][r] + bj[j];
                if (seg == 2) {
                    #pragma unroll
                    for (int j = 0; j < 4; ++j)
                        oV[(long)m * DD + e0 + j * 16 + r15] = rne_bf16(vals[j]);
                } else {
                    unsigned short* os = (seg == 0) ? oQ : oK;
                    #pragma unroll
                    for (int j = 0; j < 4; ++j) {
                        float xv = vals[j];
                        _Float16 hh = (_Float16)xv;
                        float hf = (float)hh;
                        float l = xv - hf;
                        long base = (long)m * K2 + e0 + j * 16 + r15;
                        os[base] = __builtin_bit_cast(unsigned short, hh);
                        os[base + ((seg == 0) ? DD : 2 * DD)] = ff16(l * 64.f);
                        os[base + ((seg == 0) ? 2 * DD : DD)] = ff16(hf * 0.015625f);
                    }
                    float s = vals[0]*vals[0] + vals[1]*vals[1]
                            + vals[2]*vals[2] + vals[3]*vals[3];
                    s += __shfl_xor(s, 1); s += __shfl_xor(s, 2);
                    s += __shfl_xor(s, 4); s += __shfl_xor(s, 8);
                    if (r15 == 0)
                        pn[(seg ? (long)BSR * 12 : 0) + (long)m * 12 + chunk] = s;
                }
            }
        }
    }
}

// One WAVE per query row, zero LDS, zero barriers.
__global__ __launch_bounds__(256)
void select_mean(const float* __restrict__ dist, const unsigned short* __restrict__ v,
                 const unsigned short* __restrict__ q_s, const unsigned short* __restrict__ k_s,
                 const float* __restrict__ qn, const float* __restrict__ kn,
                 unsigned short* __restrict__ topo_s)
{
    const int wv = threadIdx.x >> 6;
    const int lane = threadIdx.x & 63;
    const int g = blockIdx.x * 4 + wv;      // global row 0..8191
    const int b = g >> 11;
    const float* drow = dist + (long)b * SS * SS + (long)(g & (SS - 1)) * SS;
    const unsigned short* vb = v + (long)b * SS * DD;

    float d[32];
    unsigned long long h0 = ~0ull, h1 = ~0ull, h2 = ~0ull, h3 = ~0ull,
                       h4 = ~0ull, h5 = ~0ull, h6 = ~0ull, h7 = ~0ull;
    const f32x4* dr4 = (const f32x4*)drow;
    #pragma unroll
    for (int c = 0; c < 8; ++c) {
        f32x4 tv = dr4[c * 64 + lane];
        #pragma unroll
        for (int i = 0; i < 4; ++i) {
            float x = fmaxf(tv[i], 0.f);
            d[c * 4 + i] = x;
            unsigned long long kk =
                ((unsigned long long)__builtin_bit_cast(unsigned, x) << 32)
                | (unsigned)(c * 256 + lane * 4 + i);
            if (kk < h7) {                  // branchless sorted insert
                bool l6 = kk < h6, l5 = kk < h5, l4 = kk < h4, l3 = kk < h3,
                     l2 = kk < h2, l1 = kk < h1, l0 = kk < h0;
                h7 = l6 ? h6 : kk;
                h6 = l6 ? (l5 ? h5 : kk) : h6;
                h5 = l5 ? (l4 ? h4 : kk) : h5;
                h4 = l4 ? (l3 ? h3 : kk) : h4;
                h3 = l3 ? (l2 ? h2 : kk) : h3;
                h2 = l2 ? (l1 ? h1 : kk) : h2;
                h1 = l1 ? (l0 ? h0 : kk) : h1;
                h0 = l0 ? kk : h0;
            }
        }
    }

    // ---- Phase 2: 33 global argmin iterations ----
    unsigned sel = 0;
    int cnt = 0;
    float d32v = 0.f, d33v = 0.f;

    for (int t = 0; t < 33; ++t) {
        unsigned long long best = h0;
        #pragma unroll
        for (int off = 32; off; off >>= 1) {
            unsigned long long o = __shfl_xor(best, off);
            best = o < best ? o : best;
        }
        if (t == 32) {
            d33v = __builtin_bit_cast(float, (unsigned)(best >> 32));
            break;
        }
        int j = (int)(unsigned)best;
        bool won = (lane == ((j >> 2) & 63));
        if (won) sel |= 1u << (((j >> 8) << 2) | (j & 3));
        if (t == 31) d32v = __builtin_bit_cast(float, (unsigned)(best >> 32));

        if (won) cnt++;
        bool needScan = won && (cnt >= 8);
        bool adv = won && (cnt < 8);
        h0 = adv ? h1 : h0;  h1 = adv ? h2 : h1;  h2 = adv ? h3 : h2;
        h3 = adv ? h4 : h3;  h4 = adv ? h5 : h4;  h5 = adv ? h6 : h5;
        h6 = adv ? h7 : h6;  h7 = adv ? ~0ull : h7;
        if (__any(needScan)) {              // expected never taken
            if (needScan) {
                float bv = FLT_MAX; int bs = 0; bool found = false;
                #pragma unroll
                for (int s = 0; s < 32; ++s) {
                    bool ok = !((sel >> s) & 1u);
                    bool lt = ok && (d[s] < bv);
                    bv = lt ? d[s] : bv; bs = lt ? s : bs; found |= ok;
                }
                h0 = found
                   ? (((unsigned long long)__builtin_bit_cast(unsigned, bv) << 32)
                      | (unsigned)((bs >> 2) * 256 + lane * 4 + (bs & 3)))
                   : ~0ull;
            }
        }
    }

    // ---- Phase 3: boundary-gap guard (exact fp32 recompute for the window) ----
    if (d33v - d32v < MARGIN) {
        float lo = d32v - MARGIN, hi = d33v + MARGIN;
        unsigned cand = 0;
        #pragma unroll
        for (int s = 0; s < 32; ++s)
            if (d[s] >= lo && d[s] <= hi) cand |= 1u << s;

        const unsigned short* qrow = q_s + (long)g * K2;
        #pragma unroll
        for (int s = 0; s < 32; ++s) {
            unsigned long long m = __ballot((cand >> s) & 1u);
            while (m) {
                int l2 = __ffsll(m) - 1;
                m &= m - 1;
                int j = (s >> 2) * 256 + l2 * 4 + (s & 3);
                const unsigned short* krow = k_s + ((long)b * SS + j) * K2;
                float part = 0.f;
                #pragma unroll
                for (int i = 0; i < 12; ++i) {
                    int e = i * 64 + lane;
                    float qv = f16f(qrow[e]) + f16f(qrow[DD + e]) * 0.015625f;
                    float kv = f16f(krow[e]) + f16f(krow[2 * DD + e]) * 0.015625f;
                    part = fmaf(qv, kv, part);
                }
                #pragma unroll
                for (int off = 32; off; off >>= 1) part += __shfl_xor(part, off);
                float dd = qn[g] + kn[(long)b * SS + j] - 2.f * part;
                dd = fmaxf(dd, 0.f);
                if (lane == l2) d[s] = dd;
            }
        }

        sel &= ~cand;
        int C = 0;
        #pragma unroll
        for (int s = 0; s < 32; ++s) C += (int)__popcll(__ballot((sel >> s) & 1u));
        int need = KNEI - C;
        for (int t = 0; t < need; ++t) {
            unsigned long long best = ~0ull;
            #pragma unroll
            for (int s = 0; s < 32; ++s) {
                if (((cand >> s) & 1u) && !((sel >> s) & 1u)) {
                    unsigned long long key =
                        ((unsigned long long)__builtin_bit_cast(unsigned, d[s]) << 32)
                        | (unsigned)((s >> 2) * 256 + lane * 4 + (s & 3));
                    best = key < best ? key : best;
                }
            }
            #pragma unroll
            for (int off = 32; off; off >>= 1) {
                unsigned long long o = __shfl_xor(best, off);
                best = o < best ? o : best;
            }
            if (best != ~0ull) {
                int j = (int)(unsigned)best;
                if (lane == ((j >> 2) & 63)) sel |= 1u << (((j >> 8) << 2) | (j & 3));
            }
        }
    }

    // ---- Phase 4: gather-mean of bf16 v, write split topo (A-layout) ----
    f32x4 a0 = {0.f, 0.f, 0.f, 0.f}, a1 = a0, a2 = a0;
    #pragma unroll
    for (int s = 0; s < 32; ++s) {
        unsigned long long m = __ballot((sel >> s) & 1u);
        while (m) {
            int l2 = __ffsll(m) - 1;
            m &= m - 1;
            int j = (s >> 2) * 256 + l2 * 4 + (s & 3);
            const u16x4* vr = (const u16x4*)(vb + (long)j * DD);
            u16x4 r0 = vr[lane], r1 = vr[lane + 64], r2 = vr[lane + 128];
            #pragma unroll
            for (int e = 0; e < 4; ++e) {
                a0[e] += bf16f(r0[e]);
                a1[e] += bf16f(r1[e]);
                a2[e] += bf16f(r2[e]);
            }
        }
    }
    const float sc = 1.0f / 32.0f;
    unsigned short* trow = topo_s + (long)g * K2;
    #pragma unroll
    for (int c = 0; c < 3; ++c) {
        f32x4 x = (c == 0) ? a0 : (c == 1) ? a1 : a2;
        u16x4 hi, ls, hs2;
        #pragma unroll
        for (int e = 0; e < 4; ++e) {
            float xv = x[e] * sc;
            _Float16 hh = (_Float16)xv;
            float hf = (float)hh;
            float l = xv - hf;
            hi[e]  = __builtin_bit_cast(unsigned short, hh);
            ls[e]  = ff16(l * 64.f);
            hs2[e] = ff16(hf * 0.015625f);
        }
        *(u16x4*)&trow[c * 256 + lane * 4]            = hi;
        *(u16x4*)&trow[DD + c * 256 + lane * 4]       = ls;
        *(u16x4*)&trow[2 * DD + c * 256 + lane * 4]   = hs2;
    }
}

extern "C" void kernel_launch(void* const* d_in, const int* in_sizes, int n_in,
                              void* d_out, int out_size, void* d_ws, size_t ws_size,
                              hipStream_t stream)
{
    const float* hs = (const float*)d_in[0];
    const float* Wq = (const float*)d_in[1];
    const float* bq = (const float*)d_in[2];
    const float* Wk = (const float*)d_in[3];
    const float* bk = (const float*)d_in[4];
    const float* Wv = (const float*)d_in[5];
    const float* bv = (const float*)d_in[6];
    const float* W1 = (const float*)d_in[7];
    const float* b1 = (const float*)d_in[8];
    const float* W2 = (const float*)d_in[9];
    const float* b2 = (const float*)d_in[10];
    float* out = (float*)d_out;

    // ---- workspace layout (peak ~204 MB), time-overlaid ----
    char* w = (char*)d_ws;
    const long DISTB = (long)BB * SS * SS * 4;        // 67,108,864
    const long VB    = (long)BSR * DD * 2;            // 12,582,912 (bf16 v)
    const long SPLB  = (long)BSR * K2 * 2;            // 37,748,736
    const long WSPL  = (long)DD * K2;                 // elems per split weight

    float*          dist   = (float*)w;                               // [0, 67.1M)
    unsigned short* h_s    = (unsigned short*)w;                      // overlays dead dist
    unsigned short* v      = (unsigned short*)(w + DISTB);            // bf16 v
    unsigned short* q_s    = (unsigned short*)(w + DISTB + VB);
    unsigned short* k_s    = q_s + SPLB / 2;
    unsigned short* hs_s   = k_s + SPLB / 2;
    unsigned short* topo_s = hs_s;                                    // overlays dead hs_s
    unsigned short* Wqkv_s = hs_s + SPLB / 2;                         // 3 weight splits adjacent
    unsigned short* W1_s   = Wqkv_s;                                  // overlays dead Wqkv after qkv gemm
    unsigned short* W2_s   = Wqkv_s + WSPL;
    char* tail  = (char*)(Wqkv_s + 3 * WSPL);
    float* qn   = (float*)tail;                        // 8192
    float* kn   = qn + BSR;                            // 8192
    float* pn   = kn + BSR;                            // qnp[8192][12] + knp[8192][12]
    float* bqkv = pn + (long)2 * BSR * 12;             // 2304

    dim3 blk(256);
    const int convW  = (DD * (DD / 8)) / 256;          // 288 blocks per weight
    const int convHS = (BSR * (DD / 8)) / 256;         // 3072 blocks

    concat_bias<<<9, blk, 0, stream>>>(bq, bk, bv, bqkv);
    split_f16<2><<<convW, blk, 0, stream>>>(Wq, Wqkv_s, DD);
    split_f16<2><<<convW, blk, 0, stream>>>(Wk, Wqkv_s + WSPL, DD);
    split_f16<2><<<convW, blk, 0, stream>>>(Wv, Wqkv_s + 2 * WSPL, DD);
    split_f16<1><<<convHS, blk, 0, stream>>>(hs, hs_s, DD);

    // fused QKV gemm: q->split-A + norms, k->split-B + norms, v->bf16
    gemm_mfma<4><<<dim3(2304 / 128, BSR / 128, 1), blk, 0, stream>>>(
        hs_s, Wqkv_s, bqkv, nullptr, BSR, 2304, K2,
        q_s, k_s, v, pn);

    // W1/W2 splits into dead Wqkv region
    split_f16<2><<<convW, blk, 0, stream>>>(W1, W1_s, DD);
    split_f16<2><<<convW, blk, 0, stream>>>(W2, W2_s, DD);
    finish_norms<<<(2 * BSR) / 256, blk, 0, stream>>>(pn, qn, kn);

    // squared distance matrix per batch: 256^2-tile pipelined schedule
    gemm256_dist<<<dim3(SS / 256, SS / 256, BB), dim3(512), 0, stream>>>(
        q_s, k_s, qn, kn, dist, SS, K2,
        (long)SS * K2, (long)SS * K2, (long)SS * SS, SS);

    select_mean<<<BSR / 4, blk, 0, stream>>>(dist, v, q_s, k_s, qn, kn, topo_s);

    // MLP: gemm1 writes split-A h_s directly (relu fused)
    gemm_mfma<3><<<dim3(DD / 128, BSR / 128, 1), blk, 0, stream>>>(
        topo_s, W1_s, b1, nullptr, BSR, DD, K2,
        h_s, nullptr, nullptr, nullptr);
    gemm_mfma<0><<<dim3(DD / 128, BSR / 128, 1), blk, 0, stream>>>(
        h_s, W2_s, b2, out, BSR, DD, K2,
        nullptr, nullptr, nullptr, nullptr);
}

// Round 10
// 383.889 us; speedup vs baseline: 3.2627x; 1.1019x over previous
//
#include <hip/hip_runtime.h>
#include <float.h>

#define DD 768
#define SS 2048
#define BB 4
#define BSR (BB*SS)   // 8192 total rows
#define KNEI 32
#define K2 (3*DD)     // 2304: [hi | x | y] split concat along K
#define MARGIN 0.25f  // covers single-term f16 dist error (sigma ~2e-2, >=8 sigma)

typedef __attribute__((ext_vector_type(8))) _Float16 f16x8;
typedef __attribute__((ext_vector_type(4))) float f32x4;
typedef __attribute__((ext_vector_type(8))) unsigned short u16x8;
typedef __attribute__((ext_vector_type(4))) unsigned short u16x4;

__device__ __forceinline__ float f16f(unsigned short u) {
    return (float)__builtin_bit_cast(_Float16, u);
}
__device__ __forceinline__ unsigned short ff16(float x) {
    return __builtin_bit_cast(unsigned short, (_Float16)x);
}
__device__ __forceinline__ unsigned short rne_bf16(float x) {
    unsigned u = __builtin_bit_cast(unsigned, x);
    unsigned r = u + 0x7FFFu + ((u >> 16) & 1u);
    return (unsigned short)(r >> 16);
}
__device__ __forceinline__ float bf16f(unsigned short h) {
    return __builtin_bit_cast(float, (unsigned)h << 16);
}

__device__ __forceinline__ void gload_lds16(const void* g, void* l) {
    __builtin_amdgcn_global_load_lds(
        (const __attribute__((address_space(1))) unsigned int*)g,
        (__attribute__((address_space(3))) unsigned int*)l, 16, 0, 0);
}

// fp32 -> 3-slot f16 split with power-of-2 rebalanced correction slots.
// A-layout (LO_SLOT=1): [h, l*2^6, h*2^-6];  B-layout (LO_SLOT=2): [h, h*2^-6, l*2^6]
template<int LO_SLOT>
__global__ __launch_bounds__(256)
void split_f16(const float* __restrict__ in, unsigned short* __restrict__ out, int Kc)
{
    int idx = blockIdx.x * 256 + threadIdx.x;
    int perRow = Kc >> 3;
    int row = idx / perRow, c8 = idx - row * perRow;
    const float* src = in + (long)row * Kc + c8 * 8;
    f32x4 x0 = *(const f32x4*)&src[0];
    f32x4 x1 = *(const f32x4*)&src[4];
    u16x8 hi, lsc, hsc;
    #pragma unroll
    for (int e = 0; e < 8; ++e) {
        float xv = (e < 4) ? x0[e] : x1[e - 4];
        _Float16 h = (_Float16)xv;
        float hf = (float)h;
        float l = xv - hf;
        hi[e]  = __builtin_bit_cast(unsigned short, h);
        lsc[e] = ff16(l * 64.f);
        hsc[e] = ff16(hf * 0.015625f);
    }
    long base = (long)row * (3 * Kc) + c8 * 8;
    *(u16x8*)&out[base] = hi;
    *(u16x8*)&out[base + Kc]     = (LO_SLOT == 1) ? lsc : hsc;
    *(u16x8*)&out[base + 2 * Kc] = (LO_SLOT == 1) ? hsc : lsc;
}

__global__ __launch_bounds__(256)
void concat_bias(const float* __restrict__ bq, const float* __restrict__ bk,
                 const float* __restrict__ bv, float* __restrict__ bqkv)
{
    int i = blockIdx.x * 256 + threadIdx.x;
    if (i < 768) bqkv[i] = bq[i];
    else if (i < 1536) bqkv[i] = bk[i - 768];
    else if (i < 2304) bqkv[i] = bv[i - 1536];
}

// pn rows: qnp[8192][12] then knp[8192][12] contiguous; fixed-order sum.
__global__ __launch_bounds__(256)
void finish_norms(const float* __restrict__ pn, float* __restrict__ qn, float* __restrict__ kn)
{
    int row = blockIdx.x * 256 + threadIdx.x;   // 0..16383
    const float* p = pn + (long)row * 12;
    float s = 0.f;
    #pragma unroll
    for (int c = 0; c < 12; ++c) s += p[c];
    if (row < BSR) qn[row] = s; else kn[row - BSR] = s;
}

// ---------------------------------------------------------------------------
// 256x256-tile pipelined distance GEMM (counted-vmcnt, raw barriers).
// Single-term f16: Kd=768 (hi slots only), row stride lda/ldb = K2.
// d[m][n] = rm[m] + rn[n] - 2 * sum_k Ahi[m][k]*Bhi[n][k]  (approx; select's
// margin guard recomputes exact fp32 for the boundary window)
// ---------------------------------------------------------------------------
__global__ __launch_bounds__(512)
void gemm256_dist(const unsigned short* __restrict__ A, const unsigned short* __restrict__ B,
                  const float* __restrict__ rm, const float* __restrict__ rn,
                  float* __restrict__ C,
                  int N, int Kd, long lda, long ldb,
                  long sA, long sB, long sC, long sR)
{
    const int z = blockIdx.z;
    A += (long)z * sA;
    B += (long)z * sB;
    C += (long)z * sC;
    const float* rmz = rm + (long)z * sR;
    const float* rnz = rn + (long)z * sR;

    // bijective XCD swizzle over the 64 blocks of this batch
    int lid = blockIdx.y * gridDim.x + blockIdx.x;
    int xcd = lid & 7, pos = lid >> 3;
    int nlid = xcd * 8 + pos;
    const int bx = nlid & 7, by = nlid >> 3;

    __shared__ __align__(16) unsigned short lds[2 * 32768];  // 2 bufs x (A 16384 | B 16384) f16

    const int tid = threadIdx.x;
    const int lane = tid & 63;
    const int wave = tid >> 6;
    const int wm = wave >> 2, wn = wave & 3;   // 2 x 4 wave grid
    const int m0 = by * 256, n0 = bx * 256;
    const int r15 = lane & 15;
    const int g4 = lane >> 4;

    f32x4 acc[8][4] = {};

    long aB[4], bB[4];
    int lof[4];
    #pragma unroll
    for (int i = 0; i < 4; ++i) {
        int L = i * 512 + tid;          // 0..2047 chunk id (16B chunks)
        int row = L >> 3, ch = L & 7;
        int chs = ch ^ (row & 7);
        aB[i] = (long)(m0 + row) * lda * 2 + chs * 16;
        bB[i] = (long)(n0 + row) * ldb * 2 + chs * 16;
        lof[i] = L * 8;
    }

    const int NT = Kd >> 6;             // 12 K-tiles of 64

    // prologue: stage tile 0 into buf 0
    #pragma unroll
    for (int i = 0; i < 4; ++i) {
        gload_lds16((const char*)A + aB[i], &lds[lof[i]]);
        gload_lds16((const char*)B + bB[i], &lds[16384 + lof[i]]);
    }

    int cur = 0;
    for (int t = 0; t < NT; ++t) {
        if (t + 1 < NT) {
            long kb = (long)(t + 1) * 128;
            int off = (cur ^ 1) * 32768;
            #pragma unroll
            for (int i = 0; i < 4; ++i) {
                gload_lds16((const char*)A + aB[i] + kb, &lds[off + lof[i]]);
                gload_lds16((const char*)B + bB[i] + kb, &lds[off + 16384 + lof[i]]);
            }
            asm volatile("s_waitcnt vmcnt(8)" ::: "memory");
        } else {
            asm volatile("s_waitcnt vmcnt(0)" ::: "memory");
        }
        __builtin_amdgcn_s_barrier();
        __builtin_amdgcn_sched_barrier(0);

        const unsigned short* bufA = &lds[cur * 32768];
        const unsigned short* bufB = bufA + 16384;
        #pragma unroll
        for (int ks = 0; ks < 2; ++ks) {
            f16x8 af[8], bfr[4];
            #pragma unroll
            for (int i = 0; i < 8; ++i) {
                int r = wm * 128 + i * 16 + r15;
                int g = ks * 4 + g4;
                af[i] = *(const f16x8*)&bufA[r * 64 + (g ^ (r & 7)) * 8];
            }
            #pragma unroll
            for (int j = 0; j < 4; ++j) {
                int c = wn * 64 + j * 16 + r15;
                int g = ks * 4 + g4;
                bfr[j] = *(const f16x8*)&bufB[c * 64 + (g ^ (c & 7)) * 8];
            }
            #pragma unroll
            for (int i = 0; i < 8; ++i)
                #pragma unroll
                for (int j = 0; j < 4; ++j)
                    acc[i][j] = __builtin_amdgcn_mfma_f32_16x16x32_f16(
                        af[i], bfr[j], acc[i][j], 0, 0, 0);
        }
        __builtin_amdgcn_sched_barrier(0);
        __builtin_amdgcn_s_barrier();
        cur ^= 1;
    }

    // epilogue: C/D layout col=lane&15, row=(lane>>4)*4+reg
    float rnv[4];
    #pragma unroll
    for (int j = 0; j < 4; ++j)
        rnv[j] = rnz[n0 + wn * 64 + j * 16 + r15];
    #pragma unroll
    for (int i = 0; i < 8; ++i) {
        #pragma unroll
        for (int r = 0; r < 4; ++r) {
            int m = m0 + wm * 128 + i * 16 + g4 * 4 + r;
            float rmv = rmz[m];
            #pragma unroll
            for (int j = 0; j < 4; ++j) {
                int n = n0 + wn * 64 + j * 16 + r15;
                C[(long)m * N + n] = rmv + rnv[j] - 2.f * acc[i][j][r];
            }
        }
    }
}

// C[m][n] = epilogue( sum_k A[m][k]*B[n][k] ), NT, f16 3-term split inputs.
// Pipelined double-buffer schedule (counted vmcnt + raw barriers).
// MODE 0: +bias[n] -> f32 C
// MODE 3: relu(+bias[n]) -> split-A u16 oQ
// MODE 4: combined QKV: seg 0 -> split-A oQ + qnp; 1 -> split-B oK + knp; 2 -> bf16 oV
template<int MODE>
__global__ __launch_bounds__(256)
void gemm_mfma(const unsigned short* __restrict__ A, const unsigned short* __restrict__ B,
               const float* __restrict__ bias,
               float* __restrict__ C,
               int M, int N, int Kd,
               unsigned short* __restrict__ oQ, unsigned short* __restrict__ oK,
               unsigned short* __restrict__ oV, float* __restrict__ pn)
{
    // ---- bijective XCD swizzle (T1/m204) ----
    const int nwgx = gridDim.x;
    const int nwg  = nwgx * gridDim.y;
    int lid = blockIdx.y * nwgx + blockIdx.x;
    int qq = nwg >> 3, rr = nwg & 7;
    int xcd = lid & 7, pos = lid >> 3;
    int nlid = (xcd < rr ? xcd * (qq + 1) : rr * (qq + 1) + (xcd - rr) * qq) + pos;
    const int bx = nlid % nwgx;
    const int by = nlid / nwgx;

    __shared__ __align__(16) unsigned short lds[2 * 16384];  // 2 bufs x (A 8192 | B 8192)

    const int tid = threadIdx.x;
    const int lane = tid & 63;
    const int wave = tid >> 6;
    const int wm = wave >> 1, wn = wave & 1;
    const int m0 = by * 128, n0 = bx * 128;
    const int r15 = lane & 15;
    const int g4 = lane >> 4;

    f32x4 acc[4][4] = {};

    long aByte[4], bByte[4];
    int ldsOff[4];
    #pragma unroll
    for (int i = 0; i < 4; ++i) {
        int L = i * 256 + tid;
        int row = L >> 3, ch = L & 7;
        int chs = ch ^ (row & 7);
        aByte[i] = (long)(m0 + row) * Kd * 2 + chs * 16;
        bByte[i] = (long)(n0 + row) * Kd * 2 + chs * 16;
        ldsOff[i] = L * 8;
    }

    const int NT = Kd >> 6;   // 36

    // prologue: stage tile 0 into buf 0
    #pragma unroll
    for (int i = 0; i < 4; ++i) {
        gload_lds16((const char*)A + aByte[i], &lds[ldsOff[i]]);
        gload_lds16((const char*)B + bByte[i], &lds[8192 + ldsOff[i]]);
    }

    int cur = 0;
    for (int t = 0; t < NT; ++t) {
        if (t + 1 < NT) {
            long kb = (long)(t + 1) * 128;
            int off = (cur ^ 1) * 16384;
            #pragma unroll
            for (int i = 0; i < 4; ++i) {
                gload_lds16((const char*)A + aByte[i] + kb, &lds[off + ldsOff[i]]);
                gload_lds16((const char*)B + bByte[i] + kb, &lds[off + 8192 + ldsOff[i]]);
            }
            asm volatile("s_waitcnt vmcnt(8)" ::: "memory");
        } else {
            asm volatile("s_waitcnt vmcnt(0)" ::: "memory");
        }
        __builtin_amdgcn_s_barrier();
        __builtin_amdgcn_sched_barrier(0);

        const unsigned short* bufA = &lds[cur * 16384];
        const unsigned short* bufB = bufA + 8192;
        #pragma unroll
        for (int ks = 0; ks < 2; ++ks) {
            f16x8 af[4], bfr[4];
            #pragma unroll
            for (int i = 0; i < 4; ++i) {
                int row = wm * 64 + i * 16 + r15;
                int chs = (ks * 4 + g4) ^ (r15 & 7);
                af[i] = *(const f16x8*)&bufA[row * 64 + chs * 8];
            }
            #pragma unroll
            for (int j = 0; j < 4; ++j) {
                int row = wn * 64 + j * 16 + r15;
                int chs = (ks * 4 + g4) ^ (r15 & 7);
                bfr[j] = *(const f16x8*)&bufB[row * 64 + chs * 8];
            }
            #pragma unroll
            for (int i = 0; i < 4; ++i)
                #pragma unroll
                for (int j = 0; j < 4; ++j)
                    acc[i][j] = __builtin_amdgcn_mfma_f32_16x16x32_f16(
                        af[i], bfr[j], acc[i][j], 0, 0, 0);
        }
        __builtin_amdgcn_sched_barrier(0);
        __builtin_amdgcn_s_barrier();
        cur ^= 1;
    }

    float bj[4];
    #pragma unroll
    for (int j = 0; j < 4; ++j) {
        int n = n0 + wn * 64 + j * 16 + r15;
        bj[j] = bias[n];
    }

    if (MODE == 0) {
        #pragma unroll
        for (int i = 0; i < 4; ++i) {
            #pragma unroll
            for (int r = 0; r < 4; ++r) {
                int m = m0 + wm * 64 + i * 16 + g4 * 4 + r;
                #pragma unroll
                for (int j = 0; j < 4; ++j) {
                    int n = n0 + wn * 64 + j * 16 + r15;
                    C[(long)m * N + n] = acc[i][j][r] + bj[j];
                }
            }
        }
    }

    if (MODE == 3) {
        #pragma unroll
        for (int i = 0; i < 4; ++i) {
            #pragma unroll
            for (int r = 0; r < 4; ++r) {
                int m = m0 + wm * 64 + i * 16 + g4 * 4 + r;
                #pragma unroll
                for (int j = 0; j < 4; ++j) {
                    int e = n0 + wn * 64 + j * 16 + r15;
                    float xv = fmaxf(acc[i][j][r] + bj[j], 0.f);
                    _Float16 hh = (_Float16)xv;
                    float hf = (float)hh;
                    float l = xv - hf;
                    long base = (long)m * K2 + e;
                    oQ[base]          = __builtin_bit_cast(unsigned short, hh);
                    oQ[base + DD]     = ff16(l * 64.f);
                    oQ[base + 2 * DD] = ff16(hf * 0.015625f);
                }
            }
        }
    }

    if (MODE == 4) {
        const int seg = n0 / 768;                       // block-uniform: 0=q 1=k 2=v
        const int e0 = n0 - seg * 768 + wn * 64;
        const int chunk = (bx - seg * 6) * 2 + wn;      // 0..11 within segment
        #pragma unroll
        for (int i = 0; i < 4; ++i) {
            #pragma unroll
            for (int r = 0; r < 4; ++r) {
                int m = m0 + wm * 64 + i * 16 + g4 * 4 + r;
                float vals[4];
                #pragma unroll
                for (int j = 0; j < 4; ++j) vals[j] = acc[i][j][r] + bj[j];
                if (seg == 2) {
                    #pragma unroll
                    for (int j = 0; j < 4; ++j)
                        oV[(long)m * DD + e0 + j * 16 + r15] = rne_bf16(vals[j]);
                } else {
                    unsigned short* os = (seg == 0) ? oQ : oK;
                    #pragma unroll
                    for (int j = 0; j < 4; ++j) {
                        float xv = vals[j];
                        _Float16 hh = (_Float16)xv;
                        float hf = (float)hh;
                        float l = xv - hf;
                        long base = (long)m * K2 + e0 + j * 16 + r15;
                        os[base] = __builtin_bit_cast(unsigned short, hh);
                        os[base + ((seg == 0) ? DD : 2 * DD)] = ff16(l * 64.f);
                        os[base + ((seg == 0) ? 2 * DD : DD)] = ff16(hf * 0.015625f);
                    }
                    float s = vals[0]*vals[0] + vals[1]*vals[1]
                            + vals[2]*vals[2] + vals[3]*vals[3];
                    s += __shfl_xor(s, 1); s += __shfl_xor(s, 2);
                    s += __shfl_xor(s, 4); s += __shfl_xor(s, 8);
                    if (r15 == 0)
                        pn[(seg ? (long)BSR * 12 : 0) + (long)m * 12 + chunk] = s;
                }
            }
        }
    }
}

// One WAVE per query row, zero LDS, zero barriers.
__global__ __launch_bounds__(256)
void select_mean(const float* __restrict__ dist, const unsigned short* __restrict__ v,
                 const unsigned short* __restrict__ q_s, const unsigned short* __restrict__ k_s,
                 const float* __restrict__ qn, const float* __restrict__ kn,
                 unsigned short* __restrict__ topo_s)
{
    const int wv = threadIdx.x >> 6;
    const int lane = threadIdx.x & 63;
    const int g = blockIdx.x * 4 + wv;      // global row 0..8191
    const int b = g >> 11;
    const float* drow = dist + (long)b * SS * SS + (long)(g & (SS - 1)) * SS;
    const unsigned short* vb = v + (long)b * SS * DD;

    float d[32];
    unsigned long long h0 = ~0ull, h1 = ~0ull, h2 = ~0ull, h3 = ~0ull,
                       h4 = ~0ull, h5 = ~0ull, h6 = ~0ull, h7 = ~0ull;
    const f32x4* dr4 = (const f32x4*)drow;
    #pragma unroll
    for (int c = 0; c < 8; ++c) {
        f32x4 tv = dr4[c * 64 + lane];
        #pragma unroll
        for (int i = 0; i < 4; ++i) {
            float x = fmaxf(tv[i], 0.f);
            d[c * 4 + i] = x;
            unsigned long long kk =
                ((unsigned long long)__builtin_bit_cast(unsigned, x) << 32)
                | (unsigned)(c * 256 + lane * 4 + i);
            if (kk < h7) {                  // branchless sorted insert
                bool l6 = kk < h6, l5 = kk < h5, l4 = kk < h4, l3 = kk < h3,
                     l2 = kk < h2, l1 = kk < h1, l0 = kk < h0;
                h7 = l6 ? h6 : kk;
                h6 = l6 ? (l5 ? h5 : kk) : h6;
                h5 = l5 ? (l4 ? h4 : kk) : h5;
                h4 = l4 ? (l3 ? h3 : kk) : h4;
                h3 = l3 ? (l2 ? h2 : kk) : h3;
                h2 = l2 ? (l1 ? h1 : kk) : h2;
                h1 = l1 ? (l0 ? h0 : kk) : h1;
                h0 = l0 ? kk : h0;
            }
        }
    }

    // ---- Phase 2: 33 global argmin iterations ----
    unsigned sel = 0;
    int cnt = 0;
    float d32v = 0.f, d33v = 0.f;

    for (int t = 0; t < 33; ++t) {
        unsigned long long best = h0;
        #pragma unroll
        for (int off = 32; off; off >>= 1) {
            unsigned long long o = __shfl_xor(best, off);
            best = o < best ? o : best;
        }
        if (t == 32) {
            d33v = __builtin_bit_cast(float, (unsigned)(best >> 32));
            break;
        }
        int j = (int)(unsigned)best;
        bool won = (lane == ((j >> 2) & 63));
        if (won) sel |= 1u << (((j >> 8) << 2) | (j & 3));
        if (t == 31) d32v = __builtin_bit_cast(float, (unsigned)(best >> 32));

        if (won) cnt++;
        bool needScan = won && (cnt >= 8);
        bool adv = won && (cnt < 8);
        h0 = adv ? h1 : h0;  h1 = adv ? h2 : h1;  h2 = adv ? h3 : h2;
        h3 = adv ? h4 : h3;  h4 = adv ? h5 : h4;  h5 = adv ? h6 : h5;
        h6 = adv ? h7 : h6;  h7 = adv ? ~0ull : h7;
        if (__any(needScan)) {              // expected never taken
            if (needScan) {
                float bv = FLT_MAX; int bs = 0; bool found = false;
                #pragma unroll
                for (int s = 0; s < 32; ++s) {
                    bool ok = !((sel >> s) & 1u);
                    bool lt = ok && (d[s] < bv);
                    bv = lt ? d[s] : bv; bs = lt ? s : bs; found |= ok;
                }
                h0 = found
                   ? (((unsigned long long)__builtin_bit_cast(unsigned, bv) << 32)
                      | (unsigned)((bs >> 2) * 256 + lane * 4 + (bs & 3)))
                   : ~0ull;
            }
        }
    }

    // ---- Phase 3: boundary-gap guard (exact fp32 recompute for the window) ----
    if (d33v - d32v < MARGIN) {
        float lo = d32v - MARGIN, hi = d33v + MARGIN;
        unsigned cand = 0;
        #pragma unroll
        for (int s = 0; s < 32; ++s)
            if (d[s] >= lo && d[s] <= hi) cand |= 1u << s;

        const unsigned short* qrow = q_s + (long)g * K2;
        #pragma unroll
        for (int s = 0; s < 32; ++s) {
            unsigned long long m = __ballot((cand >> s) & 1u);
            while (m) {
                int l2 = __ffsll(m) - 1;
                m &= m - 1;
                int j = (s >> 2) * 256 + l2 * 4 + (s & 3);
                const unsigned short* krow = k_s + ((long)b * SS + j) * K2;
                float part = 0.f;
                #pragma unroll
                for (int i = 0; i < 12; ++i) {
                    int e = i * 64 + lane;
                    float qv = f16f(qrow[e]) + f16f(qrow[DD + e]) * 0.015625f;
                    float kv = f16f(krow[e]) + f16f(krow[2 * DD + e]) * 0.015625f;
                    part = fmaf(qv, kv, part);
                }
                #pragma unroll
                for (int off = 32; off; off >>= 1) part += __shfl_xor(part, off);
                float dd = qn[g] + kn[(long)b * SS + j] - 2.f * part;
                dd = fmaxf(dd, 0.f);
                if (lane == l2) d[s] = dd;
            }
        }

        sel &= ~cand;
        int C = 0;
        #pragma unroll
        for (int s = 0; s < 32; ++s) C += (int)__popcll(__ballot((sel >> s) & 1u));
        int need = KNEI - C;
        for (int t = 0; t < need; ++t) {
            unsigned long long best = ~0ull;
            #pragma unroll
            for (int s = 0; s < 32; ++s) {
                if (((cand >> s) & 1u) && !((sel >> s) & 1u)) {
                    unsigned long long key =
                        ((unsigned long long)__builtin_bit_cast(unsigned, d[s]) << 32)
                        | (unsigned)((s >> 2) * 256 + lane * 4 + (s & 3));
                    best = key < best ? key : best;
                }
            }
            #pragma unroll
            for (int off = 32; off; off >>= 1) {
                unsigned long long o = __shfl_xor(best, off);
                best = o < best ? o : best;
            }
            if (best != ~0ull) {
                int j = (int)(unsigned)best;
                if (lane == ((j >> 2) & 63)) sel |= 1u << (((j >> 8) << 2) | (j & 3));
            }
        }
    }

    // ---- Phase 4: gather-mean of bf16 v, write split topo (A-layout) ----
    f32x4 a0 = {0.f, 0.f, 0.f, 0.f}, a1 = a0, a2 = a0;
    #pragma unroll
    for (int s = 0; s < 32; ++s) {
        unsigned long long m = __ballot((sel >> s) & 1u);
        while (m) {
            int l2 = __ffsll(m) - 1;
            m &= m - 1;
            int j = (s >> 2) * 256 + l2 * 4 + (s & 3);
            const u16x4* vr = (const u16x4*)(vb + (long)j * DD);
            u16x4 r0 = vr[lane], r1 = vr[lane + 64], r2 = vr[lane + 128];
            #pragma unroll
            for (int e = 0; e < 4; ++e) {
                a0[e] += bf16f(r0[e]);
                a1[e] += bf16f(r1[e]);
                a2[e] += bf16f(r2[e]);
            }
        }
    }
    const float sc = 1.0f / 32.0f;
    unsigned short* trow = topo_s + (long)g * K2;
    #pragma unroll
    for (int c = 0; c < 3; ++c) {
        f32x4 x = (c == 0) ? a0 : (c == 1) ? a1 : a2;
        u16x4 hi, ls, hs2;
        #pragma unroll
        for (int e = 0; e < 4; ++e) {
            float xv = x[e] * sc;
            _Float16 hh = (_Float16)xv;
            float hf = (float)hh;
            float l = xv - hf;
            hi[e]  = __builtin_bit_cast(unsigned short, hh);
            ls[e]  = ff16(l * 64.f);
            hs2[e] = ff16(hf * 0.015625f);
        }
        *(u16x4*)&trow[c * 256 + lane * 4]            = hi;
        *(u16x4*)&trow[DD + c * 256 + lane * 4]       = ls;
        *(u16x4*)&trow[2 * DD + c * 256 + lane * 4]   = hs2;
    }
}

extern "C" void kernel_launch(void* const* d_in, const int* in_sizes, int n_in,
                              void* d_out, int out_size, void* d_ws, size_t ws_size,
                              hipStream_t stream)
{
    const float* hs = (const float*)d_in[0];
    const float* Wq = (const float*)d_in[1];
    const float* bq = (const float*)d_in[2];
    const float* Wk = (const float*)d_in[3];
    const float* bk = (const float*)d_in[4];
    const float* Wv = (const float*)d_in[5];
    const float* bv = (const float*)d_in[6];
    const float* W1 = (const float*)d_in[7];
    const float* b1 = (const float*)d_in[8];
    const float* W2 = (const float*)d_in[9];
    const float* b2 = (const float*)d_in[10];
    float* out = (float*)d_out;

    // ---- workspace layout (peak ~204 MB), time-overlaid ----
    char* w = (char*)d_ws;
    const long DISTB = (long)BB * SS * SS * 4;        // 67,108,864
    const long VB    = (long)BSR * DD * 2;            // 12,582,912 (bf16 v)
    const long SPLB  = (long)BSR * K2 * 2;            // 37,748,736
    const long WSPL  = (long)DD * K2;                 // elems per split weight

    float*          dist   = (float*)w;                               // [0, 67.1M)
    unsigned short* h_s    = (unsigned short*)w;                      // overlays dead dist
    unsigned short* v      = (unsigned short*)(w + DISTB);            // bf16 v
    unsigned short* q_s    = (unsigned short*)(w + DISTB + VB);
    unsigned short* k_s    = q_s + SPLB / 2;
    unsigned short* hs_s   = k_s + SPLB / 2;
    unsigned short* topo_s = hs_s;                                    // overlays dead hs_s
    unsigned short* Wqkv_s = hs_s + SPLB / 2;                         // 3 weight splits adjacent
    unsigned short* W1_s   = Wqkv_s;                                  // overlays dead Wqkv after qkv gemm
    unsigned short* W2_s   = Wqkv_s + WSPL;
    char* tail  = (char*)(Wqkv_s + 3 * WSPL);
    float* qn   = (float*)tail;                        // 8192
    float* kn   = qn + BSR;                            // 8192
    float* pn   = kn + BSR;                            // qnp[8192][12] + knp[8192][12]
    float* bqkv = pn + (long)2 * BSR * 12;             // 2304

    dim3 blk(256);
    const int convW  = (DD * (DD / 8)) / 256;          // 288 blocks per weight
    const int convHS = (BSR * (DD / 8)) / 256;         // 3072 blocks

    concat_bias<<<9, blk, 0, stream>>>(bq, bk, bv, bqkv);
    split_f16<2><<<convW, blk, 0, stream>>>(Wq, Wqkv_s, DD);
    split_f16<2><<<convW, blk, 0, stream>>>(Wk, Wqkv_s + WSPL, DD);
    split_f16<2><<<convW, blk, 0, stream>>>(Wv, Wqkv_s + 2 * WSPL, DD);
    split_f16<1><<<convHS, blk, 0, stream>>>(hs, hs_s, DD);

    // fused QKV gemm: q->split-A + norms, k->split-B + norms, v->bf16
    gemm_mfma<4><<<dim3(2304 / 128, BSR / 128, 1), blk, 0, stream>>>(
        hs_s, Wqkv_s, bqkv, nullptr, BSR, 2304, K2,
        q_s, k_s, v, pn);

    // W1/W2 splits into dead Wqkv region
    split_f16<2><<<convW, blk, 0, stream>>>(W1, W1_s, DD);
    split_f16<2><<<convW, blk, 0, stream>>>(W2, W2_s, DD);
    finish_norms<<<(2 * BSR) / 256, blk, 0, stream>>>(pn, qn, kn);

    // squared distance matrix per batch: single-term f16 (Kd=768, stride K2)
    gemm256_dist<<<dim3(SS / 256, SS / 256, BB), dim3(512), 0, stream>>>(
        q_s, k_s, qn, kn, dist, SS, DD, K2, K2,
        (long)SS * K2, (long)SS * K2, (long)SS * SS, SS);

    select_mean<<<BSR / 4, blk, 0, stream>>>(dist, v, q_s, k_s, qn, kn, topo_s);

    // MLP: gemm1 writes split-A h_s directly (relu fused)
    gemm_mfma<3><<<dim3(DD / 128, BSR / 128, 1), blk, 0, stream>>>(
        topo_s, W1_s, b1, nullptr, BSR, DD, K2,
        h_s, nullptr, nullptr, nullptr);
    gemm_mfma<0><<<dim3(DD / 128, BSR / 128, 1), blk, 0, stream>>>(
        h_s, W2_s, b2, out, BSR, DD, K2,
        nullptr, nullptr, nullptr, nullptr);
}

// Round 11
// 341.791 us; speedup vs baseline: 3.6645x; 1.1232x over previous
//
#include <hip/hip_runtime.h>
#include <float.h>

#define DD 768
#define SS 2048
#define BB 4
#define BSR (BB*SS)   // 8192 total rows
#define KNEI 32
#define K2 (3*DD)     // 2304: [hi | x | y] split concat along K
#define MARGIN 0.12f  // >=6 sigma of single-term f16 pairwise dist error

typedef __attribute__((ext_vector_type(8))) _Float16 f16x8;
typedef __attribute__((ext_vector_type(4))) float f32x4;
typedef __attribute__((ext_vector_type(8))) unsigned short u16x8;
typedef __attribute__((ext_vector_type(4))) unsigned short u16x4;

__device__ __forceinline__ float f16f(unsigned short u) {
    return (float)__builtin_bit_cast(_Float16, u);
}
__device__ __forceinline__ unsigned short ff16(float x) {
    return __builtin_bit_cast(unsigned short, (_Float16)x);
}
__device__ __forceinline__ unsigned short rne_bf16(float x) {
    unsigned u = __builtin_bit_cast(unsigned, x);
    unsigned r = u + 0x7FFFu + ((u >> 16) & 1u);
    return (unsigned short)(r >> 16);
}
__device__ __forceinline__ float bf16f(unsigned short h) {
    return __builtin_bit_cast(float, (unsigned)h << 16);
}

__device__ __forceinline__ void gload_lds16(const void* g, void* l) {
    __builtin_amdgcn_global_load_lds(
        (const __attribute__((address_space(1))) unsigned int*)g,
        (__attribute__((address_space(3))) unsigned int*)l, 16, 0, 0);
}

// fp32 -> 3-slot f16 split with power-of-2 rebalanced correction slots.
// A-layout (LO_SLOT=1): [h, l*2^6, h*2^-6];  B-layout (LO_SLOT=2): [h, h*2^-6, l*2^6]
template<int LO_SLOT>
__global__ __launch_bounds__(256)
void split_f16(const float* __restrict__ in, unsigned short* __restrict__ out, int Kc)
{
    int idx = blockIdx.x * 256 + threadIdx.x;
    int perRow = Kc >> 3;
    int row = idx / perRow, c8 = idx - row * perRow;
    const float* src = in + (long)row * Kc + c8 * 8;
    f32x4 x0 = *(const f32x4*)&src[0];
    f32x4 x1 = *(const f32x4*)&src[4];
    u16x8 hi, lsc, hsc;
    #pragma unroll
    for (int e = 0; e < 8; ++e) {
        float xv = (e < 4) ? x0[e] : x1[e - 4];
        _Float16 h = (_Float16)xv;
        float hf = (float)h;
        float l = xv - hf;
        hi[e]  = __builtin_bit_cast(unsigned short, h);
        lsc[e] = ff16(l * 64.f);
        hsc[e] = ff16(hf * 0.015625f);
    }
    long base = (long)row * (3 * Kc) + c8 * 8;
    *(u16x8*)&out[base] = hi;
    *(u16x8*)&out[base + Kc]     = (LO_SLOT == 1) ? lsc : hsc;
    *(u16x8*)&out[base + 2 * Kc] = (LO_SLOT == 1) ? hsc : lsc;
}

__global__ __launch_bounds__(256)
void concat_bias(const float* __restrict__ bq, const float* __restrict__ bk,
                 const float* __restrict__ bv, float* __restrict__ bqkv)
{
    int i = blockIdx.x * 256 + threadIdx.x;
    if (i < 768) bqkv[i] = bq[i];
    else if (i < 1536) bqkv[i] = bk[i - 768];
    else if (i < 2304) bqkv[i] = bv[i - 1536];
}

// pn rows: qnp[8192][12] then knp[8192][12] contiguous; fixed-order sum.
__global__ __launch_bounds__(256)
void finish_norms(const float* __restrict__ pn, float* __restrict__ qn, float* __restrict__ kn)
{
    int row = blockIdx.x * 256 + threadIdx.x;   // 0..16383
    const float* p = pn + (long)row * 12;
    float s = 0.f;
    #pragma unroll
    for (int c = 0; c < 12; ++c) s += p[c];
    if (row < BSR) qn[row] = s; else kn[row - BSR] = s;
}

// ---------------------------------------------------------------------------
// 256x256-tile pipelined distance GEMM (counted-vmcnt, raw barriers).
// Single-term f16: Kd=768 (hi slots only), row stride lda/ldb = K2.
// ---------------------------------------------------------------------------
__global__ __launch_bounds__(512)
void gemm256_dist(const unsigned short* __restrict__ A, const unsigned short* __restrict__ B,
                  const float* __restrict__ rm, const float* __restrict__ rn,
                  float* __restrict__ C,
                  int N, int Kd, long lda, long ldb,
                  long sA, long sB, long sC, long sR)
{
    const int z = blockIdx.z;
    A += (long)z * sA;
    B += (long)z * sB;
    C += (long)z * sC;
    const float* rmz = rm + (long)z * sR;
    const float* rnz = rn + (long)z * sR;

    // bijective XCD swizzle over the 64 blocks of this batch
    int lid = blockIdx.y * gridDim.x + blockIdx.x;
    int xcd = lid & 7, pos = lid >> 3;
    int nlid = xcd * 8 + pos;
    const int bx = nlid & 7, by = nlid >> 3;

    __shared__ __align__(16) unsigned short lds[2 * 32768];  // 2 bufs x (A 16384 | B 16384) f16

    const int tid = threadIdx.x;
    const int lane = tid & 63;
    const int wave = tid >> 6;
    const int wm = wave >> 2, wn = wave & 3;   // 2 x 4 wave grid
    const int m0 = by * 256, n0 = bx * 256;
    const int r15 = lane & 15;
    const int g4 = lane >> 4;

    f32x4 acc[8][4] = {};

    long aB[4], bB[4];
    int lof[4];
    #pragma unroll
    for (int i = 0; i < 4; ++i) {
        int L = i * 512 + tid;          // 0..2047 chunk id (16B chunks)
        int row = L >> 3, ch = L & 7;
        int chs = ch ^ (row & 7);
        aB[i] = (long)(m0 + row) * lda * 2 + chs * 16;
        bB[i] = (long)(n0 + row) * ldb * 2 + chs * 16;
        lof[i] = L * 8;
    }

    const int NT = Kd >> 6;             // 12 K-tiles of 64

    // prologue: stage tile 0 into buf 0
    #pragma unroll
    for (int i = 0; i < 4; ++i) {
        gload_lds16((const char*)A + aB[i], &lds[lof[i]]);
        gload_lds16((const char*)B + bB[i], &lds[16384 + lof[i]]);
    }

    int cur = 0;
    for (int t = 0; t < NT; ++t) {
        if (t + 1 < NT) {
            long kb = (long)(t + 1) * 128;
            int off = (cur ^ 1) * 32768;
            #pragma unroll
            for (int i = 0; i < 4; ++i) {
                gload_lds16((const char*)A + aB[i] + kb, &lds[off + lof[i]]);
                gload_lds16((const char*)B + bB[i] + kb, &lds[off + 16384 + lof[i]]);
            }
            asm volatile("s_waitcnt vmcnt(8)" ::: "memory");
        } else {
            asm volatile("s_waitcnt vmcnt(0)" ::: "memory");
        }
        __builtin_amdgcn_s_barrier();
        __builtin_amdgcn_sched_barrier(0);

        const unsigned short* bufA = &lds[cur * 32768];
        const unsigned short* bufB = bufA + 16384;
        #pragma unroll
        for (int ks = 0; ks < 2; ++ks) {
            f16x8 af[8], bfr[4];
            #pragma unroll
            for (int i = 0; i < 8; ++i) {
                int r = wm * 128 + i * 16 + r15;
                int g = ks * 4 + g4;
                af[i] = *(const f16x8*)&bufA[r * 64 + (g ^ (r & 7)) * 8];
            }
            #pragma unroll
            for (int j = 0; j < 4; ++j) {
                int c = wn * 64 + j * 16 + r15;
                int g = ks * 4 + g4;
                bfr[j] = *(const f16x8*)&bufB[c * 64 + (g ^ (c & 7)) * 8];
            }
            #pragma unroll
            for (int i = 0; i < 8; ++i)
                #pragma unroll
                for (int j = 0; j < 4; ++j)
                    acc[i][j] = __builtin_amdgcn_mfma_f32_16x16x32_f16(
                        af[i], bfr[j], acc[i][j], 0, 0, 0);
        }
        __builtin_amdgcn_sched_barrier(0);
        __builtin_amdgcn_s_barrier();
        cur ^= 1;
    }

    // epilogue: C/D layout col=lane&15, row=(lane>>4)*4+reg
    float rnv[4];
    #pragma unroll
    for (int j = 0; j < 4; ++j)
        rnv[j] = rnz[n0 + wn * 64 + j * 16 + r15];
    #pragma unroll
    for (int i = 0; i < 8; ++i) {
        #pragma unroll
        for (int r = 0; r < 4; ++r) {
            int m = m0 + wm * 128 + i * 16 + g4 * 4 + r;
            float rmv = rmz[m];
            #pragma unroll
            for (int j = 0; j < 4; ++j) {
                int n = n0 + wn * 64 + j * 16 + r15;
                C[(long)m * N + n] = rmv + rnv[j] - 2.f * acc[i][j][r];
            }
        }
    }
}

// C[m][n] = epilogue( sum_k A[m][k]*B[n][k] ), NT, f16 3-term split inputs.
// Pipelined double-buffer schedule (counted vmcnt + raw barriers).
// MODE 0: +bias[n] -> f32 C
// MODE 3: relu(+bias[n]) -> split-A u16 oQ
// MODE 4: combined QKV: seg 0 -> split-A oQ + qnp; 1 -> split-B oK + knp; 2 -> bf16 oV
template<int MODE>
__global__ __launch_bounds__(256)
void gemm_mfma(const unsigned short* __restrict__ A, const unsigned short* __restrict__ B,
               const float* __restrict__ bias,
               float* __restrict__ C,
               int M, int N, int Kd,
               unsigned short* __restrict__ oQ, unsigned short* __restrict__ oK,
               unsigned short* __restrict__ oV, float* __restrict__ pn)
{
    // ---- bijective XCD swizzle (T1/m204) ----
    const int nwgx = gridDim.x;
    const int nwg  = nwgx * gridDim.y;
    int lid = blockIdx.y * nwgx + blockIdx.x;
    int qq = nwg >> 3, rr = nwg & 7;
    int xcd = lid & 7, pos = lid >> 3;
    int nlid = (xcd < rr ? xcd * (qq + 1) : rr * (qq + 1) + (xcd - rr) * qq) + pos;
    const int bx = nlid % nwgx;
    const int by = nlid / nwgx;

    __shared__ __align__(16) unsigned short lds[2 * 16384];  // 2 bufs x (A 8192 | B 8192)

    const int tid = threadIdx.x;
    const int lane = tid & 63;
    const int wave = tid >> 6;
    const int wm = wave >> 1, wn = wave & 1;
    const int m0 = by * 128, n0 = bx * 128;
    const int r15 = lane & 15;
    const int g4 = lane >> 4;

    f32x4 acc[4][4] = {};

    long aByte[4], bByte[4];
    int ldsOff[4];
    #pragma unroll
    for (int i = 0; i < 4; ++i) {
        int L = i * 256 + tid;
        int row = L >> 3, ch = L & 7;
        int chs = ch ^ (row & 7);
        aByte[i] = (long)(m0 + row) * Kd * 2 + chs * 16;
        bByte[i] = (long)(n0 + row) * Kd * 2 + chs * 16;
        ldsOff[i] = L * 8;
    }

    const int NT = Kd >> 6;   // 36 or 12

    // prologue: stage tile 0 into buf 0
    #pragma unroll
    for (int i = 0; i < 4; ++i) {
        gload_lds16((const char*)A + aByte[i], &lds[ldsOff[i]]);
        gload_lds16((const char*)B + bByte[i], &lds[8192 + ldsOff[i]]);
    }

    int cur = 0;
    for (int t = 0; t < NT; ++t) {
        if (t + 1 < NT) {
            long kb = (long)(t + 1) * 128;
            int off = (cur ^ 1) * 16384;
            #pragma unroll
            for (int i = 0; i < 4; ++i) {
                gload_lds16((const char*)A + aByte[i] + kb, &lds[off + ldsOff[i]]);
                gload_lds16((const char*)B + bByte[i] + kb, &lds[off + 8192 + ldsOff[i]]);
            }
            asm volatile("s_waitcnt vmcnt(8)" ::: "memory");
        } else {
            asm volatile("s_waitcnt vmcnt(0)" ::: "memory");
        }
        __builtin_amdgcn_s_barrier();
        __builtin_amdgcn_sched_barrier(0);

        const unsigned short* bufA = &lds[cur * 16384];
        const unsigned short* bufB = bufA + 8192;
        #pragma unroll
        for (int ks = 0; ks < 2; ++ks) {
            f16x8 af[4], bfr[4];
            #pragma unroll
            for (int i = 0; i < 4; ++i) {
                int row = wm * 64 + i * 16 + r15;
                int chs = (ks * 4 + g4) ^ (r15 & 7);
                af[i] = *(const f16x8*)&bufA[row * 64 + chs * 8];
            }
            #pragma unroll
            for (int j = 0; j < 4; ++j) {
                int row = wn * 64 + j * 16 + r15;
                int chs = (ks * 4 + g4) ^ (r15 & 7);
                bfr[j] = *(const f16x8*)&bufB[row * 64 + chs * 8];
            }
            #pragma unroll
            for (int i = 0; i < 4; ++i)
                #pragma unroll
                for (int j = 0; j < 4; ++j)
                    acc[i][j] = __builtin_amdgcn_mfma_f32_16x16x32_f16(
                        af[i], bfr[j], acc[i][j], 0, 0, 0);
        }
        __builtin_amdgcn_sched_barrier(0);
        __builtin_amdgcn_s_barrier();
        cur ^= 1;
    }

    float bj[4];
    #pragma unroll
    for (int j = 0; j < 4; ++j) {
        int n = n0 + wn * 64 + j * 16 + r15;
        bj[j] = bias[n];
    }

    if (MODE == 0) {
        #pragma unroll
        for (int i = 0; i < 4; ++i) {
            #pragma unroll
            for (int r = 0; r < 4; ++r) {
                int m = m0 + wm * 64 + i * 16 + g4 * 4 + r;
                #pragma unroll
                for (int j = 0; j < 4; ++j) {
                    int n = n0 + wn * 64 + j * 16 + r15;
                    C[(long)m * N + n] = acc[i][j][r] + bj[j];
                }
            }
        }
    }

    if (MODE == 3) {
        #pragma unroll
        for (int i = 0; i < 4; ++i) {
            #pragma unroll
            for (int r = 0; r < 4; ++r) {
                int m = m0 + wm * 64 + i * 16 + g4 * 4 + r;
                #pragma unroll
                for (int j = 0; j < 4; ++j) {
                    int e = n0 + wn * 64 + j * 16 + r15;
                    float xv = fmaxf(acc[i][j][r] + bj[j], 0.f);
                    _Float16 hh = (_Float16)xv;
                    float hf = (float)hh;
                    float l = xv - hf;
                    long base = (long)m * K2 + e;
                    oQ[base]          = __builtin_bit_cast(unsigned short, hh);
                    oQ[base + DD]     = ff16(l * 64.f);
                    oQ[base + 2 * DD] = ff16(hf * 0.015625f);
                }
            }
        }
    }

    if (MODE == 4) {
        const int seg = n0 / 768;                       // block-uniform: 0=q 1=k 2=v
        const int e0 = n0 - seg * 768 + wn * 64;
        const int chunk = (bx - seg * 6) * 2 + wn;      // 0..11 within segment
        #pragma unroll
        for (int i = 0; i < 4; ++i) {
            #pragma unroll
            for (int r = 0; r < 4; ++r) {
                int m = m0 + wm * 64 + i * 16 + g4 * 4 + r;
                float vals[4];
                #pragma unroll
                for (int j = 0; j < 4; ++j) vals[j] = acc[i][j][r] + bj[j];
                if (seg == 2) {
                    #pragma unroll
                    for (int j = 0; j < 4; ++j)
                        oV[(long)m * DD + e0 + j * 16 + r15] = rne_bf16(vals[j]);
                } else {
                    unsigned short* os = (seg == 0) ? oQ : oK;
                    #pragma unroll
                    for (int j = 0; j < 4; ++j) {
                        float xv = vals[j];
                        _Float16 hh = (_Float16)xv;
                        float hf = (float)hh;
                        float l = xv - hf;
                        long base = (long)m * K2 + e0 + j * 16 + r15;
                        os[base] = __builtin_bit_cast(unsigned short, hh);
                        os[base + ((seg == 0) ? DD : 2 * DD)] = ff16(l * 64.f);
                        os[base + ((seg == 0) ? 2 * DD : DD)] = ff16(hf * 0.015625f);
                    }
                    float s = vals[0]*vals[0] + vals[1]*vals[1]
                            + vals[2]*vals[2] + vals[3]*vals[3];
                    s += __shfl_xor(s, 1); s += __shfl_xor(s, 2);
                    s += __shfl_xor(s, 4); s += __shfl_xor(s, 8);
                    if (r15 == 0)
                        pn[(seg ? (long)BSR * 12 : 0) + (long)m * 12 + chunk] = s;
                }
            }
        }
    }
}

// One WAVE per query row, zero LDS, zero barriers.
// Phase 1: streaming branchless insertion top-8 per lane (sorted u64 keys).
// Phase 2: threshold selection — 32-step binary search on value bits with
//          ballot-based counting (no shuffle chains); exact ties by index;
//          wave-uniform fallback to the proven 33-iteration path if any lane
//          might hold >8 of the top-32 (saturation; ~1e-6 probability).
// Phase 3: boundary-gap guard (exact fp32 recompute from splits).
// Phase 4: gather-mean of v (bf16), write SPLIT topo (A-layout) directly.
// Element j of the row lives at slot s, lane l: j = (s>>2)*256 + l*4 + (s&3)
__global__ __launch_bounds__(256)
void select_mean(const float* __restrict__ dist, const unsigned short* __restrict__ v,
                 const unsigned short* __restrict__ q_s, const unsigned short* __restrict__ k_s,
                 const float* __restrict__ qn, const float* __restrict__ kn,
                 unsigned short* __restrict__ topo_s)
{
    const int wv = threadIdx.x >> 6;
    const int lane = threadIdx.x & 63;
    const int g = blockIdx.x * 4 + wv;      // global row 0..8191
    const int b = g >> 11;
    const float* drow = dist + (long)b * SS * SS + (long)(g & (SS - 1)) * SS;
    const unsigned short* vb = v + (long)b * SS * DD;

    float d[32];
    unsigned long long h0 = ~0ull, h1 = ~0ull, h2 = ~0ull, h3 = ~0ull,
                       h4 = ~0ull, h5 = ~0ull, h6 = ~0ull, h7 = ~0ull;
    const f32x4* dr4 = (const f32x4*)drow;
    #pragma unroll
    for (int c = 0; c < 8; ++c) {
        f32x4 tv = dr4[c * 64 + lane];
        #pragma unroll
        for (int i = 0; i < 4; ++i) {
            float x = fmaxf(tv[i], 0.f);
            d[c * 4 + i] = x;
            unsigned long long kk =
                ((unsigned long long)__builtin_bit_cast(unsigned, x) << 32)
                | (unsigned)(c * 256 + lane * 4 + i);
            if (kk < h7) {                  // branchless sorted insert
                bool l6 = kk < h6, l5 = kk < h5, l4 = kk < h4, l3 = kk < h3,
                     l2 = kk < h2, l1 = kk < h1, l0 = kk < h0;
                h7 = l6 ? h6 : kk;
                h6 = l6 ? (l5 ? h5 : kk) : h6;
                h5 = l5 ? (l4 ? h4 : kk) : h5;
                h4 = l4 ? (l3 ? h3 : kk) : h4;
                h3 = l3 ? (l2 ? h2 : kk) : h3;
                h2 = l2 ? (l1 ? h1 : kk) : h2;
                h1 = l1 ? (l0 ? h0 : kk) : h1;
                h0 = l0 ? kk : h0;
            }
        }
    }

    unsigned sel = 0;
    float d32v = 0.f, d33v = 0.f;

    // ---- Phase 2: threshold selection via value-bit binary search ----
    // V* = max v with #{value < v} <= 31  => V* = value of rank-31 (0-idx) key
    unsigned Vv = 0;
    for (int bit = 31; bit >= 0; --bit) {
        unsigned candv = Vv | (1u << bit);
        int cntv = 0;
        cntv += (int)__popcll(__ballot((unsigned)(h0 >> 32) < candv));
        cntv += (int)__popcll(__ballot((unsigned)(h1 >> 32) < candv));
        cntv += (int)__popcll(__ballot((unsigned)(h2 >> 32) < candv));
        cntv += (int)__popcll(__ballot((unsigned)(h3 >> 32) < candv));
        cntv += (int)__popcll(__ballot((unsigned)(h4 >> 32) < candv));
        cntv += (int)__popcll(__ballot((unsigned)(h5 >> 32) < candv));
        cntv += (int)__popcll(__ballot((unsigned)(h6 >> 32) < candv));
        cntv += (int)__popcll(__ballot((unsigned)(h7 >> 32) < candv));
        if (cntv <= 31) Vv = candv;
    }
    bool fallback = __any((unsigned)(h7 >> 32) <= Vv);

    if (!fallback) {
        int c_lt = 0;
        c_lt += (int)__popcll(__ballot((unsigned)(h0 >> 32) < Vv));
        c_lt += (int)__popcll(__ballot((unsigned)(h1 >> 32) < Vv));
        c_lt += (int)__popcll(__ballot((unsigned)(h2 >> 32) < Vv));
        c_lt += (int)__popcll(__ballot((unsigned)(h3 >> 32) < Vv));
        c_lt += (int)__popcll(__ballot((unsigned)(h4 >> 32) < Vv));
        c_lt += (int)__popcll(__ballot((unsigned)(h5 >> 32) < Vv));
        c_lt += (int)__popcll(__ballot((unsigned)(h6 >> 32) < Vv));
        c_lt += (int)__popcll(__ballot((unsigned)(h7 >> 32) < Vv));
        #pragma unroll
        for (int s = 0; s < 32; ++s)
            if (__builtin_bit_cast(unsigned, d[s]) < Vv) sel |= 1u << s;
        int need = KNEI - c_lt;
        for (int t2 = 0; t2 < need; ++t2) {
            unsigned mi = 0xffffffffu;
            #pragma unroll
            for (int s = 0; s < 32; ++s) {
                bool eq = (__builtin_bit_cast(unsigned, d[s]) == Vv) && !((sel >> s) & 1u);
                unsigned jj = (unsigned)((s >> 2) * 256 + lane * 4 + (s & 3));
                if (eq && jj < mi) mi = jj;
            }
            #pragma unroll
            for (int off = 32; off; off >>= 1) {
                unsigned o = __shfl_xor(mi, off);
                mi = o < mi ? o : mi;
            }
            if (mi != 0xffffffffu && lane == ((mi >> 2) & 63))
                sel |= 1u << (((mi >> 8) << 2) | (mi & 3));
        }
        d32v = __builtin_bit_cast(float, Vv);
        int c_le = 0;
        c_le += (int)__popcll(__ballot((unsigned)(h0 >> 32) <= Vv));
        c_le += (int)__popcll(__ballot((unsigned)(h1 >> 32) <= Vv));
        c_le += (int)__popcll(__ballot((unsigned)(h2 >> 32) <= Vv));
        c_le += (int)__popcll(__ballot((unsigned)(h3 >> 32) <= Vv));
        c_le += (int)__popcll(__ballot((unsigned)(h4 >> 32) <= Vv));
        c_le += (int)__popcll(__ballot((unsigned)(h5 >> 32) <= Vv));
        c_le += (int)__popcll(__ballot((unsigned)(h6 >> 32) <= Vv));
        c_le += (int)__popcll(__ballot((unsigned)(h7 >> 32) <= Vv));
        if (c_le >= 33) {
            d33v = d32v;
        } else {
            unsigned mv = 0xffffffffu;
            { unsigned hv = (unsigned)(h0 >> 32); if (hv > Vv && hv < mv) mv = hv; }
            { unsigned hv = (unsigned)(h1 >> 32); if (hv > Vv && hv < mv) mv = hv; }
            { unsigned hv = (unsigned)(h2 >> 32); if (hv > Vv && hv < mv) mv = hv; }
            { unsigned hv = (unsigned)(h3 >> 32); if (hv > Vv && hv < mv) mv = hv; }
            { unsigned hv = (unsigned)(h4 >> 32); if (hv > Vv && hv < mv) mv = hv; }
            { unsigned hv = (unsigned)(h5 >> 32); if (hv > Vv && hv < mv) mv = hv; }
            { unsigned hv = (unsigned)(h6 >> 32); if (hv > Vv && hv < mv) mv = hv; }
            { unsigned hv = (unsigned)(h7 >> 32); if (hv > Vv && hv < mv) mv = hv; }
            #pragma unroll
            for (int off = 32; off; off >>= 1) {
                unsigned o = __shfl_xor(mv, off);
                mv = o < mv ? o : mv;
            }
            d33v = __builtin_bit_cast(float, mv);
        }
    } else {
        // ---- proven 33-iteration tournament path (rare) ----
        int cnt = 0;
        for (int t = 0; t < 33; ++t) {
            unsigned long long best = h0;
            #pragma unroll
            for (int off = 32; off; off >>= 1) {
                unsigned long long o = __shfl_xor(best, off);
                best = o < best ? o : best;
            }
            if (t == 32) {
                d33v = __builtin_bit_cast(float, (unsigned)(best >> 32));
                break;
            }
            int j = (int)(unsigned)best;
            bool won = (lane == ((j >> 2) & 63));
            if (won) sel |= 1u << (((j >> 8) << 2) | (j & 3));
            if (t == 31) d32v = __builtin_bit_cast(float, (unsigned)(best >> 32));

            if (won) cnt++;
            bool needScan = won && (cnt >= 8);
            bool adv = won && (cnt < 8);
            h0 = adv ? h1 : h0;  h1 = adv ? h2 : h1;  h2 = adv ? h3 : h2;
            h3 = adv ? h4 : h3;  h4 = adv ? h5 : h4;  h5 = adv ? h6 : h5;
            h6 = adv ? h7 : h6;  h7 = adv ? ~0ull : h7;
            if (__any(needScan)) {
                if (needScan) {
                    float bv = FLT_MAX; int bs = 0; bool found = false;
                    #pragma unroll
                    for (int s = 0; s < 32; ++s) {
                        bool ok = !((sel >> s) & 1u);
                        bool lt = ok && (d[s] < bv);
                        bv = lt ? d[s] : bv; bs = lt ? s : bs; found |= ok;
                    }
                    h0 = found
                       ? (((unsigned long long)__builtin_bit_cast(unsigned, bv) << 32)
                          | (unsigned)((bs >> 2) * 256 + lane * 4 + (bs & 3)))
                       : ~0ull;
                }
            }
        }
    }

    // ---- Phase 3: boundary-gap guard (exact fp32 recompute for the window) ----
    if (d33v - d32v < MARGIN) {
        float lo = d32v - MARGIN, hi = d33v + MARGIN;
        unsigned cand = 0;
        #pragma unroll
        for (int s = 0; s < 32; ++s)
            if (d[s] >= lo && d[s] <= hi) cand |= 1u << s;

        const unsigned short* qrow = q_s + (long)g * K2;
        const u16x4* qh = (const u16x4*)&qrow[lane * 12];
        const u16x4* ql = (const u16x4*)&qrow[DD + lane * 12];
        #pragma unroll
        for (int s = 0; s < 32; ++s) {
            unsigned long long m = __ballot((cand >> s) & 1u);
            while (m) {
                int l2 = __ffsll(m) - 1;
                m &= m - 1;
                int j = (s >> 2) * 256 + l2 * 4 + (s & 3);
                const unsigned short* krow = k_s + ((long)b * SS + j) * K2;
                const u16x4* kh = (const u16x4*)&krow[lane * 12];
                const u16x4* kl = (const u16x4*)&krow[2 * DD + lane * 12];
                float part = 0.f;
                #pragma unroll
                for (int c = 0; c < 3; ++c) {
                    u16x4 qa = qh[c], qb = ql[c], ka = kh[c], kb2 = kl[c];
                    #pragma unroll
                    for (int e = 0; e < 4; ++e) {
                        float qv = f16f(qa[e]) + f16f(qb[e]) * 0.015625f;
                        float kv = f16f(ka[e]) + f16f(kb2[e]) * 0.015625f;
                        part = fmaf(qv, kv, part);
                    }
                }
                #pragma unroll
                for (int off = 32; off; off >>= 1) part += __shfl_xor(part, off);
                float dd = qn[g] + kn[(long)b * SS + j] - 2.f * part;
                dd = fmaxf(dd, 0.f);
                if (lane == l2) d[s] = dd;
            }
        }

        sel &= ~cand;
        int C = 0;
        #pragma unroll
        for (int s = 0; s < 32; ++s) C += (int)__popcll(__ballot((sel >> s) & 1u));
        int need = KNEI - C;
        for (int t = 0; t < need; ++t) {
            unsigned long long best = ~0ull;
            #pragma unroll
            for (int s = 0; s < 32; ++s) {
                if (((cand >> s) & 1u) && !((sel >> s) & 1u)) {
                    unsigned long long key =
                        ((unsigned long long)__builtin_bit_cast(unsigned, d[s]) << 32)
                        | (unsigned)((s >> 2) * 256 + lane * 4 + (s & 3));
                    best = key < best ? key : best;
                }
            }
            #pragma unroll
            for (int off = 32; off; off >>= 1) {
                unsigned long long o = __shfl_xor(best, off);
                best = o < best ? o : best;
            }
            if (best != ~0ull) {
                int j = (int)(unsigned)best;
                if (lane == ((j >> 2) & 63)) sel |= 1u << (((j >> 8) << 2) | (j & 3));
            }
        }
    }

    // ---- Phase 4: gather-mean of bf16 v, write split topo (A-layout) ----
    f32x4 a0 = {0.f, 0.f, 0.f, 0.f}, a1 = a0, a2 = a0;
    #pragma unroll
    for (int s = 0; s < 32; ++s) {
        unsigned long long m = __ballot((sel >> s) & 1u);
        while (m) {
            int l2 = __ffsll(m) - 1;
            m &= m - 1;
            int j = (s >> 2) * 256 + l2 * 4 + (s & 3);
            const u16x4* vr = (const u16x4*)(vb + (long)j * DD);
            u16x4 r0 = vr[lane], r1 = vr[lane + 64], r2 = vr[lane + 128];
            #pragma unroll
            for (int e = 0; e < 4; ++e) {
                a0[e] += bf16f(r0[e]);
                a1[e] += bf16f(r1[e]);
                a2[e] += bf16f(r2[e]);
            }
        }
    }
    const float sc = 1.0f / 32.0f;
    unsigned short* trow = topo_s + (long)g * K2;
    #pragma unroll
    for (int c = 0; c < 3; ++c) {
        f32x4 x = (c == 0) ? a0 : (c == 1) ? a1 : a2;
        u16x4 hi, ls, hs2;
        #pragma unroll
        for (int e = 0; e < 4; ++e) {
            float xv = x[e] * sc;
            _Float16 hh = (_Float16)xv;
            float hf = (float)hh;
            float l = xv - hf;
            hi[e]  = __builtin_bit_cast(unsigned short, hh);
            ls[e]  = ff16(l * 64.f);
            hs2[e] = ff16(hf * 0.015625f);
        }
        *(u16x4*)&trow[c * 256 + lane * 4]            = hi;
        *(u16x4*)&trow[DD + c * 256 + lane * 4]       = ls;
        *(u16x4*)&trow[2 * DD + c * 256 + lane * 4]   = hs2;
    }
}

extern "C" void kernel_launch(void* const* d_in, const int* in_sizes, int n_in,
                              void* d_out, int out_size, void* d_ws, size_t ws_size,
                              hipStream_t stream)
{
    const float* hs = (const float*)d_in[0];
    const float* Wq = (const float*)d_in[1];
    const float* bq = (const float*)d_in[2];
    const float* Wk = (const float*)d_in[3];
    const float* bk = (const float*)d_in[4];
    const float* Wv = (const float*)d_in[5];
    const float* bv = (const float*)d_in[6];
    const float* W1 = (const float*)d_in[7];
    const float* b1 = (const float*)d_in[8];
    const float* W2 = (const float*)d_in[9];
    const float* b2 = (const float*)d_in[10];
    float* out = (float*)d_out;

    // ---- workspace layout (peak ~204 MB), time-overlaid ----
    char* w = (char*)d_ws;
    const long DISTB = (long)BB * SS * SS * 4;        // 67,108,864
    const long VB    = (long)BSR * DD * 2;            // 12,582,912 (bf16 v)
    const long SPLB  = (long)BSR * K2 * 2;            // 37,748,736
    const long WSPL  = (long)DD * K2;                 // elems per split weight

    float*          dist   = (float*)w;                               // [0, 67.1M)
    unsigned short* h_s    = (unsigned short*)w;                      // overlays dead dist
    unsigned short* v      = (unsigned short*)(w + DISTB);            // bf16 v
    unsigned short* q_s    = (unsigned short*)(w + DISTB + VB);
    unsigned short* k_s    = q_s + SPLB / 2;
    unsigned short* hs_s   = k_s + SPLB / 2;
    unsigned short* topo_s = hs_s;                                    // overlays dead hs_s
    unsigned short* Wqkv_s = hs_s + SPLB / 2;                         // 3 weight splits adjacent
    unsigned short* W1_s   = Wqkv_s;                                  // overlays dead Wqkv after qkv gemm
    unsigned short* W2_s   = Wqkv_s + WSPL;
    char* tail  = (char*)(Wqkv_s + 3 * WSPL);
    float* qn   = (float*)tail;                        // 8192
    float* kn   = qn + BSR;                            // 8192
    float* pn   = kn + BSR;                            // qnp[8192][12] + knp[8192][12]
    float* bqkv = pn + (long)2 * BSR * 12;             // 2304

    dim3 blk(256);
    const int convW  = (DD * (DD / 8)) / 256;          // 288 blocks per weight
    const int convHS = (BSR * (DD / 8)) / 256;         // 3072 blocks

    concat_bias<<<9, blk, 0, stream>>>(bq, bk, bv, bqkv);
    split_f16<2><<<convW, blk, 0, stream>>>(Wq, Wqkv_s, DD);
    split_f16<2><<<convW, blk, 0, stream>>>(Wk, Wqkv_s + WSPL, DD);
    split_f16<2><<<convW, blk, 0, stream>>>(Wv, Wqkv_s + 2 * WSPL, DD);
    split_f16<1><<<convHS, blk, 0, stream>>>(hs, hs_s, DD);

    // fused QKV gemm: q->split-A + norms, k->split-B + norms, v->bf16
    gemm_mfma<4><<<dim3(2304 / 128, BSR / 128, 1), blk, 0, stream>>>(
        hs_s, Wqkv_s, bqkv, nullptr, BSR, 2304, K2,
        q_s, k_s, v, pn);

    // W1/W2 splits into dead Wqkv region
    split_f16<2><<<convW, blk, 0, stream>>>(W1, W1_s, DD);
    split_f16<2><<<convW, blk, 0, stream>>>(W2, W2_s, DD);
    finish_norms<<<(2 * BSR) / 256, blk, 0, stream>>>(pn, qn, kn);

    // squared distance matrix per batch: single-term f16 (Kd=768, stride K2)
    gemm256_dist<<<dim3(SS / 256, SS / 256, BB), dim3(512), 0, stream>>>(
        q_s, k_s, qn, kn, dist, SS, DD, K2, K2,
        (long)SS * K2, (long)SS * K2, (long)SS * SS, SS);

    select_mean<<<BSR / 4, blk, 0, stream>>>(dist, v, q_s, k_s, qn, kn, topo_s);

    // MLP: gemm1 writes split-A h_s directly (relu fused)
    gemm_mfma<3><<<dim3(DD / 128, BSR / 128, 1), blk, 0, stream>>>(
        topo_s, W1_s, b1, nullptr, BSR, DD, K2,
        h_s, nullptr, nullptr, nullptr);
    gemm_mfma<0><<<dim3(DD / 128, BSR / 128, 1), blk, 0, stream>>>(
        h_s, W2_s, b2, out, BSR, DD, K2,
        nullptr, nullptr, nullptr, nullptr);
}

// Round 12
// 327.508 us; speedup vs baseline: 3.8243x; 1.0436x over previous
//
#include <hip/hip_runtime.h>
#include <float.h>

#define DD 768
#define SS 2048
#define BB 4
#define BSR (BB*SS)   // 8192 total rows
#define KNEI 32
#define K2 (3*DD)     // 2304: [hi | x | y] split concat along K
#define MARGIN 0.12f  // >=6 sigma of single-term f16 pairwise dist error

typedef __attribute__((ext_vector_type(8))) _Float16 f16x8;
typedef __attribute__((ext_vector_type(4))) float f32x4;
typedef __attribute__((ext_vector_type(8))) unsigned short u16x8;
typedef __attribute__((ext_vector_type(4))) unsigned short u16x4;

__device__ __forceinline__ float f16f(unsigned short u) {
    return (float)__builtin_bit_cast(_Float16, u);
}
__device__ __forceinline__ unsigned short ff16(float x) {
    return __builtin_bit_cast(unsigned short, (_Float16)x);
}
__device__ __forceinline__ unsigned short rne_bf16(float x) {
    unsigned u = __builtin_bit_cast(unsigned, x);
    unsigned r = u + 0x7FFFu + ((u >> 16) & 1u);
    return (unsigned short)(r >> 16);
}
__device__ __forceinline__ float bf16f(unsigned short h) {
    return __builtin_bit_cast(float, (unsigned)h << 16);
}

__device__ __forceinline__ void gload_lds16(const void* g, void* l) {
    __builtin_amdgcn_global_load_lds(
        (const __attribute__((address_space(1))) unsigned int*)g,
        (__attribute__((address_space(3))) unsigned int*)l, 16, 0, 0);
}

// fp32 -> 3-slot f16 split with power-of-2 rebalanced correction slots.
// A-layout (LO_SLOT=1): [h, l*2^6, h*2^-6];  B-layout (LO_SLOT=2): [h, h*2^-6, l*2^6]
template<int LO_SLOT>
__global__ __launch_bounds__(256)
void split_f16(const float* __restrict__ in, unsigned short* __restrict__ out, int Kc)
{
    int idx = blockIdx.x * 256 + threadIdx.x;
    int perRow = Kc >> 3;
    int row = idx / perRow, c8 = idx - row * perRow;
    const float* src = in + (long)row * Kc + c8 * 8;
    f32x4 x0 = *(const f32x4*)&src[0];
    f32x4 x1 = *(const f32x4*)&src[4];
    u16x8 hi, lsc, hsc;
    #pragma unroll
    for (int e = 0; e < 8; ++e) {
        float xv = (e < 4) ? x0[e] : x1[e - 4];
        _Float16 h = (_Float16)xv;
        float hf = (float)h;
        float l = xv - hf;
        hi[e]  = __builtin_bit_cast(unsigned short, h);
        lsc[e] = ff16(l * 64.f);
        hsc[e] = ff16(hf * 0.015625f);
    }
    long base = (long)row * (3 * Kc) + c8 * 8;
    *(u16x8*)&out[base] = hi;
    *(u16x8*)&out[base + Kc]     = (LO_SLOT == 1) ? lsc : hsc;
    *(u16x8*)&out[base + 2 * Kc] = (LO_SLOT == 1) ? hsc : lsc;
}

__global__ __launch_bounds__(256)
void concat_bias(const float* __restrict__ bq, const float* __restrict__ bk,
                 const float* __restrict__ bv, float* __restrict__ bqkv)
{
    int i = blockIdx.x * 256 + threadIdx.x;
    if (i < 768) bqkv[i] = bq[i];
    else if (i < 1536) bqkv[i] = bk[i - 768];
    else if (i < 2304) bqkv[i] = bv[i - 1536];
}

// pn rows: qnp[8192][12] then knp[8192][12] contiguous; fixed-order sum.
__global__ __launch_bounds__(256)
void finish_norms(const float* __restrict__ pn, float* __restrict__ qn, float* __restrict__ kn)
{
    int row = blockIdx.x * 256 + threadIdx.x;   // 0..16383
    const float* p = pn + (long)row * 12;
    float s = 0.f;
    #pragma unroll
    for (int c = 0; c < 12; ++c) s += p[c];
    if (row < BSR) qn[row] = s; else kn[row - BSR] = s;
}

// ---------------------------------------------------------------------------
// 256x256-tile pipelined distance GEMM (counted-vmcnt, raw barriers).
// Single-term f16: Kd=768 (hi slots only), row stride lda/ldb = K2.
// ---------------------------------------------------------------------------
__global__ __launch_bounds__(512)
void gemm256_dist(const unsigned short* __restrict__ A, const unsigned short* __restrict__ B,
                  const float* __restrict__ rm, const float* __restrict__ rn,
                  float* __restrict__ C,
                  int N, int Kd, long lda, long ldb,
                  long sA, long sB, long sC, long sR)
{
    const int z = blockIdx.z;
    A += (long)z * sA;
    B += (long)z * sB;
    C += (long)z * sC;
    const float* rmz = rm + (long)z * sR;
    const float* rnz = rn + (long)z * sR;

    // bijective XCD swizzle over the 64 blocks of this batch
    int lid = blockIdx.y * gridDim.x + blockIdx.x;
    int xcd = lid & 7, pos = lid >> 3;
    int nlid = xcd * 8 + pos;
    const int bx = nlid & 7, by = nlid >> 3;

    __shared__ __align__(16) unsigned short lds[2 * 32768];  // 2 bufs x (A 16384 | B 16384) f16

    const int tid = threadIdx.x;
    const int lane = tid & 63;
    const int wave = tid >> 6;
    const int wm = wave >> 2, wn = wave & 3;   // 2 x 4 wave grid
    const int m0 = by * 256, n0 = bx * 256;
    const int r15 = lane & 15;
    const int g4 = lane >> 4;

    f32x4 acc[8][4] = {};

    long aB[4], bB[4];
    int lof[4];
    #pragma unroll
    for (int i = 0; i < 4; ++i) {
        int L = i * 512 + tid;          // 0..2047 chunk id (16B chunks)
        int row = L >> 3, ch = L & 7;
        int chs = ch ^ (row & 7);
        aB[i] = (long)(m0 + row) * lda * 2 + chs * 16;
        bB[i] = (long)(n0 + row) * ldb * 2 + chs * 16;
        lof[i] = L * 8;
    }

    const int NT = Kd >> 6;             // 12 K-tiles of 64

    // prologue: stage tile 0 into buf 0
    #pragma unroll
    for (int i = 0; i < 4; ++i) {
        gload_lds16((const char*)A + aB[i], &lds[lof[i]]);
        gload_lds16((const char*)B + bB[i], &lds[16384 + lof[i]]);
    }

    int cur = 0;
    for (int t = 0; t < NT; ++t) {
        if (t + 1 < NT) {
            long kb = (long)(t + 1) * 128;
            int off = (cur ^ 1) * 32768;
            #pragma unroll
            for (int i = 0; i < 4; ++i) {
                gload_lds16((const char*)A + aB[i] + kb, &lds[off + lof[i]]);
                gload_lds16((const char*)B + bB[i] + kb, &lds[off + 16384 + lof[i]]);
            }
            asm volatile("s_waitcnt vmcnt(8)" ::: "memory");
        } else {
            asm volatile("s_waitcnt vmcnt(0)" ::: "memory");
        }
        __builtin_amdgcn_s_barrier();
        __builtin_amdgcn_sched_barrier(0);

        const unsigned short* bufA = &lds[cur * 32768];
        const unsigned short* bufB = bufA + 16384;
        #pragma unroll
        for (int ks = 0; ks < 2; ++ks) {
            f16x8 af[8], bfr[4];
            #pragma unroll
            for (int i = 0; i < 8; ++i) {
                int r = wm * 128 + i * 16 + r15;
                int g = ks * 4 + g4;
                af[i] = *(const f16x8*)&bufA[r * 64 + (g ^ (r & 7)) * 8];
            }
            #pragma unroll
            for (int j = 0; j < 4; ++j) {
                int c = wn * 64 + j * 16 + r15;
                int g = ks * 4 + g4;
                bfr[j] = *(const f16x8*)&bufB[c * 64 + (g ^ (c & 7)) * 8];
            }
            #pragma unroll
            for (int i = 0; i < 8; ++i)
                #pragma unroll
                for (int j = 0; j < 4; ++j)
                    acc[i][j] = __builtin_amdgcn_mfma_f32_16x16x32_f16(
                        af[i], bfr[j], acc[i][j], 0, 0, 0);
        }
        __builtin_amdgcn_sched_barrier(0);
        __builtin_amdgcn_s_barrier();
        cur ^= 1;
    }

    // epilogue: C/D layout col=lane&15, row=(lane>>4)*4+reg
    float rnv[4];
    #pragma unroll
    for (int j = 0; j < 4; ++j)
        rnv[j] = rnz[n0 + wn * 64 + j * 16 + r15];
    #pragma unroll
    for (int i = 0; i < 8; ++i) {
        #pragma unroll
        for (int r = 0; r < 4; ++r) {
            int m = m0 + wm * 128 + i * 16 + g4 * 4 + r;
            float rmv = rmz[m];
            #pragma unroll
            for (int j = 0; j < 4; ++j) {
                int n = n0 + wn * 64 + j * 16 + r15;
                C[(long)m * N + n] = rmv + rnv[j] - 2.f * acc[i][j][r];
            }
        }
    }
}

// C[m][n] = epilogue( sum_k A[m][k]*B[n][k] ), NT, f16 3-term split inputs.
// Pipelined double-buffer schedule (counted vmcnt + raw barriers).
// MODE 0: +bias[n] -> f32 C
// MODE 3: relu(+bias[n]) -> split-A u16 oQ
// MODE 4: combined QKV: seg 0 -> split-A oQ + qnp; 1 -> split-B oK + knp;
//         2 -> bf16 oV with SINGLE-TERM K=768 (hi slots only; v error << bf16 quant)
template<int MODE>
__global__ __launch_bounds__(256)
void gemm_mfma(const unsigned short* __restrict__ A, const unsigned short* __restrict__ B,
               const float* __restrict__ bias,
               float* __restrict__ C,
               int M, int N, int Kd,
               unsigned short* __restrict__ oQ, unsigned short* __restrict__ oK,
               unsigned short* __restrict__ oV, float* __restrict__ pn)
{
    // ---- bijective XCD swizzle (T1/m204) ----
    const int nwgx = gridDim.x;
    const int nwg  = nwgx * gridDim.y;
    int lid = blockIdx.y * nwgx + blockIdx.x;
    int qq = nwg >> 3, rr = nwg & 7;
    int xcd = lid & 7, pos = lid >> 3;
    int nlid = (xcd < rr ? xcd * (qq + 1) : rr * (qq + 1) + (xcd - rr) * qq) + pos;
    const int bx = nlid % nwgx;
    const int by = nlid / nwgx;

    __shared__ __align__(16) unsigned short lds[2 * 16384];  // 2 bufs x (A 8192 | B 8192)

    const int tid = threadIdx.x;
    const int lane = tid & 63;
    const int wave = tid >> 6;
    const int wm = wave >> 1, wn = wave & 1;
    const int m0 = by * 128, n0 = bx * 128;
    const int r15 = lane & 15;
    const int g4 = lane >> 4;

    f32x4 acc[4][4] = {};

    long aByte[4], bByte[4];
    int ldsOff[4];
    #pragma unroll
    for (int i = 0; i < 4; ++i) {
        int L = i * 256 + tid;
        int row = L >> 3, ch = L & 7;
        int chs = ch ^ (row & 7);
        aByte[i] = (long)(m0 + row) * Kd * 2 + chs * 16;
        bByte[i] = (long)(n0 + row) * Kd * 2 + chs * 16;
        ldsOff[i] = L * 8;
    }

    int NT = Kd >> 6;                          // 36 (or 12 for v segment below)
    if (MODE == 4 && n0 >= 1536) NT = 12;      // v: single-term f16 (hi slots only)

    // prologue: stage tile 0 into buf 0
    #pragma unroll
    for (int i = 0; i < 4; ++i) {
        gload_lds16((const char*)A + aByte[i], &lds[ldsOff[i]]);
        gload_lds16((const char*)B + bByte[i], &lds[8192 + ldsOff[i]]);
    }

    int cur = 0;
    for (int t = 0; t < NT; ++t) {
        if (t + 1 < NT) {
            long kb = (long)(t + 1) * 128;
            int off = (cur ^ 1) * 16384;
            #pragma unroll
            for (int i = 0; i < 4; ++i) {
                gload_lds16((const char*)A + aByte[i] + kb, &lds[off + ldsOff[i]]);
                gload_lds16((const char*)B + bByte[i] + kb, &lds[off + 8192 + ldsOff[i]]);
            }
            asm volatile("s_waitcnt vmcnt(8)" ::: "memory");
        } else {
            asm volatile("s_waitcnt vmcnt(0)" ::: "memory");
        }
        __builtin_amdgcn_s_barrier();
        __builtin_amdgcn_sched_barrier(0);

        const unsigned short* bufA = &lds[cur * 16384];
        const unsigned short* bufB = bufA + 8192;
        #pragma unroll
        for (int ks = 0; ks < 2; ++ks) {
            f16x8 af[4], bfr[4];
            #pragma unroll
            for (int i = 0; i < 4; ++i) {
                int row = wm * 64 + i * 16 + r15;
                int chs = (ks * 4 + g4) ^ (r15 & 7);
                af[i] = *(const f16x8*)&bufA[row * 64 + chs * 8];
            }
            #pragma unroll
            for (int j = 0; j < 4; ++j) {
                int row = wn * 64 + j * 16 + r15;
                int chs = (ks * 4 + g4) ^ (r15 & 7);
                bfr[j] = *(const f16x8*)&bufB[row * 64 + chs * 8];
            }
            #pragma unroll
            for (int i = 0; i < 4; ++i)
                #pragma unroll
                for (int j = 0; j < 4; ++j)
                    acc[i][j] = __builtin_amdgcn_mfma_f32_16x16x32_f16(
                        af[i], bfr[j], acc[i][j], 0, 0, 0);
        }
        __builtin_amdgcn_sched_barrier(0);
        __builtin_amdgcn_s_barrier();
        cur ^= 1;
    }

    float bj[4];
    #pragma unroll
    for (int j = 0; j < 4; ++j) {
        int n = n0 + wn * 64 + j * 16 + r15;
        bj[j] = bias[n];
    }

    if (MODE == 0) {
        #pragma unroll
        for (int i = 0; i < 4; ++i) {
            #pragma unroll
            for (int r = 0; r < 4; ++r) {
                int m = m0 + wm * 64 + i * 16 + g4 * 4 + r;
                #pragma unroll
                for (int j = 0; j < 4; ++j) {
                    int n = n0 + wn * 64 + j * 16 + r15;
                    C[(long)m * N + n] = acc[i][j][r] + bj[j];
                }
            }
        }
    }

    if (MODE == 3) {
        #pragma unroll
        for (int i = 0; i < 4; ++i) {
            #pragma unroll
            for (int r = 0; r < 4; ++r) {
                int m = m0 + wm * 64 + i * 16 + g4 * 4 + r;
                #pragma unroll
                for (int j = 0; j < 4; ++j) {
                    int e = n0 + wn * 64 + j * 16 + r15;
                    float xv = fmaxf(acc[i][j][r] + bj[j], 0.f);
                    _Float16 hh = (_Float16)xv;
                    float hf = (float)hh;
                    float l = xv - hf;
                    long base = (long)m * K2 + e;
                    oQ[base]          = __builtin_bit_cast(unsigned short, hh);
                    oQ[base + DD]     = ff16(l * 64.f);
                    oQ[base + 2 * DD] = ff16(hf * 0.015625f);
                }
            }
        }
    }

    if (MODE == 4) {
        const int seg = n0 / 768;                       // block-uniform: 0=q 1=k 2=v
        const int e0 = n0 - seg * 768 + wn * 64;
        const int chunk = (bx - seg * 6) * 2 + wn;      // 0..11 within segment
        #pragma unroll
        for (int i = 0; i < 4; ++i) {
            #pragma unroll
            for (int r = 0; r < 4; ++r) {
                int m = m0 + wm * 64 + i * 16 + g4 * 4 + r;
                float vals[4];
                #pragma unroll
                for (int j = 0; j < 4; ++j) vals[j] = acc[i][j][r] + bj[j];
                if (seg == 2) {
                    #pragma unroll
                    for (int j = 0; j < 4; ++j)
                        oV[(long)m * DD + e0 + j * 16 + r15] = rne_bf16(vals[j]);
                } else {
                    unsigned short* os = (seg == 0) ? oQ : oK;
                    #pragma unroll
                    for (int j = 0; j < 4; ++j) {
                        float xv = vals[j];
                        _Float16 hh = (_Float16)xv;
                        float hf = (float)hh;
                        float l = xv - hf;
                        long base = (long)m * K2 + e0 + j * 16 + r15;
                        os[base] = __builtin_bit_cast(unsigned short, hh);
                        os[base + ((seg == 0) ? DD : 2 * DD)] = ff16(l * 64.f);
                        os[base + ((seg == 0) ? 2 * DD : DD)] = ff16(hf * 0.015625f);
                    }
                    float s = vals[0]*vals[0] + vals[1]*vals[1]
                            + vals[2]*vals[2] + vals[3]*vals[3];
                    s += __shfl_xor(s, 1); s += __shfl_xor(s, 2);
                    s += __shfl_xor(s, 4); s += __shfl_xor(s, 8);
                    if (r15 == 0)
                        pn[(seg ? (long)BSR * 12 : 0) + (long)m * 12 + chunk] = s;
                }
            }
        }
    }
}

// One WAVE per query row, zero LDS, zero barriers.
// Phase 1: streaming branchless insertion top-8 per lane (sorted u64 keys).
// Phase 2: threshold selection (ballot binary search) + exact tie-break;
//          wave-uniform fallback to 33-iteration tournament on saturation.
// Phase 3: boundary-gap guard (exact fp32 recompute from splits).
// Phase 4: rank-based index assignment (lane p -> p-th selected index) then
//          fully-unrolled pipelined gather; order matches old ffsll order.
// Element j of the row lives at slot s, lane l: j = (s>>2)*256 + l*4 + (s&3)
__global__ __launch_bounds__(256)
void select_mean(const float* __restrict__ dist, const unsigned short* __restrict__ v,
                 const unsigned short* __restrict__ q_s, const unsigned short* __restrict__ k_s,
                 const float* __restrict__ qn, const float* __restrict__ kn,
                 unsigned short* __restrict__ topo_s)
{
    const int wv = threadIdx.x >> 6;
    const int lane = threadIdx.x & 63;
    const int g = blockIdx.x * 4 + wv;      // global row 0..8191
    const int b = g >> 11;
    const float* drow = dist + (long)b * SS * SS + (long)(g & (SS - 1)) * SS;
    const unsigned short* vb = v + (long)b * SS * DD;

    float d[32];
    unsigned long long h0 = ~0ull, h1 = ~0ull, h2 = ~0ull, h3 = ~0ull,
                       h4 = ~0ull, h5 = ~0ull, h6 = ~0ull, h7 = ~0ull;
    const f32x4* dr4 = (const f32x4*)drow;
    #pragma unroll
    for (int c = 0; c < 8; ++c) {
        f32x4 tv = dr4[c * 64 + lane];
        #pragma unroll
        for (int i = 0; i < 4; ++i) {
            float x = fmaxf(tv[i], 0.f);
            d[c * 4 + i] = x;
            unsigned long long kk =
                ((unsigned long long)__builtin_bit_cast(unsigned, x) << 32)
                | (unsigned)(c * 256 + lane * 4 + i);
            if (kk < h7) {                  // branchless sorted insert
                bool l6 = kk < h6, l5 = kk < h5, l4 = kk < h4, l3 = kk < h3,
                     l2 = kk < h2, l1 = kk < h1, l0 = kk < h0;
                h7 = l6 ? h6 : kk;
                h6 = l6 ? (l5 ? h5 : kk) : h6;
                h5 = l5 ? (l4 ? h4 : kk) : h5;
                h4 = l4 ? (l3 ? h3 : kk) : h4;
                h3 = l3 ? (l2 ? h2 : kk) : h3;
                h2 = l2 ? (l1 ? h1 : kk) : h2;
                h1 = l1 ? (l0 ? h0 : kk) : h1;
                h0 = l0 ? kk : h0;
            }
        }
    }

    unsigned sel = 0;
    float d32v = 0.f, d33v = 0.f;

    // ---- Phase 2: threshold selection via value-bit binary search ----
    unsigned Vv = 0;
    for (int bit = 31; bit >= 0; --bit) {
        unsigned candv = Vv | (1u << bit);
        int cntv = 0;
        cntv += (int)__popcll(__ballot((unsigned)(h0 >> 32) < candv));
        cntv += (int)__popcll(__ballot((unsigned)(h1 >> 32) < candv));
        cntv += (int)__popcll(__ballot((unsigned)(h2 >> 32) < candv));
        cntv += (int)__popcll(__ballot((unsigned)(h3 >> 32) < candv));
        cntv += (int)__popcll(__ballot((unsigned)(h4 >> 32) < candv));
        cntv += (int)__popcll(__ballot((unsigned)(h5 >> 32) < candv));
        cntv += (int)__popcll(__ballot((unsigned)(h6 >> 32) < candv));
        cntv += (int)__popcll(__ballot((unsigned)(h7 >> 32) < candv));
        if (cntv <= 31) Vv = candv;
    }
    bool fallback = __any((unsigned)(h7 >> 32) <= Vv);

    if (!fallback) {
        int c_lt = 0;
        c_lt += (int)__popcll(__ballot((unsigned)(h0 >> 32) < Vv));
        c_lt += (int)__popcll(__ballot((unsigned)(h1 >> 32) < Vv));
        c_lt += (int)__popcll(__ballot((unsigned)(h2 >> 32) < Vv));
        c_lt += (int)__popcll(__ballot((unsigned)(h3 >> 32) < Vv));
        c_lt += (int)__popcll(__ballot((unsigned)(h4 >> 32) < Vv));
        c_lt += (int)__popcll(__ballot((unsigned)(h5 >> 32) < Vv));
        c_lt += (int)__popcll(__ballot((unsigned)(h6 >> 32) < Vv));
        c_lt += (int)__popcll(__ballot((unsigned)(h7 >> 32) < Vv));
        #pragma unroll
        for (int s = 0; s < 32; ++s)
            if (__builtin_bit_cast(unsigned, d[s]) < Vv) sel |= 1u << s;
        int need = KNEI - c_lt;
        for (int t2 = 0; t2 < need; ++t2) {
            unsigned mi = 0xffffffffu;
            #pragma unroll
            for (int s = 0; s < 32; ++s) {
                bool eq = (__builtin_bit_cast(unsigned, d[s]) == Vv) && !((sel >> s) & 1u);
                unsigned jj = (unsigned)((s >> 2) * 256 + lane * 4 + (s & 3));
                if (eq && jj < mi) mi = jj;
            }
            #pragma unroll
            for (int off = 32; off; off >>= 1) {
                unsigned o = __shfl_xor(mi, off);
                mi = o < mi ? o : mi;
            }
            if (mi != 0xffffffffu && lane == ((mi >> 2) & 63))
                sel |= 1u << (((mi >> 8) << 2) | (mi & 3));
        }
        d32v = __builtin_bit_cast(float, Vv);
        int c_le = 0;
        c_le += (int)__popcll(__ballot((unsigned)(h0 >> 32) <= Vv));
        c_le += (int)__popcll(__ballot((unsigned)(h1 >> 32) <= Vv));
        c_le += (int)__popcll(__ballot((unsigned)(h2 >> 32) <= Vv));
        c_le += (int)__popcll(__ballot((unsigned)(h3 >> 32) <= Vv));
        c_le += (int)__popcll(__ballot((unsigned)(h4 >> 32) <= Vv));
        c_le += (int)__popcll(__ballot((unsigned)(h5 >> 32) <= Vv));
        c_le += (int)__popcll(__ballot((unsigned)(h6 >> 32) <= Vv));
        c_le += (int)__popcll(__ballot((unsigned)(h7 >> 32) <= Vv));
        if (c_le >= 33) {
            d33v = d32v;
        } else {
            unsigned mv = 0xffffffffu;
            { unsigned hv = (unsigned)(h0 >> 32); if (hv > Vv && hv < mv) mv = hv; }
            { unsigned hv = (unsigned)(h1 >> 32); if (hv > Vv && hv < mv) mv = hv; }
            { unsigned hv = (unsigned)(h2 >> 32); if (hv > Vv && hv < mv) mv = hv; }
            { unsigned hv = (unsigned)(h3 >> 32); if (hv > Vv && hv < mv) mv = hv; }
            { unsigned hv = (unsigned)(h4 >> 32); if (hv > Vv && hv < mv) mv = hv; }
            { unsigned hv = (unsigned)(h5 >> 32); if (hv > Vv && hv < mv) mv = hv; }
            { unsigned hv = (unsigned)(h6 >> 32); if (hv > Vv && hv < mv) mv = hv; }
            { unsigned hv = (unsigned)(h7 >> 32); if (hv > Vv && hv < mv) mv = hv; }
            #pragma unroll
            for (int off = 32; off; off >>= 1) {
                unsigned o = __shfl_xor(mv, off);
                mv = o < mv ? o : mv;
            }
            d33v = __builtin_bit_cast(float, mv);
        }
    } else {
        // ---- proven 33-iteration tournament path (rare) ----
        int cnt = 0;
        for (int t = 0; t < 33; ++t) {
            unsigned long long best = h0;
            #pragma unroll
            for (int off = 32; off; off >>= 1) {
                unsigned long long o = __shfl_xor(best, off);
                best = o < best ? o : best;
            }
            if (t == 32) {
                d33v = __builtin_bit_cast(float, (unsigned)(best >> 32));
                break;
            }
            int j = (int)(unsigned)best;
            bool won = (lane == ((j >> 2) & 63));
            if (won) sel |= 1u << (((j >> 8) << 2) | (j & 3));
            if (t == 31) d32v = __builtin_bit_cast(float, (unsigned)(best >> 32));

            if (won) cnt++;
            bool needScan = won && (cnt >= 8);
            bool adv = won && (cnt < 8);
            h0 = adv ? h1 : h0;  h1 = adv ? h2 : h1;  h2 = adv ? h3 : h2;
            h3 = adv ? h4 : h3;  h4 = adv ? h5 : h4;  h5 = adv ? h6 : h5;
            h6 = adv ? h7 : h6;  h7 = adv ? ~0ull : h7;
            if (__any(needScan)) {
                if (needScan) {
                    float bv = FLT_MAX; int bs = 0; bool found = false;
                    #pragma unroll
                    for (int s = 0; s < 32; ++s) {
                        bool ok = !((sel >> s) & 1u);
                        bool lt = ok && (d[s] < bv);
                        bv = lt ? d[s] : bv; bs = lt ? s : bs; found |= ok;
                    }
                    h0 = found
                       ? (((unsigned long long)__builtin_bit_cast(unsigned, bv) << 32)
                          | (unsigned)((bs >> 2) * 256 + lane * 4 + (bs & 3)))
                       : ~0ull;
                }
            }
        }
    }

    // ---- Phase 3: boundary-gap guard (exact fp32 recompute for the window) ----
    if (d33v - d32v < MARGIN) {
        float lo = d32v - MARGIN, hi = d33v + MARGIN;
        unsigned cand = 0;
        #pragma unroll
        for (int s = 0; s < 32; ++s)
            if (d[s] >= lo && d[s] <= hi) cand |= 1u << s;

        const unsigned short* qrow = q_s + (long)g * K2;
        const u16x4* qh = (const u16x4*)&qrow[lane * 12];
        const u16x4* ql = (const u16x4*)&qrow[DD + lane * 12];
        #pragma unroll
        for (int s = 0; s < 32; ++s) {
            unsigned long long m = __ballot((cand >> s) & 1u);
            while (m) {
                int l2 = __ffsll(m) - 1;
                m &= m - 1;
                int j = (s >> 2) * 256 + l2 * 4 + (s & 3);
                const unsigned short* krow = k_s + ((long)b * SS + j) * K2;
                const u16x4* kh = (const u16x4*)&krow[lane * 12];
                const u16x4* kl = (const u16x4*)&krow[2 * DD + lane * 12];
                float part = 0.f;
                #pragma unroll
                for (int c = 0; c < 3; ++c) {
                    u16x4 qa = qh[c], qb = ql[c], ka = kh[c], kb2 = kl[c];
                    #pragma unroll
                    for (int e = 0; e < 4; ++e) {
                        float qv = f16f(qa[e]) + f16f(qb[e]) * 0.015625f;
                        float kv = f16f(ka[e]) + f16f(kb2[e]) * 0.015625f;
                        part = fmaf(qv, kv, part);
                    }
                }
                #pragma unroll
                for (int off = 32; off; off >>= 1) part += __shfl_xor(part, off);
                float dd = qn[g] + kn[(long)b * SS + j] - 2.f * part;
                dd = fmaxf(dd, 0.f);
                if (lane == l2) d[s] = dd;
            }
        }

        sel &= ~cand;
        int C = 0;
        #pragma unroll
        for (int s = 0; s < 32; ++s) C += (int)__popcll(__ballot((sel >> s) & 1u));
        int need = KNEI - C;
        for (int t = 0; t < need; ++t) {
            unsigned long long best = ~0ull;
            #pragma unroll
            for (int s = 0; s < 32; ++s) {
                if (((cand >> s) & 1u) && !((sel >> s) & 1u)) {
                    unsigned long long key =
                        ((unsigned long long)__builtin_bit_cast(unsigned, d[s]) << 32)
                        | (unsigned)((s >> 2) * 256 + lane * 4 + (s & 3));
                    best = key < best ? key : best;
                }
            }
            #pragma unroll
            for (int off = 32; off; off >>= 1) {
                unsigned long long o = __shfl_xor(best, off);
                best = o < best ? o : best;
            }
            if (best != ~0ull) {
                int j = (int)(unsigned)best;
                if (lane == ((j >> 2) & 63)) sel |= 1u << (((j >> 8) << 2) | (j & 3));
            }
        }
    }

    // ---- Phase 4: rank-based selected-index assignment + pipelined gather ----
    int myj = 0;
    {
        int target = lane & 31;            // lane p (and p+32) own the p-th selected index
        int cum = 0;
        #pragma unroll
        for (int s = 0; s < 32; ++s) {
            unsigned long long m = __ballot((sel >> s) & 1u);
            int c = (int)__popcll(m);
            if (target >= cum && target < cum + c) {
                int nth = target - cum;
                unsigned long long mm = m;
                int base = 0;
                int c32 = (int)__popcll(mm & 0xffffffffull);
                if (nth >= c32) { nth -= c32; mm >>= 32; base += 32; }
                int c16 = (int)__popcll(mm & 0xffffull);
                if (nth >= c16) { nth -= c16; mm >>= 16; base += 16; }
                int c8 = (int)__popcll(mm & 0xffull);
                if (nth >= c8) { nth -= c8; mm >>= 8; base += 8; }
                int c4 = (int)__popcll(mm & 0xfull);
                if (nth >= c4) { nth -= c4; mm >>= 4; base += 4; }
                int c2 = (int)__popcll(mm & 0x3ull);
                if (nth >= c2) { nth -= c2; mm >>= 2; base += 2; }
                int c1 = (int)(mm & 1ull);
                if (nth >= c1) { base += 1; }
                myj = (s >> 2) * 256 + base * 4 + (s & 3);
            }
            cum += c;
        }
    }
    f32x4 a0 = {0.f, 0.f, 0.f, 0.f}, a1 = a0, a2 = a0;
    #pragma unroll
    for (int t = 0; t < KNEI; ++t) {
        int j = __shfl(myj, t);            // rank order == old (s asc, lane asc) order
        const u16x4* vr = (const u16x4*)(vb + (long)j * DD);
        u16x4 r0 = vr[lane], r1 = vr[lane + 64], r2 = vr[lane + 128];
        #pragma unroll
        for (int e = 0; e < 4; ++e) {
            a0[e] += bf16f(r0[e]);
            a1[e] += bf16f(r1[e]);
            a2[e] += bf16f(r2[e]);
        }
    }
    const float sc = 1.0f / 32.0f;
    unsigned short* trow = topo_s + (long)g * K2;
    #pragma unroll
    for (int c = 0; c < 3; ++c) {
        f32x4 x = (c == 0) ? a0 : (c == 1) ? a1 : a2;
        u16x4 hi, ls, hs2;
        #pragma unroll
        for (int e = 0; e < 4; ++e) {
            float xv = x[e] * sc;
            _Float16 hh = (_Float16)xv;
            float hf = (float)hh;
            float l = xv - hf;
            hi[e]  = __builtin_bit_cast(unsigned short, hh);
            ls[e]  = ff16(l * 64.f);
            hs2[e] = ff16(hf * 0.015625f);
        }
        *(u16x4*)&trow[c * 256 + lane * 4]            = hi;
        *(u16x4*)&trow[DD + c * 256 + lane * 4]       = ls;
        *(u16x4*)&trow[2 * DD + c * 256 + lane * 4]   = hs2;
    }
}

extern "C" void kernel_launch(void* const* d_in, const int* in_sizes, int n_in,
                              void* d_out, int out_size, void* d_ws, size_t ws_size,
                              hipStream_t stream)
{
    const float* hs = (const float*)d_in[0];
    const float* Wq = (const float*)d_in[1];
    const float* bq = (const float*)d_in[2];
    const float* Wk = (const float*)d_in[3];
    const float* bk = (const float*)d_in[4];
    const float* Wv = (const float*)d_in[5];
    const float* bv = (const float*)d_in[6];
    const float* W1 = (const float*)d_in[7];
    const float* b1 = (const float*)d_in[8];
    const float* W2 = (const float*)d_in[9];
    const float* b2 = (const float*)d_in[10];
    float* out = (float*)d_out;

    // ---- workspace layout (peak ~204 MB), time-overlaid ----
    char* w = (char*)d_ws;
    const long DISTB = (long)BB * SS * SS * 4;        // 67,108,864
    const long VB    = (long)BSR * DD * 2;            // 12,582,912 (bf16 v)
    const long SPLB  = (long)BSR * K2 * 2;            // 37,748,736
    const long WSPL  = (long)DD * K2;                 // elems per split weight

    float*          dist   = (float*)w;                               // [0, 67.1M)
    unsigned short* h_s    = (unsigned short*)w;                      // overlays dead dist
    unsigned short* v      = (unsigned short*)(w + DISTB);            // bf16 v
    unsigned short* q_s    = (unsigned short*)(w + DISTB + VB);
    unsigned short* k_s    = q_s + SPLB / 2;
    unsigned short* hs_s   = k_s + SPLB / 2;
    unsigned short* topo_s = hs_s;                                    // overlays dead hs_s
    unsigned short* Wqkv_s = hs_s + SPLB / 2;                         // 3 weight splits adjacent
    unsigned short* W1_s   = Wqkv_s;                                  // overlays dead Wqkv after qkv gemm
    unsigned short* W2_s   = Wqkv_s + WSPL;
    char* tail  = (char*)(Wqkv_s + 3 * WSPL);
    float* qn   = (float*)tail;                        // 8192
    float* kn   = qn + BSR;                            // 8192
    float* pn   = kn + BSR;                            // qnp[8192][12] + knp[8192][12]
    float* bqkv = pn + (long)2 * BSR * 12;             // 2304

    dim3 blk(256);
    const int convW  = (DD * (DD / 8)) / 256;          // 288 blocks per weight
    const int convHS = (BSR * (DD / 8)) / 256;         // 3072 blocks

    concat_bias<<<9, blk, 0, stream>>>(bq, bk, bv, bqkv);
    split_f16<2><<<convW, blk, 0, stream>>>(Wq, Wqkv_s, DD);
    split_f16<2><<<convW, blk, 0, stream>>>(Wk, Wqkv_s + WSPL, DD);
    split_f16<2><<<convW, blk, 0, stream>>>(Wv, Wqkv_s + 2 * WSPL, DD);
    split_f16<1><<<convHS, blk, 0, stream>>>(hs, hs_s, DD);

    // fused QKV gemm: q->split-A + norms, k->split-B + norms, v->bf16 (K=768)
    gemm_mfma<4><<<dim3(2304 / 128, BSR / 128, 1), blk, 0, stream>>>(
        hs_s, Wqkv_s, bqkv, nullptr, BSR, 2304, K2,
        q_s, k_s, v, pn);

    // W1/W2 splits into dead Wqkv region
    split_f16<2><<<convW, blk, 0, stream>>>(W1, W1_s, DD);
    split_f16<2><<<convW, blk, 0, stream>>>(W2, W2_s, DD);
    finish_norms<<<(2 * BSR) / 256, blk, 0, stream>>>(pn, qn, kn);

    // squared distance matrix per batch: single-term f16 (Kd=768, stride K2)
    gemm256_dist<<<dim3(SS / 256, SS / 256, BB), dim3(512), 0, stream>>>(
        q_s, k_s, qn, kn, dist, SS, DD, K2, K2,
        (long)SS * K2, (long)SS * K2, (long)SS * SS, SS);

    select_mean<<<BSR / 4, blk, 0, stream>>>(dist, v, q_s, k_s, qn, kn, topo_s);

    // MLP: gemm1 writes split-A h_s directly (relu fused)
    gemm_mfma<3><<<dim3(DD / 128, BSR / 128, 1), blk, 0, stream>>>(
        topo_s, W1_s, b1, nullptr, BSR, DD, K2,
        h_s, nullptr, nullptr, nullptr);
    gemm_mfma<0><<<dim3(DD / 128, BSR / 128, 1), blk, 0, stream>>>(
        h_s, W2_s, b2, out, BSR, DD, K2,
        nullptr, nullptr, nullptr, nullptr);
}

// Round 14
// 285.635 us; speedup vs baseline: 4.3850x; 1.1466x over previous
//
#include <hip/hip_runtime.h>
#include <float.h>

#define DD 768
#define SS 2048
#define BB 4
#define BSR (BB*SS)   // 8192 total rows
#define KNEI 32
#define K2 (3*DD)     // 2304: [hi | x | y] split concat along K
#define MARGIN 0.12f  // >=6 sigma of single-term f16 pairwise dist error

typedef __attribute__((ext_vector_type(8))) _Float16 f16x8;
typedef __attribute__((ext_vector_type(4))) float f32x4;
typedef __attribute__((ext_vector_type(8))) unsigned short u16x8;
typedef __attribute__((ext_vector_type(4))) unsigned short u16x4;

__device__ __forceinline__ float f16f(unsigned short u) {
    return (float)__builtin_bit_cast(_Float16, u);
}
__device__ __forceinline__ unsigned short ff16(float x) {
    return __builtin_bit_cast(unsigned short, (_Float16)x);
}
__device__ __forceinline__ unsigned short rne_bf16(float x) {
    unsigned u = __builtin_bit_cast(unsigned, x);
    unsigned r = u + 0x7FFFu + ((u >> 16) & 1u);
    return (unsigned short)(r >> 16);
}
__device__ __forceinline__ float bf16f(unsigned short h) {
    return __builtin_bit_cast(float, (unsigned)h << 16);
}

__device__ __forceinline__ void gload_lds16(const void* g, void* l) {
    __builtin_amdgcn_global_load_lds(
        (const __attribute__((address_space(1))) unsigned int*)g,
        (__attribute__((address_space(3))) unsigned int*)l, 16, 0, 0);
}

// fp32 -> 3-slot f16 split with power-of-2 rebalanced correction slots.
// A-layout (LO_SLOT=1): [h, l*2^6, h*2^-6];  B-layout (LO_SLOT=2): [h, h*2^-6, l*2^6]
template<int LO_SLOT>
__global__ __launch_bounds__(256)
void split_f16(const float* __restrict__ in, unsigned short* __restrict__ out, int Kc)
{
    int idx = blockIdx.x * 256 + threadIdx.x;
    int perRow = Kc >> 3;
    int row = idx / perRow, c8 = idx - row * perRow;
    const float* src = in + (long)row * Kc + c8 * 8;
    f32x4 x0 = *(const f32x4*)&src[0];
    f32x4 x1 = *(const f32x4*)&src[4];
    u16x8 hi, lsc, hsc;
    #pragma unroll
    for (int e = 0; e < 8; ++e) {
        float xv = (e < 4) ? x0[e] : x1[e - 4];
        _Float16 h = (_Float16)xv;
        float hf = (float)h;
        float l = xv - hf;
        hi[e]  = __builtin_bit_cast(unsigned short, h);
        lsc[e] = ff16(l * 64.f);
        hsc[e] = ff16(hf * 0.015625f);
    }
    long base = (long)row * (3 * Kc) + c8 * 8;
    *(u16x8*)&out[base] = hi;
    *(u16x8*)&out[base + Kc]     = (LO_SLOT == 1) ? lsc : hsc;
    *(u16x8*)&out[base + 2 * Kc] = (LO_SLOT == 1) ? hsc : lsc;
}

// plain f32 -> f16 compact convert (for single-term MLP weights)
__global__ __launch_bounds__(256)
void conv_f16(const float* __restrict__ in, unsigned short* __restrict__ out)
{
    int idx = blockIdx.x * 256 + threadIdx.x;   // 8 elems per thread
    const float* src = in + (long)idx * 8;
    f32x4 x0 = *(const f32x4*)&src[0];
    f32x4 x1 = *(const f32x4*)&src[4];
    u16x8 o;
    #pragma unroll
    for (int e = 0; e < 8; ++e) {
        float xv = (e < 4) ? x0[e] : x1[e - 4];
        o[e] = ff16(xv);
    }
    *(u16x8*)&out[(long)idx * 8] = o;
}

__global__ __launch_bounds__(256)
void concat_bias(const float* __restrict__ bq, const float* __restrict__ bk,
                 const float* __restrict__ bv, float* __restrict__ bqkv)
{
    int i = blockIdx.x * 256 + threadIdx.x;
    if (i < 768) bqkv[i] = bq[i];
    else if (i < 1536) bqkv[i] = bk[i - 768];
    else if (i < 2304) bqkv[i] = bv[i - 1536];
}

// pn rows: qnp[8192][12] then knp[8192][12] contiguous; fixed-order sum.
__global__ __launch_bounds__(256)
void finish_norms(const float* __restrict__ pn, float* __restrict__ qn, float* __restrict__ kn)
{
    int row = blockIdx.x * 256 + threadIdx.x;   // 0..16383
    const float* p = pn + (long)row * 12;
    float s = 0.f;
    #pragma unroll
    for (int c = 0; c < 12; ++c) s += p[c];
    if (row < BSR) qn[row] = s; else kn[row - BSR] = s;
}

// ---------------------------------------------------------------------------
// 256x256-tile distance GEMM, "minimum 2-phase" schedule: issue next-tile
// prefetch into buf^1, compute buf[cur], then ONE __syncthreads() per tile.
// __syncthreads' enforced vmcnt(0)+lgkmcnt(0) drain closes every hazard.
// Single-term f16: Kd=768 (hi slots only), row stride lda/ldb = K2.
// ---------------------------------------------------------------------------
__global__ __launch_bounds__(512)
void gemm256_dist(const unsigned short* __restrict__ A, const unsigned short* __restrict__ B,
                  const float* __restrict__ rm, const float* __restrict__ rn,
                  float* __restrict__ C,
                  int N, int Kd, long lda, long ldb,
                  long sA, long sB, long sC, long sR)
{
    const int z = blockIdx.z;
    A += (long)z * sA;
    B += (long)z * sB;
    C += (long)z * sC;
    const float* rmz = rm + (long)z * sR;
    const float* rnz = rn + (long)z * sR;

    // bijective XCD swizzle over the 64 blocks of this batch
    int lid = blockIdx.y * gridDim.x + blockIdx.x;
    int xcd = lid & 7, pos = lid >> 3;
    int nlid = xcd * 8 + pos;
    const int bx = nlid & 7, by = nlid >> 3;

    __shared__ __align__(16) unsigned short lds[2 * 32768];  // 2 bufs x (A 16384 | B 16384) f16

    const int tid = threadIdx.x;
    const int lane = tid & 63;
    const int wave = tid >> 6;
    const int wm = wave >> 2, wn = wave & 3;   // 2 x 4 wave grid
    const int m0 = by * 256, n0 = bx * 256;
    const int r15 = lane & 15;
    const int g4 = lane >> 4;

    f32x4 acc[8][4] = {};

    long aB[4], bB[4];
    int lof[4];
    #pragma unroll
    for (int i = 0; i < 4; ++i) {
        int L = i * 512 + tid;          // 0..2047 chunk id (16B chunks)
        int row = L >> 3, ch = L & 7;
        int chs = ch ^ (row & 7);
        aB[i] = (long)(m0 + row) * lda * 2 + chs * 16;
        bB[i] = (long)(n0 + row) * ldb * 2 + chs * 16;
        lof[i] = L * 8;
    }

    const int NT = Kd >> 6;             // 12 K-tiles of 64

    // prologue: stage tile 0 into buf 0, full drain
    #pragma unroll
    for (int i = 0; i < 4; ++i) {
        gload_lds16((const char*)A + aB[i], &lds[lof[i]]);
        gload_lds16((const char*)B + bB[i], &lds[16384 + lof[i]]);
    }
    __syncthreads();

    int cur = 0;
    for (int t = 0; t < NT; ++t) {
        if (t + 1 < NT) {               // prefetch next tile into the other buffer
            long kb = (long)(t + 1) * 128;
            int off = (cur ^ 1) * 32768;
            #pragma unroll
            for (int i = 0; i < 4; ++i) {
                gload_lds16((const char*)A + aB[i] + kb, &lds[off + lof[i]]);
                gload_lds16((const char*)B + bB[i] + kb, &lds[off + 16384 + lof[i]]);
            }
        }
        const unsigned short* bufA = &lds[cur * 32768];
        const unsigned short* bufB = bufA + 16384;
        #pragma unroll
        for (int ks = 0; ks < 2; ++ks) {
            f16x8 af[8], bfr[4];
            #pragma unroll
            for (int i = 0; i < 8; ++i) {
                int r = wm * 128 + i * 16 + r15;
                int g = ks * 4 + g4;
                af[i] = *(const f16x8*)&bufA[r * 64 + (g ^ (r & 7)) * 8];
            }
            #pragma unroll
            for (int j = 0; j < 4; ++j) {
                int c = wn * 64 + j * 16 + r15;
                int g = ks * 4 + g4;
                bfr[j] = *(const f16x8*)&bufB[c * 64 + (g ^ (c & 7)) * 8];
            }
            #pragma unroll
            for (int i = 0; i < 8; ++i)
                #pragma unroll
                for (int j = 0; j < 4; ++j)
                    acc[i][j] = __builtin_amdgcn_mfma_f32_16x16x32_f16(
                        af[i], bfr[j], acc[i][j], 0, 0, 0);
        }
        __syncthreads();                // full drain: prefetch landed, reads done
        cur ^= 1;
    }

    // epilogue: C/D layout col=lane&15, row=(lane>>4)*4+reg
    float rnv[4];
    #pragma unroll
    for (int j = 0; j < 4; ++j)
        rnv[j] = rnz[n0 + wn * 64 + j * 16 + r15];
    #pragma unroll
    for (int i = 0; i < 8; ++i) {
        #pragma unroll
        for (int r = 0; r < 4; ++r) {
            int m = m0 + wm * 128 + i * 16 + g4 * 4 + r;
            float rmv = rmz[m];
            #pragma unroll
            for (int j = 0; j < 4; ++j) {
                int n = n0 + wn * 64 + j * 16 + r15;
                C[(long)m * N + n] = rmv + rnv[j] - 2.f * acc[i][j][r];
            }
        }
    }
}

// C[m][n] = epilogue( sum_k A[m][k]*B[n][k] ), NT f16 inputs, strides lda/ldb.
// Same minimum-2-phase __syncthreads schedule.
// MODE 0: +bias[n] -> f32 C
// MODE 3: relu(+bias[n]) -> compact f16 oQ [m][768]
// MODE 4: combined QKV: seg 0 -> split-A oQ + qnp; 1 -> split-B oK + knp;
//         2 -> bf16 oV with SINGLE-TERM K=768
template<int MODE>
__global__ __launch_bounds__(256)
void gemm_mfma(const unsigned short* __restrict__ A, const unsigned short* __restrict__ B,
               const float* __restrict__ bias,
               float* __restrict__ C,
               int M, int N, int Kd, long lda, long ldb,
               unsigned short* __restrict__ oQ, unsigned short* __restrict__ oK,
               unsigned short* __restrict__ oV, float* __restrict__ pn)
{
    // ---- bijective XCD swizzle (T1/m204) ----
    const int nwgx = gridDim.x;
    const int nwg  = nwgx * gridDim.y;
    int lid = blockIdx.y * nwgx + blockIdx.x;
    int qq = nwg >> 3, rr = nwg & 7;
    int xcd = lid & 7, pos = lid >> 3;
    int nlid = (xcd < rr ? xcd * (qq + 1) : rr * (qq + 1) + (xcd - rr) * qq) + pos;
    const int bx = nlid % nwgx;
    const int by = nlid / nwgx;

    __shared__ __align__(16) unsigned short lds[2 * 16384];  // 2 bufs x (A 8192 | B 8192)

    const int tid = threadIdx.x;
    const int lane = tid & 63;
    const int wave = tid >> 6;
    const int wm = wave >> 1, wn = wave & 1;
    const int m0 = by * 128, n0 = bx * 128;
    const int r15 = lane & 15;
    const int g4 = lane >> 4;

    f32x4 acc[4][4] = {};

    long aByte[4], bByte[4];
    int ldsOff[4];
    #pragma unroll
    for (int i = 0; i < 4; ++i) {
        int L = i * 256 + tid;
        int row = L >> 3, ch = L & 7;
        int chs = ch ^ (row & 7);
        aByte[i] = (long)(m0 + row) * lda * 2 + chs * 16;
        bByte[i] = (long)(n0 + row) * ldb * 2 + chs * 16;
        ldsOff[i] = L * 8;
    }

    int NT = Kd >> 6;                          // 36 (or 12 for v segment below)
    if (MODE == 4 && n0 >= 1536) NT = 12;      // v: single-term f16 (hi slots only)

    // prologue: stage tile 0 into buf 0, full drain
    #pragma unroll
    for (int i = 0; i < 4; ++i) {
        gload_lds16((const char*)A + aByte[i], &lds[ldsOff[i]]);
        gload_lds16((const char*)B + bByte[i], &lds[8192 + ldsOff[i]]);
    }
    __syncthreads();

    int cur = 0;
    for (int t = 0; t < NT; ++t) {
        if (t + 1 < NT) {
            long kb = (long)(t + 1) * 128;
            int off = (cur ^ 1) * 16384;
            #pragma unroll
            for (int i = 0; i < 4; ++i) {
                gload_lds16((const char*)A + aByte[i] + kb, &lds[off + ldsOff[i]]);
                gload_lds16((const char*)B + bByte[i] + kb, &lds[off + 8192 + ldsOff[i]]);
            }
        }
        const unsigned short* bufA = &lds[cur * 16384];
        const unsigned short* bufB = bufA + 8192;
        #pragma unroll
        for (int ks = 0; ks < 2; ++ks) {
            f16x8 af[4], bfr[4];
            #pragma unroll
            for (int i = 0; i < 4; ++i) {
                int row = wm * 64 + i * 16 + r15;
                int chs = (ks * 4 + g4) ^ (r15 & 7);
                af[i] = *(const f16x8*)&bufA[row * 64 + chs * 8];
            }
            #pragma unroll
            for (int j = 0; j < 4; ++j) {
                int row = wn * 64 + j * 16 + r15;
                int chs = (ks * 4 + g4) ^ (r15 & 7);
                bfr[j] = *(const f16x8*)&bufB[row * 64 + chs * 8];
            }
            #pragma unroll
            for (int i = 0; i < 4; ++i)
                #pragma unroll
                for (int j = 0; j < 4; ++j)
                    acc[i][j] = __builtin_amdgcn_mfma_f32_16x16x32_f16(
                        af[i], bfr[j], acc[i][j], 0, 0, 0);
        }
        __syncthreads();
        cur ^= 1;
    }

    float bj[4];
    #pragma unroll
    for (int j = 0; j < 4; ++j) {
        int n = n0 + wn * 64 + j * 16 + r15;
        bj[j] = bias[n];
    }

    if (MODE == 0) {
        #pragma unroll
        for (int i = 0; i < 4; ++i) {
            #pragma unroll
            for (int r = 0; r < 4; ++r) {
                int m = m0 + wm * 64 + i * 16 + g4 * 4 + r;
                #pragma unroll
                for (int j = 0; j < 4; ++j) {
                    int n = n0 + wn * 64 + j * 16 + r15;
                    C[(long)m * N + n] = acc[i][j][r] + bj[j];
                }
            }
        }
    }

    if (MODE == 3) {
        #pragma unroll
        for (int i = 0; i < 4; ++i) {
            #pragma unroll
            for (int r = 0; r < 4; ++r) {
                int m = m0 + wm * 64 + i * 16 + g4 * 4 + r;
                #pragma unroll
                for (int j = 0; j < 4; ++j) {
                    int e = n0 + wn * 64 + j * 16 + r15;
                    float xv = fmaxf(acc[i][j][r] + bj[j], 0.f);
                    oQ[(long)m * DD + e] = ff16(xv);
                }
            }
        }
    }

    if (MODE == 4) {
        const int seg = n0 / 768;                       // block-uniform: 0=q 1=k 2=v
        const int e0 = n0 - seg * 768 + wn * 64;
        const int chunk = (bx - seg * 6) * 2 + wn;      // 0..11 within segment
        #pragma unroll
        for (int i = 0; i < 4; ++i) {
            #pragma unroll
            for (int r = 0; r < 4; ++r) {
                int m = m0 + wm * 64 + i * 16 + g4 * 4 + r;
                float vals[4];
                #pragma unroll
                for (int j = 0; j < 4; ++j) vals[j] = acc[i][j][r] + bj[j];
                if (seg == 2) {
                    #pragma unroll
                    for (int j = 0; j < 4; ++j)
                        oV[(long)m * DD + e0 + j * 16 + r15] = rne_bf16(vals[j]);
                } else {
                    unsigned short* os = (seg == 0) ? oQ : oK;
                    #pragma unroll
                    for (int j = 0; j < 4; ++j) {
                        float xv = vals[j];
                        _Float16 hh = (_Float16)xv;
                        float hf = (float)hh;
                        float l = xv - hf;
                        long base = (long)m * K2 + e0 + j * 16 + r15;
                        os[base] = __builtin_bit_cast(unsigned short, hh);
                        os[base + ((seg == 0) ? DD : 2 * DD)] = ff16(l * 64.f);
                        os[base + ((seg == 0) ? 2 * DD : DD)] = ff16(hf * 0.015625f);
                    }
                    float s = vals[0]*vals[0] + vals[1]*vals[1]
                            + vals[2]*vals[2] + vals[3]*vals[3];
                    s += __shfl_xor(s, 1); s += __shfl_xor(s, 2);
                    s += __shfl_xor(s, 4); s += __shfl_xor(s, 8);
                    if (r15 == 0)
                        pn[(seg ? (long)BSR * 12 : 0) + (long)m * 12 + chunk] = s;
                }
            }
        }
    }
}

// One WAVE per query row, zero LDS, zero barriers.
// Phase 1: streaming branchless insertion top-8 per lane (sorted u64 keys).
// Phase 2: threshold selection (bitplane-ballot binary search) + exact tie-break;
//          wave-uniform fallback to 33-iteration tournament on saturation.
// Phase 3: boundary-gap guard (exact fp32 recompute from splits).
// Phase 4: rank-based index assignment, gather batched 8 rows at a time.
// Writes COMPACT f16 topo [g][768].
__global__ __launch_bounds__(256)
void select_mean(const float* __restrict__ dist, const unsigned short* __restrict__ v,
                 const unsigned short* __restrict__ q_s, const unsigned short* __restrict__ k_s,
                 const float* __restrict__ qn, const float* __restrict__ kn,
                 unsigned short* __restrict__ topo_f16)
{
    const int wv = threadIdx.x >> 6;
    const int lane = threadIdx.x & 63;
    const int g = blockIdx.x * 4 + wv;      // global row 0..8191
    const int b = g >> 11;
    const float* drow = dist + (long)b * SS * SS + (long)(g & (SS - 1)) * SS;
    const unsigned short* vb = v + (long)b * SS * DD;

    float d[32];
    unsigned long long h0 = ~0ull, h1 = ~0ull, h2 = ~0ull, h3 = ~0ull,
                       h4 = ~0ull, h5 = ~0ull, h6 = ~0ull, h7 = ~0ull;
    const f32x4* dr4 = (const f32x4*)drow;
    #pragma unroll
    for (int c = 0; c < 8; ++c) {
        f32x4 tv = dr4[c * 64 + lane];
        #pragma unroll
        for (int i = 0; i < 4; ++i) {
            float x = fmaxf(tv[i], 0.f);
            d[c * 4 + i] = x;
            unsigned long long kk =
                ((unsigned long long)__builtin_bit_cast(unsigned, x) << 32)
                | (unsigned)(c * 256 + lane * 4 + i);
            if (kk < h7) {                  // branchless sorted insert
                bool l6 = kk < h6, l5 = kk < h5, l4 = kk < h4, l3 = kk < h3,
                     l2 = kk < h2, l1 = kk < h1, l0 = kk < h0;
                h7 = l6 ? h6 : kk;
                h6 = l6 ? (l5 ? h5 : kk) : h6;
                h5 = l5 ? (l4 ? h4 : kk) : h5;
                h4 = l4 ? (l3 ? h3 : kk) : h4;
                h3 = l3 ? (l2 ? h2 : kk) : h3;
                h2 = l2 ? (l1 ? h1 : kk) : h2;
                h1 = l1 ? (l0 ? h0 : kk) : h1;
                h0 = l0 ? kk : h0;
            }
        }
    }

    const unsigned hv0 = (unsigned)(h0 >> 32), hv1 = (unsigned)(h1 >> 32),
                   hv2 = (unsigned)(h2 >> 32), hv3 = (unsigned)(h3 >> 32),
                   hv4 = (unsigned)(h4 >> 32), hv5 = (unsigned)(h5 >> 32),
                   hv6 = (unsigned)(h6 >> 32), hv7 = (unsigned)(h7 >> 32);

    unsigned sel = 0;
    float d32v = 0.f, d33v = 0.f;

    // ---- Phase 2: threshold selection via value-bit binary search ----
    unsigned Vv = 0;
    for (int bit = 31; bit >= 0; --bit) {
        unsigned candv = Vv | (1u << bit);
        int c = (hv0 < candv) + (hv1 < candv) + (hv2 < candv) + (hv3 < candv)
              + (hv4 < candv) + (hv5 < candv) + (hv6 < candv) + (hv7 < candv);
        int tot = (int)__popcll(__ballot(c & 1))
                + 2 * (int)__popcll(__ballot(c & 2))
                + 4 * (int)__popcll(__ballot(c & 4))
                + 8 * (int)__popcll(__ballot(c & 8));
        if (tot <= 31) Vv = candv;
    }
    bool fallback = __any(hv7 <= Vv);

    if (!fallback) {
        int cl = (hv0 < Vv) + (hv1 < Vv) + (hv2 < Vv) + (hv3 < Vv)
               + (hv4 < Vv) + (hv5 < Vv) + (hv6 < Vv) + (hv7 < Vv);
        int c_lt = (int)__popcll(__ballot(cl & 1))
                 + 2 * (int)__popcll(__ballot(cl & 2))
                 + 4 * (int)__popcll(__ballot(cl & 4))
                 + 8 * (int)__popcll(__ballot(cl & 8));
        #pragma unroll
        for (int s = 0; s < 32; ++s)
            if (__builtin_bit_cast(unsigned, d[s]) < Vv) sel |= 1u << s;
        int need = KNEI - c_lt;
        for (int t2 = 0; t2 < need; ++t2) {
            unsigned mi = 0xffffffffu;
            #pragma unroll
            for (int s = 0; s < 32; ++s) {
                bool eq = (__builtin_bit_cast(unsigned, d[s]) == Vv) && !((sel >> s) & 1u);
                unsigned jj = (unsigned)((s >> 2) * 256 + lane * 4 + (s & 3));
                if (eq && jj < mi) mi = jj;
            }
            #pragma unroll
            for (int off = 32; off; off >>= 1) {
                unsigned o = __shfl_xor(mi, off);
                mi = o < mi ? o : mi;
            }
            if (mi != 0xffffffffu && lane == ((mi >> 2) & 63))
                sel |= 1u << (((mi >> 8) << 2) | (mi & 3));
        }
        d32v = __builtin_bit_cast(float, Vv);
        int ce = (hv0 <= Vv) + (hv1 <= Vv) + (hv2 <= Vv) + (hv3 <= Vv)
               + (hv4 <= Vv) + (hv5 <= Vv) + (hv6 <= Vv) + (hv7 <= Vv);
        int c_le = (int)__popcll(__ballot(ce & 1))
                 + 2 * (int)__popcll(__ballot(ce & 2))
                 + 4 * (int)__popcll(__ballot(ce & 4))
                 + 8 * (int)__popcll(__ballot(ce & 8));
        if (c_le >= 33) {
            d33v = d32v;
        } else {
            unsigned mv = 0xffffffffu;
            if (hv0 > Vv && hv0 < mv) mv = hv0;
            if (hv1 > Vv && hv1 < mv) mv = hv1;
            if (hv2 > Vv && hv2 < mv) mv = hv2;
            if (hv3 > Vv && hv3 < mv) mv = hv3;
            if (hv4 > Vv && hv4 < mv) mv = hv4;
            if (hv5 > Vv && hv5 < mv) mv = hv5;
            if (hv6 > Vv && hv6 < mv) mv = hv6;
            if (hv7 > Vv && hv7 < mv) mv = hv7;
            #pragma unroll
            for (int off = 32; off; off >>= 1) {
                unsigned o = __shfl_xor(mv, off);
                mv = o < mv ? o : mv;
            }
            d33v = __builtin_bit_cast(float, mv);
        }
    } else {
        // ---- proven 33-iteration tournament path (rare) ----
        unsigned long long g0 = h0, g1 = h1, g2 = h2, g3 = h3,
                           g4b = h4, g5 = h5, g6 = h6, g7 = h7;
        int cnt = 0;
        for (int t = 0; t < 33; ++t) {
            unsigned long long best = g0;
            #pragma unroll
            for (int off = 32; off; off >>= 1) {
                unsigned long long o = __shfl_xor(best, off);
                best = o < best ? o : best;
            }
            if (t == 32) {
                d33v = __builtin_bit_cast(float, (unsigned)(best >> 32));
                break;
            }
            int j = (int)(unsigned)best;
            bool won = (lane == ((j >> 2) & 63));
            if (won) sel |= 1u << (((j >> 8) << 2) | (j & 3));
            if (t == 31) d32v = __builtin_bit_cast(float, (unsigned)(best >> 32));

            if (won) cnt++;
            bool needScan = won && (cnt >= 8);
            bool adv = won && (cnt < 8);
            g0 = adv ? g1 : g0;  g1 = adv ? g2 : g1;  g2 = adv ? g3 : g2;
            g3 = adv ? g4b : g3; g4b = adv ? g5 : g4b; g5 = adv ? g6 : g5;
            g6 = adv ? g7 : g6;  g7 = adv ? ~0ull : g7;
            if (__any(needScan)) {
                if (needScan) {
                    float bv = FLT_MAX; int bs = 0; bool found = false;
                    #pragma unroll
                    for (int s = 0; s < 32; ++s) {
                        bool ok = !((sel >> s) & 1u);
                        bool lt = ok && (d[s] < bv);
                        bv = lt ? d[s] : bv; bs = lt ? s : bs; found |= ok;
                    }
                    g0 = found
                       ? (((unsigned long long)__builtin_bit_cast(unsigned, bv) << 32)
                          | (unsigned)((bs >> 2) * 256 + lane * 4 + (bs & 3)))
                       : ~0ull;
                }
            }
        }
    }

    // ---- Phase 3: boundary-gap guard (exact fp32 recompute for the window) ----
    if (d33v - d32v < MARGIN) {
        float lo = d32v - MARGIN, hi = d33v + MARGIN;
        unsigned cand = 0;
        #pragma unroll
        for (int s = 0; s < 32; ++s)
            if (d[s] >= lo && d[s] <= hi) cand |= 1u << s;

        const unsigned short* qrow = q_s + (long)g * K2;
        const u16x4* qh = (const u16x4*)&qrow[lane * 12];
        const u16x4* ql = (const u16x4*)&qrow[DD + lane * 12];
        #pragma unroll
        for (int s = 0; s < 32; ++s) {
            unsigned long long m = __ballot((cand >> s) & 1u);
            while (m) {
                int l2 = __ffsll(m) - 1;
                m &= m - 1;
                int j = (s >> 2) * 256 + l2 * 4 + (s & 3);
                const unsigned short* krow = k_s + ((long)b * SS + j) * K2;
                const u16x4* kh = (const u16x4*)&krow[lane * 12];
                const u16x4* kl = (const u16x4*)&krow[2 * DD + lane * 12];
                float part = 0.f;
                #pragma unroll
                for (int c = 0; c < 3; ++c) {
                    u16x4 qa = qh[c], qb = ql[c], ka = kh[c], kb2 = kl[c];
                    #pragma unroll
                    for (int e = 0; e < 4; ++e) {
                        float qv = f16f(qa[e]) + f16f(qb[e]) * 0.015625f;
                        float kv = f16f(ka[e]) + f16f(kb2[e]) * 0.015625f;
                        part = fmaf(qv, kv, part);
                    }
                }
                #pragma unroll
                for (int off = 32; off; off >>= 1) part += __shfl_xor(part, off);
                float dd = qn[g] + kn[(long)b * SS + j] - 2.f * part;
                dd = fmaxf(dd, 0.f);
                if (lane == l2) d[s] = dd;
            }
        }

        sel &= ~cand;
        int C = 0;
        #pragma unroll
        for (int s = 0; s < 32; ++s) C += (int)__popcll(__ballot((sel >> s) & 1u));
        int need = KNEI - C;
        for (int t = 0; t < need; ++t) {
            unsigned long long best = ~0ull;
            #pragma unroll
            for (int s = 0; s < 32; ++s) {
                if (((cand >> s) & 1u) && !((sel >> s) & 1u)) {
                    unsigned long long key =
                        ((unsigned long long)__builtin_bit_cast(unsigned, d[s]) << 32)
                        | (unsigned)((s >> 2) * 256 + lane * 4 + (s & 3));
                    best = key < best ? key : best;
                }
            }
            #pragma unroll
            for (int off = 32; off; off >>= 1) {
                unsigned long long o = __shfl_xor(best, off);
                best = o < best ? o : best;
            }
            if (best != ~0ull) {
                int j = (int)(unsigned)best;
                if (lane == ((j >> 2) & 63)) sel |= 1u << (((j >> 8) << 2) | (j & 3));
            }
        }
    }

    // ---- Phase 4: rank-based selected-index assignment + batched gather ----
    int myj = 0;
    {
        int target = lane & 31;            // lane p (and p+32) own the p-th selected index
        int cum = 0;
        #pragma unroll
        for (int s = 0; s < 32; ++s) {
            unsigned long long m = __ballot((sel >> s) & 1u);
            int c = (int)__popcll(m);
            if (target >= cum && target < cum + c) {
                int nth = target - cum;
                unsigned long long mm = m;
                int base = 0;
                int c32 = (int)__popcll(mm & 0xffffffffull);
                if (nth >= c32) { nth -= c32; mm >>= 32; base += 32; }
                int c16 = (int)__popcll(mm & 0xffffull);
                if (nth >= c16) { nth -= c16; mm >>= 16; base += 16; }
                int c8 = (int)__popcll(mm & 0xffull);
                if (nth >= c8) { nth -= c8; mm >>= 8; base += 8; }
                int c4 = (int)__popcll(mm & 0xfull);
                if (nth >= c4) { nth -= c4; mm >>= 4; base += 4; }
                int c2 = (int)__popcll(mm & 0x3ull);
                if (nth >= c2) { nth -= c2; mm >>= 2; base += 2; }
                int c1 = (int)(mm & 1ull);
                if (nth >= c1) { base += 1; }
                myj = (s >> 2) * 256 + base * 4 + (s & 3);
            }
            cum += c;
        }
    }
    f32x4 a0 = {0.f, 0.f, 0.f, 0.f}, a1 = a0, a2 = a0;
    #pragma unroll
    for (int tb = 0; tb < 4; ++tb) {
        u16x4 r0[8], r1[8], r2[8];
        #pragma unroll
        for (int u = 0; u < 8; ++u) {
            int j = __shfl(myj, tb * 8 + u);
            const u16x4* vr = (const u16x4*)(vb + (long)j * DD);
            r0[u] = vr[lane];
            r1[u] = vr[lane + 64];
            r2[u] = vr[lane + 128];
        }
        #pragma unroll
        for (int u = 0; u < 8; ++u) {
            #pragma unroll
            for (int e = 0; e < 4; ++e) {
                a0[e] += bf16f(r0[u][e]);
                a1[e] += bf16f(r1[u][e]);
                a2[e] += bf16f(r2[u][e]);
            }
        }
    }
    const float sc = 1.0f / 32.0f;
    unsigned short* trow = topo_f16 + (long)g * DD;
    #pragma unroll
    for (int c = 0; c < 3; ++c) {
        f32x4 x = (c == 0) ? a0 : (c == 1) ? a1 : a2;
        u16x4 hi;
        #pragma unroll
        for (int e = 0; e < 4; ++e) hi[e] = ff16(x[e] * sc);
        *(u16x4*)&trow[c * 256 + lane * 4] = hi;
    }
}

extern "C" void kernel_launch(void* const* d_in, const int* in_sizes, int n_in,
                              void* d_out, int out_size, void* d_ws, size_t ws_size,
                              hipStream_t stream)
{
    const float* hs = (const float*)d_in[0];
    const float* Wq = (const float*)d_in[1];
    const float* bq = (const float*)d_in[2];
    const float* Wk = (const float*)d_in[3];
    const float* bk = (const float*)d_in[4];
    const float* Wv = (const float*)d_in[5];
    const float* bv = (const float*)d_in[6];
    const float* W1 = (const float*)d_in[7];
    const float* b1 = (const float*)d_in[8];
    const float* W2 = (const float*)d_in[9];
    const float* b2 = (const float*)d_in[10];
    float* out = (float*)d_out;

    // ---- workspace layout (peak ~204 MB), time-overlaid ----
    char* w = (char*)d_ws;
    const long DISTB = (long)BB * SS * SS * 4;        // 67,108,864
    const long VB    = (long)BSR * DD * 2;            // 12,582,912 (bf16 v)
    const long SPLB  = (long)BSR * K2 * 2;            // 37,748,736
    const long WSPL  = (long)DD * K2;                 // elems per split weight

    float*          dist   = (float*)w;                               // [0, 67.1M)
    unsigned short* h_f16  = (unsigned short*)w;                      // overlays dead dist
    unsigned short* v      = (unsigned short*)(w + DISTB);            // bf16 v
    unsigned short* q_s    = (unsigned short*)(w + DISTB + VB);
    unsigned short* k_s    = q_s + SPLB / 2;
    unsigned short* hs_s   = k_s + SPLB / 2;
    unsigned short* topo_f16 = hs_s;                                  // overlays dead hs_s
    unsigned short* Wqkv_s = hs_s + SPLB / 2;                         // 3 weight splits adjacent
    unsigned short* W1_f16 = Wqkv_s;                                  // overlays dead Wqkv
    unsigned short* W2_f16 = Wqkv_s + (long)DD * DD;
    char* tail  = (char*)(Wqkv_s + 3 * WSPL);
    float* qn   = (float*)tail;                        // 8192
    float* kn   = qn + BSR;                            // 8192
    float* pn   = kn + BSR;                            // qnp[8192][12] + knp[8192][12]
    float* bqkv = pn + (long)2 * BSR * 12;             // 2304

    dim3 blk(256);
    const int convW  = (DD * (DD / 8)) / 256;          // 288 blocks per weight
    const int convHS = (BSR * (DD / 8)) / 256;         // 3072 blocks

    concat_bias<<<9, blk, 0, stream>>>(bq, bk, bv, bqkv);
    split_f16<2><<<convW, blk, 0, stream>>>(Wq, Wqkv_s, DD);
    split_f16<2><<<convW, blk, 0, stream>>>(Wk, Wqkv_s + WSPL, DD);
    split_f16<2><<<convW, blk, 0, stream>>>(Wv, Wqkv_s + 2 * WSPL, DD);
    split_f16<1><<<convHS, blk, 0, stream>>>(hs, hs_s, DD);

    // fused QKV gemm: q->split-A + norms, k->split-B + norms, v->bf16 (K=768)
    gemm_mfma<4><<<dim3(2304 / 128, BSR / 128, 1), blk, 0, stream>>>(
        hs_s, Wqkv_s, bqkv, nullptr, BSR, 2304, K2, K2, K2,
        q_s, k_s, v, pn);

    // W1/W2 compact f16 converts into dead Wqkv region
    conv_f16<<<convW, blk, 0, stream>>>(W1, W1_f16);
    conv_f16<<<convW, blk, 0, stream>>>(W2, W2_f16);
    finish_norms<<<(2 * BSR) / 256, blk, 0, stream>>>(pn, qn, kn);

    // squared distance matrix per batch: single-term f16 (Kd=768, stride K2)
    gemm256_dist<<<dim3(SS / 256, SS / 256, BB), dim3(512), 0, stream>>>(
        q_s, k_s, qn, kn, dist, SS, DD, K2, K2,
        (long)SS * K2, (long)SS * K2, (long)SS * SS, SS);

    select_mean<<<BSR / 4, blk, 0, stream>>>(dist, v, q_s, k_s, qn, kn, topo_f16);

    // MLP single-term f16: gemm1 -> compact f16 h (relu fused), gemm2 -> f32 out
    gemm_mfma<3><<<dim3(DD / 128, BSR / 128, 1), blk, 0, stream>>>(
        topo_f16, W1_f16, b1, nullptr, BSR, DD, DD, DD, DD,
        h_f16, nullptr, nullptr, nullptr);
    gemm_mfma<0><<<dim3(DD / 128, BSR / 128, 1), blk, 0, stream>>>(
        h_f16, W2_f16, b2, out, BSR, DD, DD, DD, DD,
        nullptr, nullptr, nullptr, nullptr);
}

// Round 16
// 270.054 us; speedup vs baseline: 4.6379x; 1.0577x over previous
//
#include <hip/hip_runtime.h>
#include <float.h>

#define DD 768
#define SS 2048
#define BB 4
#define BSR (BB*SS)   // 8192 total rows
#define KNEI 32
#define K2 (3*DD)     // 2304: [hi | x | y] split concat along K (hs_s only)
#define QS (2*DD)     // 1536: 2-slot q_s/k_s layout [h, l*2^6]
#define MARGIN 0.12f  // >=6 sigma of single-term f16 pairwise dist error

typedef __attribute__((ext_vector_type(8))) _Float16 f16x8;
typedef __attribute__((ext_vector_type(4))) float f32x4;
typedef __attribute__((ext_vector_type(8))) unsigned short u16x8;
typedef __attribute__((ext_vector_type(4))) unsigned short u16x4;

__device__ __forceinline__ float f16f(unsigned short u) {
    return (float)__builtin_bit_cast(_Float16, u);
}
__device__ __forceinline__ unsigned short ff16(float x) {
    return __builtin_bit_cast(unsigned short, (_Float16)x);
}

__device__ __forceinline__ void gload_lds16(const void* g, void* l) {
    __builtin_amdgcn_global_load_lds(
        (const __attribute__((address_space(1))) unsigned int*)g,
        (__attribute__((address_space(3))) unsigned int*)l, 16, 0, 0);
}

// fp32 -> 3-slot f16 split with power-of-2 rebalanced correction slots.
// A-layout (LO_SLOT=1): [h, l*2^6, h*2^-6];  B-layout (LO_SLOT=2): [h, h*2^-6, l*2^6]
template<int LO_SLOT>
__global__ __launch_bounds__(256)
void split_f16(const float* __restrict__ in, unsigned short* __restrict__ out, int Kc)
{
    int idx = blockIdx.x * 256 + threadIdx.x;
    int perRow = Kc >> 3;
    int row = idx / perRow, c8 = idx - row * perRow;
    const float* src = in + (long)row * Kc + c8 * 8;
    f32x4 x0 = *(const f32x4*)&src[0];
    f32x4 x1 = *(const f32x4*)&src[4];
    u16x8 hi, lsc, hsc;
    #pragma unroll
    for (int e = 0; e < 8; ++e) {
        float xv = (e < 4) ? x0[e] : x1[e - 4];
        _Float16 h = (_Float16)xv;
        float hf = (float)h;
        float l = xv - hf;
        hi[e]  = __builtin_bit_cast(unsigned short, h);
        lsc[e] = ff16(l * 64.f);
        hsc[e] = ff16(hf * 0.015625f);
    }
    long base = (long)row * (3 * Kc) + c8 * 8;
    *(u16x8*)&out[base] = hi;
    *(u16x8*)&out[base + Kc]     = (LO_SLOT == 1) ? lsc : hsc;
    *(u16x8*)&out[base + 2 * Kc] = (LO_SLOT == 1) ? hsc : lsc;
}

// plain f32 -> f16 compact convert (for single-term MLP weights)
__global__ __launch_bounds__(256)
void conv_f16(const float* __restrict__ in, unsigned short* __restrict__ out)
{
    int idx = blockIdx.x * 256 + threadIdx.x;   // 8 elems per thread
    const float* src = in + (long)idx * 8;
    f32x4 x0 = *(const f32x4*)&src[0];
    f32x4 x1 = *(const f32x4*)&src[4];
    u16x8 o;
    #pragma unroll
    for (int e = 0; e < 8; ++e) {
        float xv = (e < 4) ? x0[e] : x1[e - 4];
        o[e] = ff16(xv);
    }
    *(u16x8*)&out[(long)idx * 8] = o;
}

__global__ __launch_bounds__(256)
void concat_bias(const float* __restrict__ bq, const float* __restrict__ bk,
                 const float* __restrict__ bv, float* __restrict__ bqkv)
{
    int i = blockIdx.x * 256 + threadIdx.x;
    if (i < 768) bqkv[i] = bq[i];
    else if (i < 1536) bqkv[i] = bk[i - 768];
    else if (i < 2304) bqkv[i] = bv[i - 1536];
}

// pn rows: qnp[8192][12] then knp[8192][12] contiguous; fixed-order sum.
__global__ __launch_bounds__(256)
void finish_norms(const float* __restrict__ pn, float* __restrict__ qn, float* __restrict__ kn)
{
    int row = blockIdx.x * 256 + threadIdx.x;   // 0..16383
    const float* p = pn + (long)row * 12;
    float s = 0.f;
    #pragma unroll
    for (int c = 0; c < 12; ++c) s += p[c];
    if (row < BSR) qn[row] = s; else kn[row - BSR] = s;
}

// ---------------------------------------------------------------------------
// 256x256-tile distance GEMM, minimum-2-phase __syncthreads schedule
// (prefetch next tile into buf^1, compute buf[cur], ONE __syncthreads/tile).
// Single-term f16: Kd=768 (hi slots only), row stride lda/ldb = QS.
// ---------------------------------------------------------------------------
__global__ __launch_bounds__(512)
void gemm256_dist(const unsigned short* __restrict__ A, const unsigned short* __restrict__ B,
                  const float* __restrict__ rm, const float* __restrict__ rn,
                  float* __restrict__ C,
                  int N, int Kd, long lda, long ldb,
                  long sA, long sB, long sC, long sR)
{
    const int z = blockIdx.z;
    A += (long)z * sA;
    B += (long)z * sB;
    C += (long)z * sC;
    const float* rmz = rm + (long)z * sR;
    const float* rnz = rn + (long)z * sR;

    // bijective XCD swizzle over the 64 blocks of this batch
    int lid = blockIdx.y * gridDim.x + blockIdx.x;
    int xcd = lid & 7, pos = lid >> 3;
    int nlid = xcd * 8 + pos;
    const int bx = nlid & 7, by = nlid >> 3;

    __shared__ __align__(16) unsigned short lds[2 * 32768];  // 2 bufs x (A 16384 | B 16384) f16

    const int tid = threadIdx.x;
    const int lane = tid & 63;
    const int wave = tid >> 6;
    const int wm = wave >> 2, wn = wave & 3;   // 2 x 4 wave grid
    const int m0 = by * 256, n0 = bx * 256;
    const int r15 = lane & 15;
    const int g4 = lane >> 4;

    f32x4 acc[8][4] = {};

    long aB[4], bB[4];
    int lof[4];
    #pragma unroll
    for (int i = 0; i < 4; ++i) {
        int L = i * 512 + tid;          // 0..2047 chunk id (16B chunks)
        int row = L >> 3, ch = L & 7;
        int chs = ch ^ (row & 7);
        aB[i] = (long)(m0 + row) * lda * 2 + chs * 16;
        bB[i] = (long)(n0 + row) * ldb * 2 + chs * 16;
        lof[i] = L * 8;
    }

    const int NT = Kd >> 6;             // 12 K-tiles of 64

    // prologue: stage tile 0 into buf 0, full drain
    #pragma unroll
    for (int i = 0; i < 4; ++i) {
        gload_lds16((const char*)A + aB[i], &lds[lof[i]]);
        gload_lds16((const char*)B + bB[i], &lds[16384 + lof[i]]);
    }
    __syncthreads();

    int cur = 0;
    for (int t = 0; t < NT; ++t) {
        if (t + 1 < NT) {               // prefetch next tile into the other buffer
            long kb = (long)(t + 1) * 128;
            int off = (cur ^ 1) * 32768;
            #pragma unroll
            for (int i = 0; i < 4; ++i) {
                gload_lds16((const char*)A + aB[i] + kb, &lds[off + lof[i]]);
                gload_lds16((const char*)B + bB[i] + kb, &lds[off + 16384 + lof[i]]);
            }
        }
        const unsigned short* bufA = &lds[cur * 32768];
        const unsigned short* bufB = bufA + 16384;
        #pragma unroll
        for (int ks = 0; ks < 2; ++ks) {
            f16x8 af[8], bfr[4];
            #pragma unroll
            for (int i = 0; i < 8; ++i) {
                int r = wm * 128 + i * 16 + r15;
                int g = ks * 4 + g4;
                af[i] = *(const f16x8*)&bufA[r * 64 + (g ^ (r & 7)) * 8];
            }
            #pragma unroll
            for (int j = 0; j < 4; ++j) {
                int c = wn * 64 + j * 16 + r15;
                int g = ks * 4 + g4;
                bfr[j] = *(const f16x8*)&bufB[c * 64 + (g ^ (c & 7)) * 8];
            }
            #pragma unroll
            for (int i = 0; i < 8; ++i)
                #pragma unroll
                for (int j = 0; j < 4; ++j)
                    acc[i][j] = __builtin_amdgcn_mfma_f32_16x16x32_f16(
                        af[i], bfr[j], acc[i][j], 0, 0, 0);
        }
        __syncthreads();                // full drain: prefetch landed, reads done
        cur ^= 1;
    }

    // epilogue: C/D layout col=lane&15, row=(lane>>4)*4+reg
    float rnv[4];
    #pragma unroll
    for (int j = 0; j < 4; ++j)
        rnv[j] = rnz[n0 + wn * 64 + j * 16 + r15];
    #pragma unroll
    for (int i = 0; i < 8; ++i) {
        #pragma unroll
        for (int r = 0; r < 4; ++r) {
            int m = m0 + wm * 128 + i * 16 + g4 * 4 + r;
            float rmv = rmz[m];
            #pragma unroll
            for (int j = 0; j < 4; ++j) {
                int n = n0 + wn * 64 + j * 16 + r15;
                C[(long)m * N + n] = rmv + rnv[j] - 2.f * acc[i][j][r];
            }
        }
    }
}

// C[m][n] = epilogue( sum_k A[m][k]*B[n][k] ), NT f16 inputs, strides lda/ldb.
// Minimum-2-phase __syncthreads schedule (proven replay-stable).
// MODE 0: +bias[n] -> f32 C
// MODE 3: relu(+bias[n]) -> compact f16 oQ [m][768]
// MODE 4: combined QKV: seg 0 -> 2-slot q_s + qnp; 1 -> 2-slot k_s + knp;
//         2 -> f32 oVf with SINGLE-TERM K=768
template<int MODE>
__global__ __launch_bounds__(256)
void gemm_mfma(const unsigned short* __restrict__ A, const unsigned short* __restrict__ B,
               const float* __restrict__ bias,
               float* __restrict__ C,
               int M, int N, int Kd, long lda, long ldb,
               unsigned short* __restrict__ oQ, unsigned short* __restrict__ oK,
               float* __restrict__ oVf, float* __restrict__ pn)
{
    // ---- bijective XCD swizzle (T1/m204) ----
    const int nwgx = gridDim.x;
    const int nwg  = nwgx * gridDim.y;
    int lid = blockIdx.y * nwgx + blockIdx.x;
    int qq = nwg >> 3, rr = nwg & 7;
    int xcd = lid & 7, pos = lid >> 3;
    int nlid = (xcd < rr ? xcd * (qq + 1) : rr * (qq + 1) + (xcd - rr) * qq) + pos;
    const int bx = nlid % nwgx;
    const int by = nlid / nwgx;

    __shared__ __align__(16) unsigned short lds[2 * 16384];  // 2 bufs x (A 8192 | B 8192)

    const int tid = threadIdx.x;
    const int lane = tid & 63;
    const int wave = tid >> 6;
    const int wm = wave >> 1, wn = wave & 1;
    const int m0 = by * 128, n0 = bx * 128;
    const int r15 = lane & 15;
    const int g4 = lane >> 4;

    f32x4 acc[4][4] = {};

    long aByte[4], bByte[4];
    int ldsOff[4];
    #pragma unroll
    for (int i = 0; i < 4; ++i) {
        int L = i * 256 + tid;
        int row = L >> 3, ch = L & 7;
        int chs = ch ^ (row & 7);
        aByte[i] = (long)(m0 + row) * lda * 2 + chs * 16;
        bByte[i] = (long)(n0 + row) * ldb * 2 + chs * 16;
        ldsOff[i] = L * 8;
    }

    int NT = Kd >> 6;                          // 36 (or 12 for v segment below)
    if (MODE == 4 && n0 >= 1536) NT = 12;      // v: single-term f16 (hi slots only)

    // prologue: stage tile 0 into buf 0, full drain
    #pragma unroll
    for (int i = 0; i < 4; ++i) {
        gload_lds16((const char*)A + aByte[i], &lds[ldsOff[i]]);
        gload_lds16((const char*)B + bByte[i], &lds[8192 + ldsOff[i]]);
    }
    __syncthreads();

    int cur = 0;
    for (int t = 0; t < NT; ++t) {
        if (t + 1 < NT) {
            long kb = (long)(t + 1) * 128;
            int off = (cur ^ 1) * 16384;
            #pragma unroll
            for (int i = 0; i < 4; ++i) {
                gload_lds16((const char*)A + aByte[i] + kb, &lds[off + ldsOff[i]]);
                gload_lds16((const char*)B + bByte[i] + kb, &lds[off + 8192 + ldsOff[i]]);
            }
        }
        const unsigned short* bufA = &lds[cur * 16384];
        const unsigned short* bufB = bufA + 8192;
        #pragma unroll
        for (int ks = 0; ks < 2; ++ks) {
            f16x8 af[4], bfr[4];
            #pragma unroll
            for (int i = 0; i < 4; ++i) {
                int row = wm * 64 + i * 16 + r15;
                int chs = (ks * 4 + g4) ^ (r15 & 7);
                af[i] = *(const f16x8*)&bufA[row * 64 + chs * 8];
            }
            #pragma unroll
            for (int j = 0; j < 4; ++j) {
                int row = wn * 64 + j * 16 + r15;
                int chs = (ks * 4 + g4) ^ (r15 & 7);
                bfr[j] = *(const f16x8*)&bufB[row * 64 + chs * 8];
            }
            #pragma unroll
            for (int i = 0; i < 4; ++i)
                #pragma unroll
                for (int j = 0; j < 4; ++j)
                    acc[i][j] = __builtin_amdgcn_mfma_f32_16x16x32_f16(
                        af[i], bfr[j], acc[i][j], 0, 0, 0);
        }
        __syncthreads();
        cur ^= 1;
    }

    float bj[4];
    #pragma unroll
    for (int j = 0; j < 4; ++j) {
        int n = n0 + wn * 64 + j * 16 + r15;
        bj[j] = bias[n];
    }

    if (MODE == 0) {
        #pragma unroll
        for (int i = 0; i < 4; ++i) {
            #pragma unroll
            for (int r = 0; r < 4; ++r) {
                int m = m0 + wm * 64 + i * 16 + g4 * 4 + r;
                #pragma unroll
                for (int j = 0; j < 4; ++j) {
                    int n = n0 + wn * 64 + j * 16 + r15;
                    C[(long)m * N + n] = acc[i][j][r] + bj[j];
                }
            }
        }
    }

    if (MODE == 3) {
        #pragma unroll
        for (int i = 0; i < 4; ++i) {
            #pragma unroll
            for (int r = 0; r < 4; ++r) {
                int m = m0 + wm * 64 + i * 16 + g4 * 4 + r;
                #pragma unroll
                for (int j = 0; j < 4; ++j) {
                    int e = n0 + wn * 64 + j * 16 + r15;
                    float xv = fmaxf(acc[i][j][r] + bj[j], 0.f);
                    oQ[(long)m * DD + e] = ff16(xv);
                }
            }
        }
    }

    if (MODE == 4) {
        const int seg = n0 / 768;                       // block-uniform: 0=q 1=k 2=v
        const int e0 = n0 - seg * 768 + wn * 64;
        const int chunk = (bx - seg * 6) * 2 + wn;      // 0..11 within segment
        #pragma unroll
        for (int i = 0; i < 4; ++i) {
            #pragma unroll
            for (int r = 0; r < 4; ++r) {
                int m = m0 + wm * 64 + i * 16 + g4 * 4 + r;
                float vals[4];
                #pragma unroll
                for (int j = 0; j < 4; ++j) vals[j] = acc[i][j][r] + bj[j];
                if (seg == 2) {
                    #pragma unroll
                    for (int j = 0; j < 4; ++j)
                        oVf[(long)m * DD + e0 + j * 16 + r15] = vals[j];
                } else {
                    unsigned short* os = (seg == 0) ? oQ : oK;
                    #pragma unroll
                    for (int j = 0; j < 4; ++j) {
                        float xv = vals[j];
                        _Float16 hh = (_Float16)xv;
                        float hf = (float)hh;
                        float l = xv - hf;
                        long base = (long)m * QS + e0 + j * 16 + r15;
                        os[base]      = __builtin_bit_cast(unsigned short, hh);
                        os[base + DD] = ff16(l * 64.f);
                    }
                    float s = vals[0]*vals[0] + vals[1]*vals[1]
                            + vals[2]*vals[2] + vals[3]*vals[3];
                    s += __shfl_xor(s, 1); s += __shfl_xor(s, 2);
                    s += __shfl_xor(s, 4); s += __shfl_xor(s, 8);
                    if (r15 == 0)
                        pn[(seg ? (long)BSR * 12 : 0) + (long)m * 12 + chunk] = s;
                }
            }
        }
    }
}

// One WAVE per query row, zero LDS, zero barriers.
// Phase 1: streaming per-lane top-8 VALUES (u32, exec-masked sorted insert).
// Phase 2: threshold selection via common-prefix-narrowed binary search on
//          value bits (bitplane ballots); exact tie-break by index from d[];
//          wave-uniform fallback rebuilds u64 keys + 33-iteration tournament
//          on saturation (expected never).
// Phase 3: boundary-gap guard (exact fp32 recompute from 2-slot splits).
// Phase 4: rank-based index assignment; f32 v gather batched 4 rows.
// Writes COMPACT f16 topo [g][768].
__global__ __launch_bounds__(256)
void select_mean(const float* __restrict__ dist, const float* __restrict__ v,
                 const unsigned short* __restrict__ q_s, const unsigned short* __restrict__ k_s,
                 const float* __restrict__ qn, const float* __restrict__ kn,
                 unsigned short* __restrict__ topo_f16)
{
    const int wv = threadIdx.x >> 6;
    const int lane = threadIdx.x & 63;
    const int g = blockIdx.x * 4 + wv;      // global row 0..8191
    const int b = g >> 11;
    const float* drow = dist + (long)b * SS * SS + (long)(g & (SS - 1)) * SS;
    const float* vb   = v    + (long)b * SS * DD;

    float d[32];
    unsigned h0 = 0xffffffffu, h1 = 0xffffffffu, h2 = 0xffffffffu, h3 = 0xffffffffu,
             h4 = 0xffffffffu, h5 = 0xffffffffu, h6 = 0xffffffffu, h7 = 0xffffffffu;
    const f32x4* dr4 = (const f32x4*)drow;
    #pragma unroll
    for (int c = 0; c < 8; ++c) {
        f32x4 tv = dr4[c * 64 + lane];
        #pragma unroll
        for (int i = 0; i < 4; ++i) {
            float x = fmaxf(tv[i], 0.f);
            d[c * 4 + i] = x;
            unsigned xv = __builtin_bit_cast(unsigned, x);
            if (xv < h7) {                  // exec-masked sorted insert (values only)
                bool l0 = xv < h0, l1 = xv < h1, l2 = xv < h2, l3 = xv < h3,
                     l4 = xv < h4, l5 = xv < h5, l6 = xv < h6;
                h7 = l6 ? h6 : xv;
                h6 = l6 ? (l5 ? h5 : xv) : h6;
                h5 = l5 ? (l4 ? h4 : xv) : h5;
                h4 = l4 ? (l3 ? h3 : xv) : h4;
                h3 = l3 ? (l2 ? h2 : xv) : h3;
                h2 = l2 ? (l1 ? h1 : xv) : h2;
                h1 = l1 ? (l0 ? h0 : xv) : h1;
                h0 = l0 ? xv : h0;
            }
        }
    }

    unsigned sel = 0;
    float d32v = 0.f, d33v = 0.f;

    // ---- Phase 2: narrowed binary search for the rank-31 value ----
    unsigned lo = h0, hi = h7;
    #pragma unroll
    for (int off = 32; off; off >>= 1) {
        unsigned ol = __shfl_xor(lo, off); lo = ol < lo ? ol : lo;
        unsigned oh = __shfl_xor(hi, off); hi = oh > hi ? oh : hi;
    }
    unsigned diffb = lo ^ hi;
    unsigned Vv; int nb;
    if (diffb == 0) { Vv = lo; nb = -1; }
    else {
        nb = 31 - __builtin_clz(diffb);
        Vv = (nb >= 31) ? 0u : (lo & ~((1u << (nb + 1)) - 1u));
    }
    for (int bit = nb; bit >= 0; --bit) {
        unsigned candv = Vv | (1u << bit);
        int c = (h0 < candv) + (h1 < candv) + (h2 < candv) + (h3 < candv)
              + (h4 < candv) + (h5 < candv) + (h6 < candv) + (h7 < candv);
        int tot = (int)__popcll(__ballot(c & 1))
                + 2 * (int)__popcll(__ballot(c & 2))
                + 4 * (int)__popcll(__ballot(c & 4))
                + 8 * (int)__popcll(__ballot(c & 8));
        if (tot <= 31) Vv = candv;
    }
    bool fallback = __any(h7 <= Vv);

    if (!fallback) {
        int cl = (h0 < Vv) + (h1 < Vv) + (h2 < Vv) + (h3 < Vv)
               + (h4 < Vv) + (h5 < Vv) + (h6 < Vv) + (h7 < Vv);
        int c_lt = (int)__popcll(__ballot(cl & 1))
                 + 2 * (int)__popcll(__ballot(cl & 2))
                 + 4 * (int)__popcll(__ballot(cl & 4))
                 + 8 * (int)__popcll(__ballot(cl & 8));
        #pragma unroll
        for (int s = 0; s < 32; ++s)
            if (__builtin_bit_cast(unsigned, d[s]) < Vv) sel |= 1u << s;
        int need = KNEI - c_lt;
        for (int t2 = 0; t2 < need; ++t2) {
            unsigned mi = 0xffffffffu;
            #pragma unroll
            for (int s = 0; s < 32; ++s) {
                bool eq = (__builtin_bit_cast(unsigned, d[s]) == Vv) && !((sel >> s) & 1u);
                unsigned jj = (unsigned)((s >> 2) * 256 + lane * 4 + (s & 3));
                if (eq && jj < mi) mi = jj;
            }
            #pragma unroll
            for (int off = 32; off; off >>= 1) {
                unsigned o = __shfl_xor(mi, off);
                mi = o < mi ? o : mi;
            }
            if (mi != 0xffffffffu && lane == ((mi >> 2) & 63))
                sel |= 1u << (((mi >> 8) << 2) | (mi & 3));
        }
        d32v = __builtin_bit_cast(float, Vv);
        int ce = (h0 <= Vv) + (h1 <= Vv) + (h2 <= Vv) + (h3 <= Vv)
               + (h4 <= Vv) + (h5 <= Vv) + (h6 <= Vv) + (h7 <= Vv);
        int c_le = (int)__popcll(__ballot(ce & 1))
                 + 2 * (int)__popcll(__ballot(ce & 2))
                 + 4 * (int)__popcll(__ballot(ce & 4))
                 + 8 * (int)__popcll(__ballot(ce & 8));
        if (c_le >= 33) {
            d33v = d32v;
        } else {
            unsigned mv = 0xffffffffu;
            if (h0 > Vv && h0 < mv) mv = h0;
            if (h1 > Vv && h1 < mv) mv = h1;
            if (h2 > Vv && h2 < mv) mv = h2;
            if (h3 > Vv && h3 < mv) mv = h3;
            if (h4 > Vv && h4 < mv) mv = h4;
            if (h5 > Vv && h5 < mv) mv = h5;
            if (h6 > Vv && h6 < mv) mv = h6;
            if (h7 > Vv && h7 < mv) mv = h7;
            #pragma unroll
            for (int off = 32; off; off >>= 1) {
                unsigned o = __shfl_xor(mv, off);
                mv = o < mv ? o : mv;
            }
            d33v = __builtin_bit_cast(float, mv);
        }
    } else {
        // ---- rare saturation path: rebuild u64 keys, 33-iteration tournament ----
        unsigned long long g0 = ~0ull, g1 = ~0ull, g2 = ~0ull, g3 = ~0ull,
                           g4b = ~0ull, g5 = ~0ull, g6 = ~0ull, g7 = ~0ull;
        #pragma unroll
        for (int s = 0; s < 32; ++s) {
            unsigned long long kk =
                ((unsigned long long)__builtin_bit_cast(unsigned, d[s]) << 32)
                | (unsigned)((s >> 2) * 256 + lane * 4 + (s & 3));
            if (kk < g7) {
                bool l0 = kk < g0, l1 = kk < g1, l2 = kk < g2, l3 = kk < g3,
                     l4 = kk < g4b, l5 = kk < g5, l6 = kk < g6;
                g7 = l6 ? g6 : kk;
                g6 = l6 ? (l5 ? g5 : kk) : g6;
                g5 = l5 ? (l4 ? g4b : kk) : g5;
                g4b = l4 ? (l3 ? g3 : kk) : g4b;
                g3 = l3 ? (l2 ? g2 : kk) : g3;
                g2 = l2 ? (l1 ? g1 : kk) : g2;
                g1 = l1 ? (l0 ? g0 : kk) : g1;
                g0 = l0 ? kk : g0;
            }
        }
        int cnt = 0;
        for (int t = 0; t < 33; ++t) {
            unsigned long long best = g0;
            #pragma unroll
            for (int off = 32; off; off >>= 1) {
                unsigned long long o = __shfl_xor(best, off);
                best = o < best ? o : best;
            }
            if (t == 32) {
                d33v = __builtin_bit_cast(float, (unsigned)(best >> 32));
                break;
            }
            int j = (int)(unsigned)best;
            bool won = (lane == ((j >> 2) & 63));
            if (won) sel |= 1u << (((j >> 8) << 2) | (j & 3));
            if (t == 31) d32v = __builtin_bit_cast(float, (unsigned)(best >> 32));

            if (won) cnt++;
            bool needScan = won && (cnt >= 8);
            bool adv = won && (cnt < 8);
            g0 = adv ? g1 : g0;  g1 = adv ? g2 : g1;  g2 = adv ? g3 : g2;
            g3 = adv ? g4b : g3; g4b = adv ? g5 : g4b; g5 = adv ? g6 : g5;
            g6 = adv ? g7 : g6;  g7 = adv ? ~0ull : g7;
            if (__any(needScan)) {
                if (needScan) {
                    float bv = FLT_MAX; int bs = 0; bool found = false;
                    #pragma unroll
                    for (int s = 0; s < 32; ++s) {
                        bool ok = !((sel >> s) & 1u);
                        bool lt = ok && (d[s] < bv);
                        bv = lt ? d[s] : bv; bs = lt ? s : bs; found |= ok;
                    }
                    g0 = found
                       ? (((unsigned long long)__builtin_bit_cast(unsigned, bv) << 32)
                          | (unsigned)((bs >> 2) * 256 + lane * 4 + (bs & 3)))
                       : ~0ull;
                }
            }
        }
    }

    // ---- Phase 3: boundary-gap guard (exact fp32 recompute for the window) ----
    if (d33v - d32v < MARGIN) {
        float lo2 = d32v - MARGIN, hi2 = d33v + MARGIN;
        unsigned cand = 0;
        #pragma unroll
        for (int s = 0; s < 32; ++s)
            if (d[s] >= lo2 && d[s] <= hi2) cand |= 1u << s;

        const unsigned short* qrow = q_s + (long)g * QS;
        const u16x4* qh = (const u16x4*)&qrow[lane * 12];
        const u16x4* ql = (const u16x4*)&qrow[DD + lane * 12];
        #pragma unroll
        for (int s = 0; s < 32; ++s) {
            unsigned long long m = __ballot((cand >> s) & 1u);
            while (m) {
                int l2 = __ffsll(m) - 1;
                m &= m - 1;
                int j = (s >> 2) * 256 + l2 * 4 + (s & 3);
                const unsigned short* krow = k_s + ((long)b * SS + j) * QS;
                const u16x4* kh = (const u16x4*)&krow[lane * 12];
                const u16x4* kl = (const u16x4*)&krow[DD + lane * 12];
                float part = 0.f;
                #pragma unroll
                for (int c = 0; c < 3; ++c) {
                    u16x4 qa = qh[c], qb = ql[c], ka = kh[c], kb2 = kl[c];
                    #pragma unroll
                    for (int e = 0; e < 4; ++e) {
                        float qv = f16f(qa[e]) + f16f(qb[e]) * 0.015625f;
                        float kv = f16f(ka[e]) + f16f(kb2[e]) * 0.015625f;
                        part = fmaf(qv, kv, part);
                    }
                }
                #pragma unroll
                for (int off = 32; off; off >>= 1) part += __shfl_xor(part, off);
                float dd = qn[g] + kn[(long)b * SS + j] - 2.f * part;
                dd = fmaxf(dd, 0.f);
                if (lane == l2) d[s] = dd;
            }
        }

        sel &= ~cand;
        int C = 0;
        #pragma unroll
        for (int s = 0; s < 32; ++s) C += (int)__popcll(__ballot((sel >> s) & 1u));
        int need = KNEI - C;
        for (int t = 0; t < need; ++t) {
            unsigned long long best = ~0ull;
            #pragma unroll
            for (int s = 0; s < 32; ++s) {
                if (((cand >> s) & 1u) && !((sel >> s) & 1u)) {
                    unsigned long long key =
                        ((unsigned long long)__builtin_bit_cast(unsigned, d[s]) << 32)
                        | (unsigned)((s >> 2) * 256 + lane * 4 + (s & 3));
                    best = key < best ? key : best;
                }
            }
            #pragma unroll
            for (int off = 32; off; off >>= 1) {
                unsigned long long o = __shfl_xor(best, off);
                best = o < best ? o : best;
            }
            if (best != ~0ull) {
                int j = (int)(unsigned)best;
                if (lane == ((j >> 2) & 63)) sel |= 1u << (((j >> 8) << 2) | (j & 3));
            }
        }
    }

    // ---- Phase 4: rank-based selected-index assignment + batched f32 gather ----
    int myj = 0;
    {
        int target = lane & 31;            // lane p (and p+32) own the p-th selected index
        int cum = 0;
        #pragma unroll
        for (int s = 0; s < 32; ++s) {
            unsigned long long m = __ballot((sel >> s) & 1u);
            int c = (int)__popcll(m);
            if (target >= cum && target < cum + c) {
                int nth = target - cum;
                unsigned long long mm = m;
                int base = 0;
                int c32 = (int)__popcll(mm & 0xffffffffull);
                if (nth >= c32) { nth -= c32; mm >>= 32; base += 32; }
                int c16 = (int)__popcll(mm & 0xffffull);
                if (nth >= c16) { nth -= c16; mm >>= 16; base += 16; }
                int c8 = (int)__popcll(mm & 0xffull);
                if (nth >= c8) { nth -= c8; mm >>= 8; base += 8; }
                int c4 = (int)__popcll(mm & 0xfull);
                if (nth >= c4) { nth -= c4; mm >>= 4; base += 4; }
                int c2 = (int)__popcll(mm & 0x3ull);
                if (nth >= c2) { nth -= c2; mm >>= 2; base += 2; }
                int c1 = (int)(mm & 1ull);
                if (nth >= c1) { base += 1; }
                myj = (s >> 2) * 256 + base * 4 + (s & 3);
            }
            cum += c;
        }
    }
    f32x4 a0 = {0.f, 0.f, 0.f, 0.f}, a1 = a0, a2 = a0;
    #pragma unroll
    for (int tb = 0; tb < 8; ++tb) {
        f32x4 r0[4], r1[4], r2[4];
        #pragma unroll
        for (int u = 0; u < 4; ++u) {
            int j = __shfl(myj, tb * 4 + u);
            const f32x4* vr = (const f32x4*)(vb + (long)j * DD);
            r0[u] = vr[lane];
            r1[u] = vr[lane + 64];
            r2[u] = vr[lane + 128];
        }
        #pragma unroll
        for (int u = 0; u < 4; ++u) {
            a0 += r0[u];
            a1 += r1[u];
            a2 += r2[u];
        }
    }
    const float sc = 1.0f / 32.0f;
    unsigned short* trow = topo_f16 + (long)g * DD;
    #pragma unroll
    for (int c = 0; c < 3; ++c) {
        f32x4 x = (c == 0) ? a0 : (c == 1) ? a1 : a2;
        u16x4 hi4;
        #pragma unroll
        for (int e = 0; e < 4; ++e) hi4[e] = ff16(x[e] * sc);
        *(u16x4*)&trow[c * 256 + lane * 4] = hi4;
    }
}

extern "C" void kernel_launch(void* const* d_in, const int* in_sizes, int n_in,
                              void* d_out, int out_size, void* d_ws, size_t ws_size,
                              hipStream_t stream)
{
    const float* hs = (const float*)d_in[0];
    const float* Wq = (const float*)d_in[1];
    const float* bq = (const float*)d_in[2];
    const float* Wk = (const float*)d_in[3];
    const float* bk = (const float*)d_in[4];
    const float* Wv = (const float*)d_in[5];
    const float* bv = (const float*)d_in[6];
    const float* W1 = (const float*)d_in[7];
    const float* b1 = (const float*)d_in[8];
    const float* W2 = (const float*)d_in[9];
    const float* b2 = (const float*)d_in[10];
    float* out = (float*)d_out;

    // ---- workspace layout (peak ~192 MB), time-overlaid ----
    char* w = (char*)d_ws;
    const long DISTB = (long)BB * SS * SS * 4;        // 67,108,864
    const long VB    = (long)BSR * DD * 4;            // 25,165,824 (f32 v)
    const long WSPL  = (long)DD * K2;                 // elems per 3-term split weight

    float*          dist   = (float*)w;                               // [0, 67.1M)
    unsigned short* h_f16  = (unsigned short*)w;                      // overlays dead dist
    float*          v      = (float*)(w + DISTB);                     // f32 v
    unsigned short* q_s    = (unsigned short*)(w + DISTB + VB);       // 2-slot
    unsigned short* k_s    = q_s + (long)BSR * QS;                    // 2-slot
    unsigned short* hs_s   = k_s + (long)BSR * QS;                    // 3-term A-layout
    unsigned short* topo_f16 = hs_s;                                  // overlays dead hs_s
    unsigned short* Wqkv_s = hs_s + (long)BSR * K2;                   // 3 weight splits adjacent
    unsigned short* W1_f16 = Wqkv_s;                                  // overlays dead Wqkv
    unsigned short* W2_f16 = Wqkv_s + (long)DD * DD;
    char* tail  = (char*)(Wqkv_s + 3 * WSPL);
    float* qn   = (float*)tail;                        // 8192
    float* kn   = qn + BSR;                            // 8192
    float* pn   = kn + BSR;                            // qnp[8192][12] + knp[8192][12]
    float* bqkv = pn + (long)2 * BSR * 12;             // 2304

    dim3 blk(256);
    const int convW  = (DD * (DD / 8)) / 256;          // 288 blocks per weight
    const int convHS = (BSR * (DD / 8)) / 256;         // 3072 blocks

    concat_bias<<<9, blk, 0, stream>>>(bq, bk, bv, bqkv);
    split_f16<2><<<convW, blk, 0, stream>>>(Wq, Wqkv_s, DD);
    split_f16<2><<<convW, blk, 0, stream>>>(Wk, Wqkv_s + WSPL, DD);
    split_f16<2><<<convW, blk, 0, stream>>>(Wv, Wqkv_s + 2 * WSPL, DD);
    split_f16<1><<<convHS, blk, 0, stream>>>(hs, hs_s, DD);

    // fused QKV gemm: q -> 2-slot q_s + norms, k -> 2-slot k_s + norms, v -> f32 (K=768)
    gemm_mfma<4><<<dim3(2304 / 128, BSR / 128, 1), blk, 0, stream>>>(
        hs_s, Wqkv_s, bqkv, nullptr, BSR, 2304, K2, K2, K2,
        q_s, k_s, v, pn);

    // W1/W2 compact f16 converts into dead Wqkv region
    conv_f16<<<convW, blk, 0, stream>>>(W1, W1_f16);
    conv_f16<<<convW, blk, 0, stream>>>(W2, W2_f16);
    finish_norms<<<(2 * BSR) / 256, blk, 0, stream>>>(pn, qn, kn);

    // squared distance matrix per batch: single-term f16 (Kd=768, stride QS)
    gemm256_dist<<<dim3(SS / 256, SS / 256, BB), dim3(512), 0, stream>>>(
        q_s, k_s, qn, kn, dist, SS, DD, QS, QS,
        (long)SS * QS, (long)SS * QS, (long)SS * SS, SS);

    select_mean<<<BSR / 4, blk, 0, stream>>>(dist, v, q_s, k_s, qn, kn, topo_f16);

    // MLP single-term f16: gemm1 -> compact f16 h (relu fused), gemm2 -> f32 out
    gemm_mfma<3><<<dim3(DD / 128, BSR / 128, 1), blk, 0, stream>>>(
        topo_f16, W1_f16, b1, nullptr, BSR, DD, DD, DD, DD,
        h_f16, nullptr, nullptr, nullptr);
    gemm_mfma<0><<<dim3(DD / 128, BSR / 128, 1), blk, 0, stream>>>(
        h_f16, W2_f16, b2, out, BSR, DD, DD, DD, DD,
        nullptr, nullptr, nullptr, nullptr);
}

// Round 18
// 256.887 us; speedup vs baseline: 4.8757x; 1.0513x over previous
//
#include <hip/hip_runtime.h>
#include <float.h>

#define DD 768
#define SS 2048
#define BB 4
#define BSR (BB*SS)   // 8192 total rows
#define KNEI 32
#define K2 (3*DD)     // 2304: [hi | x | y] split concat along K (hs_s only)
#define QS (2*DD)     // 1536: 2-slot q_s/k_s layout [h, l*2^6]
#define MARGIN 0.12f  // >=6 sigma of single-term f16 pairwise dist error

typedef __attribute__((ext_vector_type(8))) _Float16 f16x8;
typedef __attribute__((ext_vector_type(4))) float f32x4;
typedef __attribute__((ext_vector_type(8))) unsigned short u16x8;
typedef __attribute__((ext_vector_type(4))) unsigned short u16x4;

__device__ __forceinline__ float f16f(unsigned short u) {
    return (float)__builtin_bit_cast(_Float16, u);
}
__device__ __forceinline__ unsigned short ff16(float x) {
    return __builtin_bit_cast(unsigned short, (_Float16)x);
}
__device__ __forceinline__ unsigned short rne_bf16(float x) {
    unsigned u = __builtin_bit_cast(unsigned, x);
    unsigned r = u + 0x7FFFu + ((u >> 16) & 1u);
    return (unsigned short)(r >> 16);
}
__device__ __forceinline__ float bf16f(unsigned short h) {
    return __builtin_bit_cast(float, (unsigned)h << 16);
}

__device__ __forceinline__ void gload_lds16(const void* g, void* l) {
    __builtin_amdgcn_global_load_lds(
        (const __attribute__((address_space(1))) unsigned int*)g,
        (__attribute__((address_space(3))) unsigned int*)l, 16, 0, 0);
}

// fp32 -> 3-slot f16 split with power-of-2 rebalanced correction slots.
// A-layout (LO_SLOT=1): [h, l*2^6, h*2^-6];  B-layout (LO_SLOT=2): [h, h*2^-6, l*2^6]
template<int LO_SLOT>
__global__ __launch_bounds__(256)
void split_f16(const float* __restrict__ in, unsigned short* __restrict__ out, int Kc)
{
    int idx = blockIdx.x * 256 + threadIdx.x;
    int perRow = Kc >> 3;
    int row = idx / perRow, c8 = idx - row * perRow;
    const float* src = in + (long)row * Kc + c8 * 8;
    f32x4 x0 = *(const f32x4*)&src[0];
    f32x4 x1 = *(const f32x4*)&src[4];
    u16x8 hi, lsc, hsc;
    #pragma unroll
    for (int e = 0; e < 8; ++e) {
        float xv = (e < 4) ? x0[e] : x1[e - 4];
        _Float16 h = (_Float16)xv;
        float hf = (float)h;
        float l = xv - hf;
        hi[e]  = __builtin_bit_cast(unsigned short, h);
        lsc[e] = ff16(l * 64.f);
        hsc[e] = ff16(hf * 0.015625f);
    }
    long base = (long)row * (3 * Kc) + c8 * 8;
    *(u16x8*)&out[base] = hi;
    *(u16x8*)&out[base + Kc]     = (LO_SLOT == 1) ? lsc : hsc;
    *(u16x8*)&out[base + 2 * Kc] = (LO_SLOT == 1) ? hsc : lsc;
}

// plain f32 -> f16 compact convert (for single-term MLP weights)
__global__ __launch_bounds__(256)
void conv_f16(const float* __restrict__ in, unsigned short* __restrict__ out)
{
    int idx = blockIdx.x * 256 + threadIdx.x;   // 8 elems per thread
    const float* src = in + (long)idx * 8;
    f32x4 x0 = *(const f32x4*)&src[0];
    f32x4 x1 = *(const f32x4*)&src[4];
    u16x8 o;
    #pragma unroll
    for (int e = 0; e < 8; ++e) {
        float xv = (e < 4) ? x0[e] : x1[e - 4];
        o[e] = ff16(xv);
    }
    *(u16x8*)&out[(long)idx * 8] = o;
}

__global__ __launch_bounds__(256)
void concat_bias(const float* __restrict__ bq, const float* __restrict__ bk,
                 const float* __restrict__ bv, float* __restrict__ bqkv)
{
    int i = blockIdx.x * 256 + threadIdx.x;
    if (i < 768) bqkv[i] = bq[i];
    else if (i < 1536) bqkv[i] = bk[i - 768];
    else if (i < 2304) bqkv[i] = bv[i - 1536];
}

// pn rows: qnp[8192][12] then knp[8192][12] contiguous; fixed-order sum.
__global__ __launch_bounds__(256)
void finish_norms(const float* __restrict__ pn, float* __restrict__ qn, float* __restrict__ kn)
{
    int row = blockIdx.x * 256 + threadIdx.x;   // 0..16383
    const float* p = pn + (long)row * 12;
    float s = 0.f;
    #pragma unroll
    for (int c = 0; c < 12; ++c) s += p[c];
    if (row < BSR) qn[row] = s; else kn[row - BSR] = s;
}

// ---------------------------------------------------------------------------
// 256x256-tile distance GEMM, minimum-2-phase __syncthreads schedule
// (prefetch next tile into buf^1, compute buf[cur], ONE __syncthreads/tile).
// Single-term f16: Kd=768 (hi slots only), row stride lda/ldb = QS.
// ---------------------------------------------------------------------------
__global__ __launch_bounds__(512)
void gemm256_dist(const unsigned short* __restrict__ A, const unsigned short* __restrict__ B,
                  const float* __restrict__ rm, const float* __restrict__ rn,
                  float* __restrict__ C,
                  int N, int Kd, long lda, long ldb,
                  long sA, long sB, long sC, long sR)
{
    const int z = blockIdx.z;
    A += (long)z * sA;
    B += (long)z * sB;
    C += (long)z * sC;
    const float* rmz = rm + (long)z * sR;
    const float* rnz = rn + (long)z * sR;

    // bijective XCD swizzle over the 64 blocks of this batch
    int lid = blockIdx.y * gridDim.x + blockIdx.x;
    int xcd = lid & 7, pos = lid >> 3;
    int nlid = xcd * 8 + pos;
    const int bx = nlid & 7, by = nlid >> 3;

    __shared__ __align__(16) unsigned short lds[2 * 32768];  // 2 bufs x (A 16384 | B 16384) f16

    const int tid = threadIdx.x;
    const int lane = tid & 63;
    const int wave = tid >> 6;
    const int wm = wave >> 2, wn = wave & 3;   // 2 x 4 wave grid
    const int m0 = by * 256, n0 = bx * 256;
    const int r15 = lane & 15;
    const int g4 = lane >> 4;

    f32x4 acc[8][4] = {};

    long aB[4], bB[4];
    int lof[4];
    #pragma unroll
    for (int i = 0; i < 4; ++i) {
        int L = i * 512 + tid;          // 0..2047 chunk id (16B chunks)
        int row = L >> 3, ch = L & 7;
        int chs = ch ^ (row & 7);
        aB[i] = (long)(m0 + row) * lda * 2 + chs * 16;
        bB[i] = (long)(n0 + row) * ldb * 2 + chs * 16;
        lof[i] = L * 8;
    }

    const int NT = Kd >> 6;             // 12 K-tiles of 64

    // prologue: stage tile 0 into buf 0, full drain
    #pragma unroll
    for (int i = 0; i < 4; ++i) {
        gload_lds16((const char*)A + aB[i], &lds[lof[i]]);
        gload_lds16((const char*)B + bB[i], &lds[16384 + lof[i]]);
    }
    __syncthreads();

    int cur = 0;
    for (int t = 0; t < NT; ++t) {
        if (t + 1 < NT) {               // prefetch next tile into the other buffer
            long kb = (long)(t + 1) * 128;
            int off = (cur ^ 1) * 32768;
            #pragma unroll
            for (int i = 0; i < 4; ++i) {
                gload_lds16((const char*)A + aB[i] + kb, &lds[off + lof[i]]);
                gload_lds16((const char*)B + bB[i] + kb, &lds[off + 16384 + lof[i]]);
            }
        }
        const unsigned short* bufA = &lds[cur * 32768];
        const unsigned short* bufB = bufA + 16384;
        #pragma unroll
        for (int ks = 0; ks < 2; ++ks) {
            f16x8 af[8], bfr[4];
            #pragma unroll
            for (int i = 0; i < 8; ++i) {
                int r = wm * 128 + i * 16 + r15;
                int g = ks * 4 + g4;
                af[i] = *(const f16x8*)&bufA[r * 64 + (g ^ (r & 7)) * 8];
            }
            #pragma unroll
            for (int j = 0; j < 4; ++j) {
                int c = wn * 64 + j * 16 + r15;
                int g = ks * 4 + g4;
                bfr[j] = *(const f16x8*)&bufB[c * 64 + (g ^ (c & 7)) * 8];
            }
            #pragma unroll
            for (int i = 0; i < 8; ++i)
                #pragma unroll
                for (int j = 0; j < 4; ++j)
                    acc[i][j] = __builtin_amdgcn_mfma_f32_16x16x32_f16(
                        af[i], bfr[j], acc[i][j], 0, 0, 0);
        }
        __syncthreads();                // full drain: prefetch landed, reads done
        cur ^= 1;
    }

    // epilogue: C/D layout col=lane&15, row=(lane>>4)*4+reg
    float rnv[4];
    #pragma unroll
    for (int j = 0; j < 4; ++j)
        rnv[j] = rnz[n0 + wn * 64 + j * 16 + r15];
    #pragma unroll
    for (int i = 0; i < 8; ++i) {
        #pragma unroll
        for (int r = 0; r < 4; ++r) {
            int m = m0 + wm * 128 + i * 16 + g4 * 4 + r;
            float rmv = rmz[m];
            #pragma unroll
            for (int j = 0; j < 4; ++j) {
                int n = n0 + wn * 64 + j * 16 + r15;
                C[(long)m * N + n] = rmv + rnv[j] - 2.f * acc[i][j][r];
            }
        }
    }
}

// C[m][n] = epilogue( sum_k A[m][k]*B[n][k] ), NT f16 inputs, strides lda/ldb.
// Minimum-2-phase __syncthreads schedule (proven replay-stable).
// MODE 0: +bias[n] -> f32 C
// MODE 3: relu(+bias[n]) -> compact f16 oQ [m][768]
// MODE 4: combined QKV: seg 0 -> 2-slot q_s + qnp; 1 -> 2-slot k_s + knp;
//         2 -> bf16 oV with SINGLE-TERM K=768
template<int MODE>
__global__ __launch_bounds__(256)
void gemm_mfma(const unsigned short* __restrict__ A, const unsigned short* __restrict__ B,
               const float* __restrict__ bias,
               float* __restrict__ C,
               int M, int N, int Kd, long lda, long ldb,
               unsigned short* __restrict__ oQ, unsigned short* __restrict__ oK,
               unsigned short* __restrict__ oV, float* __restrict__ pn)
{
    // ---- bijective XCD swizzle (T1/m204) ----
    const int nwgx = gridDim.x;
    const int nwg  = nwgx * gridDim.y;
    int lid = blockIdx.y * nwgx + blockIdx.x;
    int qq = nwg >> 3, rr = nwg & 7;
    int xcd = lid & 7, pos = lid >> 3;
    int nlid = (xcd < rr ? xcd * (qq + 1) : rr * (qq + 1) + (xcd - rr) * qq) + pos;
    const int bx = nlid % nwgx;
    const int by = nlid / nwgx;

    __shared__ __align__(16) unsigned short lds[2 * 16384];  // 2 bufs x (A 8192 | B 8192)

    const int tid = threadIdx.x;
    const int lane = tid & 63;
    const int wave = tid >> 6;
    const int wm = wave >> 1, wn = wave & 1;
    const int m0 = by * 128, n0 = bx * 128;
    const int r15 = lane & 15;
    const int g4 = lane >> 4;

    f32x4 acc[4][4] = {};

    long aByte[4], bByte[4];
    int ldsOff[4];
    #pragma unroll
    for (int i = 0; i < 4; ++i) {
        int L = i * 256 + tid;
        int row = L >> 3, ch = L & 7;
        int chs = ch ^ (row & 7);
        aByte[i] = (long)(m0 + row) * lda * 2 + chs * 16;
        bByte[i] = (long)(n0 + row) * ldb * 2 + chs * 16;
        ldsOff[i] = L * 8;
    }

    int NT = Kd >> 6;                          // 36 (or 12 for v segment below)
    if (MODE == 4 && n0 >= 1536) NT = 12;      // v: single-term f16 (hi slots only)

    // prologue: stage tile 0 into buf 0, full drain
    #pragma unroll
    for (int i = 0; i < 4; ++i) {
        gload_lds16((const char*)A + aByte[i], &lds[ldsOff[i]]);
        gload_lds16((const char*)B + bByte[i], &lds[8192 + ldsOff[i]]);
    }
    __syncthreads();

    int cur = 0;
    for (int t = 0; t < NT; ++t) {
        if (t + 1 < NT) {
            long kb = (long)(t + 1) * 128;
            int off = (cur ^ 1) * 16384;
            #pragma unroll
            for (int i = 0; i < 4; ++i) {
                gload_lds16((const char*)A + aByte[i] + kb, &lds[off + ldsOff[i]]);
                gload_lds16((const char*)B + bByte[i] + kb, &lds[off + 8192 + ldsOff[i]]);
            }
        }
        const unsigned short* bufA = &lds[cur * 16384];
        const unsigned short* bufB = bufA + 8192;
        #pragma unroll
        for (int ks = 0; ks < 2; ++ks) {
            f16x8 af[4], bfr[4];
            #pragma unroll
            for (int i = 0; i < 4; ++i) {
                int row = wm * 64 + i * 16 + r15;
                int chs = (ks * 4 + g4) ^ (r15 & 7);
                af[i] = *(const f16x8*)&bufA[row * 64 + chs * 8];
            }
            #pragma unroll
            for (int j = 0; j < 4; ++j) {
                int row = wn * 64 + j * 16 + r15;
                int chs = (ks * 4 + g4) ^ (r15 & 7);
                bfr[j] = *(const f16x8*)&bufB[row * 64 + chs * 8];
            }
            #pragma unroll
            for (int i = 0; i < 4; ++i)
                #pragma unroll
                for (int j = 0; j < 4; ++j)
                    acc[i][j] = __builtin_amdgcn_mfma_f32_16x16x32_f16(
                        af[i], bfr[j], acc[i][j], 0, 0, 0);
        }
        __syncthreads();
        cur ^= 1;
    }

    float bj[4];
    #pragma unroll
    for (int j = 0; j < 4; ++j) {
        int n = n0 + wn * 64 + j * 16 + r15;
        bj[j] = bias[n];
    }

    if (MODE == 0) {
        #pragma unroll
        for (int i = 0; i < 4; ++i) {
            #pragma unroll
            for (int r = 0; r < 4; ++r) {
                int m = m0 + wm * 64 + i * 16 + g4 * 4 + r;
                #pragma unroll
                for (int j = 0; j < 4; ++j) {
                    int n = n0 + wn * 64 + j * 16 + r15;
                    C[(long)m * N + n] = acc[i][j][r] + bj[j];
                }
            }
        }
    }

    if (MODE == 3) {
        #pragma unroll
        for (int i = 0; i < 4; ++i) {
            #pragma unroll
            for (int r = 0; r < 4; ++r) {
                int m = m0 + wm * 64 + i * 16 + g4 * 4 + r;
                #pragma unroll
                for (int j = 0; j < 4; ++j) {
                    int e = n0 + wn * 64 + j * 16 + r15;
                    float xv = fmaxf(acc[i][j][r] + bj[j], 0.f);
                    oQ[(long)m * DD + e] = ff16(xv);
                }
            }
        }
    }

    if (MODE == 4) {
        const int seg = n0 / 768;                       // block-uniform: 0=q 1=k 2=v
        const int e0 = n0 - seg * 768 + wn * 64;
        const int chunk = (bx - seg * 6) * 2 + wn;      // 0..11 within segment
        #pragma unroll
        for (int i = 0; i < 4; ++i) {
            #pragma unroll
            for (int r = 0; r < 4; ++r) {
                int m = m0 + wm * 64 + i * 16 + g4 * 4 + r;
                float vals[4];
                #pragma unroll
                for (int j = 0; j < 4; ++j) vals[j] = acc[i][j][r] + bj[j];
                if (seg == 2) {
                    #pragma unroll
                    for (int j = 0; j < 4; ++j)
                        oV[(long)m * DD + e0 + j * 16 + r15] = rne_bf16(vals[j]);
                } else {
                    unsigned short* os = (seg == 0) ? oQ : oK;
                    #pragma unroll
                    for (int j = 0; j < 4; ++j) {
                        float xv = vals[j];
                        _Float16 hh = (_Float16)xv;
                        float hf = (float)hh;
                        float l = xv - hf;
                        long base = (long)m * QS + e0 + j * 16 + r15;
                        os[base]      = __builtin_bit_cast(unsigned short, hh);
                        os[base + DD] = ff16(l * 64.f);
                    }
                    float s = vals[0]*vals[0] + vals[1]*vals[1]
                            + vals[2]*vals[2] + vals[3]*vals[3];
                    s += __shfl_xor(s, 1); s += __shfl_xor(s, 2);
                    s += __shfl_xor(s, 4); s += __shfl_xor(s, 8);
                    if (r15 == 0)
                        pn[(seg ? (long)BSR * 12 : 0) + (long)m * 12 + chunk] = s;
                }
            }
        }
    }
}

// One WAVE per query row, zero LDS, zero barriers.
// Phase 1: streaming per-lane top-8 VALUES (u32, exec-masked sorted insert).
// Phase 2: threshold selection via common-prefix-narrowed binary search on
//          value bits (bitplane ballots); exact tie-break by index from d[];
//          wave-uniform fallback rebuilds u64 keys + 33-iteration tournament
//          on saturation (expected never).
// Phase 3: boundary-gap guard (exact fp32 recompute from 2-slot splits).
// Phase 4: rank-based index assignment; bf16 v gather batched 4 rows.
// Writes COMPACT f16 topo [g][768].
__global__ __launch_bounds__(256)
void select_mean(const float* __restrict__ dist, const unsigned short* __restrict__ v,
                 const unsigned short* __restrict__ q_s, const unsigned short* __restrict__ k_s,
                 const float* __restrict__ qn, const float* __restrict__ kn,
                 unsigned short* __restrict__ topo_f16)
{
    const int wv = threadIdx.x >> 6;
    const int lane = threadIdx.x & 63;
    const int g = blockIdx.x * 4 + wv;      // global row 0..8191
    const int b = g >> 11;
    const float* drow = dist + (long)b * SS * SS + (long)(g & (SS - 1)) * SS;
    const unsigned short* vb = v + (long)b * SS * DD;

    float d[32];
    unsigned h0 = 0xffffffffu, h1 = 0xffffffffu, h2 = 0xffffffffu, h3 = 0xffffffffu,
             h4 = 0xffffffffu, h5 = 0xffffffffu, h6 = 0xffffffffu, h7 = 0xffffffffu;
    const f32x4* dr4 = (const f32x4*)drow;
    #pragma unroll
    for (int c = 0; c < 8; ++c) {
        f32x4 tv = dr4[c * 64 + lane];
        #pragma unroll
        for (int i = 0; i < 4; ++i) {
            float x = fmaxf(tv[i], 0.f);
            d[c * 4 + i] = x;
            unsigned xv = __builtin_bit_cast(unsigned, x);
            if (xv < h7) {                  // exec-masked sorted insert (values only)
                bool l0 = xv < h0, l1 = xv < h1, l2 = xv < h2, l3 = xv < h3,
                     l4 = xv < h4, l5 = xv < h5, l6 = xv < h6;
                h7 = l6 ? h6 : xv;
                h6 = l6 ? (l5 ? h5 : xv) : h6;
                h5 = l5 ? (l4 ? h4 : xv) : h5;
                h4 = l4 ? (l3 ? h3 : xv) : h4;
                h3 = l3 ? (l2 ? h2 : xv) : h3;
                h2 = l2 ? (l1 ? h1 : xv) : h2;
                h1 = l1 ? (l0 ? h0 : xv) : h1;
                h0 = l0 ? xv : h0;
            }
        }
    }

    unsigned sel = 0;
    float d32v = 0.f, d33v = 0.f;

    // ---- Phase 2: narrowed binary search for the rank-31 value ----
    unsigned lo = h0, hi = h7;
    #pragma unroll
    for (int off = 32; off; off >>= 1) {
        unsigned ol = __shfl_xor(lo, off); lo = ol < lo ? ol : lo;
        unsigned oh = __shfl_xor(hi, off); hi = oh > hi ? oh : hi;
    }
    unsigned diffb = lo ^ hi;
    unsigned Vv; int nb;
    if (diffb == 0) { Vv = lo; nb = -1; }
    else {
        nb = 31 - __builtin_clz(diffb);
        Vv = (nb >= 31) ? 0u : (lo & ~((1u << (nb + 1)) - 1u));
    }
    for (int bit = nb; bit >= 0; --bit) {
        unsigned candv = Vv | (1u << bit);
        int c = (h0 < candv) + (h1 < candv) + (h2 < candv) + (h3 < candv)
              + (h4 < candv) + (h5 < candv) + (h6 < candv) + (h7 < candv);
        int tot = (int)__popcll(__ballot(c & 1))
                + 2 * (int)__popcll(__ballot(c & 2))
                + 4 * (int)__popcll(__ballot(c & 4))
                + 8 * (int)__popcll(__ballot(c & 8));
        if (tot <= 31) Vv = candv;
    }
    bool fallback = __any(h7 <= Vv);

    if (!fallback) {
        int cl = (h0 < Vv) + (h1 < Vv) + (h2 < Vv) + (h3 < Vv)
               + (h4 < Vv) + (h5 < Vv) + (h6 < Vv) + (h7 < Vv);
        int c_lt = (int)__popcll(__ballot(cl & 1))
                 + 2 * (int)__popcll(__ballot(cl & 2))
                 + 4 * (int)__popcll(__ballot(cl & 4))
                 + 8 * (int)__popcll(__ballot(cl & 8));
        #pragma unroll
        for (int s = 0; s < 32; ++s)
            if (__builtin_bit_cast(unsigned, d[s]) < Vv) sel |= 1u << s;
        int need = KNEI - c_lt;
        for (int t2 = 0; t2 < need; ++t2) {
            unsigned mi = 0xffffffffu;
            #pragma unroll
            for (int s = 0; s < 32; ++s) {
                bool eq = (__builtin_bit_cast(unsigned, d[s]) == Vv) && !((sel >> s) & 1u);
                unsigned jj = (unsigned)((s >> 2) * 256 + lane * 4 + (s & 3));
                if (eq && jj < mi) mi = jj;
            }
            #pragma unroll
            for (int off = 32; off; off >>= 1) {
                unsigned o = __shfl_xor(mi, off);
                mi = o < mi ? o : mi;
            }
            if (mi != 0xffffffffu && lane == ((mi >> 2) & 63))
                sel |= 1u << (((mi >> 8) << 2) | (mi & 3));
        }
        d32v = __builtin_bit_cast(float, Vv);
        int ce = (h0 <= Vv) + (h1 <= Vv) + (h2 <= Vv) + (h3 <= Vv)
               + (h4 <= Vv) + (h5 <= Vv) + (h6 <= Vv) + (h7 <= Vv);
        int c_le = (int)__popcll(__ballot(ce & 1))
                 + 2 * (int)__popcll(__ballot(ce & 2))
                 + 4 * (int)__popcll(__ballot(ce & 4))
                 + 8 * (int)__popcll(__ballot(ce & 8));
        if (c_le >= 33) {
            d33v = d32v;
        } else {
            unsigned mv = 0xffffffffu;
            if (h0 > Vv && h0 < mv) mv = h0;
            if (h1 > Vv && h1 < mv) mv = h1;
            if (h2 > Vv && h2 < mv) mv = h2;
            if (h3 > Vv && h3 < mv) mv = h3;
            if (h4 > Vv && h4 < mv) mv = h4;
            if (h5 > Vv && h5 < mv) mv = h5;
            if (h6 > Vv && h6 < mv) mv = h6;
            if (h7 > Vv && h7 < mv) mv = h7;
            #pragma unroll
            for (int off = 32; off; off >>= 1) {
                unsigned o = __shfl_xor(mv, off);
                mv = o < mv ? o : mv;
            }
            d33v = __builtin_bit_cast(float, mv);
        }
    } else {
        // ---- rare saturation path: rebuild u64 keys, 33-iteration tournament ----
        unsigned long long g0 = ~0ull, g1 = ~0ull, g2 = ~0ull, g3 = ~0ull,
                           g4b = ~0ull, g5 = ~0ull, g6 = ~0ull, g7 = ~0ull;
        #pragma unroll
        for (int s = 0; s < 32; ++s) {
            unsigned long long kk =
                ((unsigned long long)__builtin_bit_cast(unsigned, d[s]) << 32)
                | (unsigned)((s >> 2) * 256 + lane * 4 + (s & 3));
            if (kk < g7) {
                bool l0 = kk < g0, l1 = kk < g1, l2 = kk < g2, l3 = kk < g3,
                     l4 = kk < g4b, l5 = kk < g5, l6 = kk < g6;
                g7 = l6 ? g6 : kk;
                g6 = l6 ? (l5 ? g5 : kk) : g6;
                g5 = l5 ? (l4 ? g4b : kk) : g5;
                g4b = l4 ? (l3 ? g3 : kk) : g4b;
                g3 = l3 ? (l2 ? g2 : kk) : g3;
                g2 = l2 ? (l1 ? g1 : kk) : g2;
                g1 = l1 ? (l0 ? g0 : kk) : g1;
                g0 = l0 ? kk : g0;
            }
        }
        int cnt = 0;
        for (int t = 0; t < 33; ++t) {
            unsigned long long best = g0;
            #pragma unroll
            for (int off = 32; off; off >>= 1) {
                unsigned long long o = __shfl_xor(best, off);
                best = o < best ? o : best;
            }
            if (t == 32) {
                d33v = __builtin_bit_cast(float, (unsigned)(best >> 32));
                break;
            }
            int j = (int)(unsigned)best;
            bool won = (lane == ((j >> 2) & 63));
            if (won) sel |= 1u << (((j >> 8) << 2) | (j & 3));
            if (t == 31) d32v = __builtin_bit_cast(float, (unsigned)(best >> 32));

            if (won) cnt++;
            bool needScan = won && (cnt >= 8);
            bool adv = won && (cnt < 8);
            g0 = adv ? g1 : g0;  g1 = adv ? g2 : g1;  g2 = adv ? g3 : g2;
            g3 = adv ? g4b : g3; g4b = adv ? g5 : g4b; g5 = adv ? g6 : g5;
            g6 = adv ? g7 : g6;  g7 = adv ? ~0ull : g7;
            if (__any(needScan)) {
                if (needScan) {
                    float bv = FLT_MAX; int bs = 0; bool found = false;
                    #pragma unroll
                    for (int s = 0; s < 32; ++s) {
                        bool ok = !((sel >> s) & 1u);
                        bool lt = ok && (d[s] < bv);
                        bv = lt ? d[s] : bv; bs = lt ? s : bs; found |= ok;
                    }
                    g0 = found
                       ? (((unsigned long long)__builtin_bit_cast(unsigned, bv) << 32)
                          | (unsigned)((bs >> 2) * 256 + lane * 4 + (bs & 3)))
                       : ~0ull;
                }
            }
        }
    }

    // ---- Phase 3: boundary-gap guard (exact fp32 recompute for the window) ----
    if (d33v - d32v < MARGIN) {
        float lo2 = d32v - MARGIN, hi2 = d33v + MARGIN;
        unsigned cand = 0;
        #pragma unroll
        for (int s = 0; s < 32; ++s)
            if (d[s] >= lo2 && d[s] <= hi2) cand |= 1u << s;

        const unsigned short* qrow = q_s + (long)g * QS;
        const u16x4* qh = (const u16x4*)&qrow[lane * 12];
        const u16x4* ql = (const u16x4*)&qrow[DD + lane * 12];
        #pragma unroll
        for (int s = 0; s < 32; ++s) {
            unsigned long long m = __ballot((cand >> s) & 1u);
            while (m) {
                int l2 = __ffsll(m) - 1;
                m &= m - 1;
                int j = (s >> 2) * 256 + l2 * 4 + (s & 3);
                const unsigned short* krow = k_s + ((long)b * SS + j) * QS;
                const u16x4* kh = (const u16x4*)&krow[lane * 12];
                const u16x4* kl = (const u16x4*)&krow[DD + lane * 12];
                float part = 0.f;
                #pragma unroll
                for (int c = 0; c < 3; ++c) {
                    u16x4 qa = qh[c], qb = ql[c], ka = kh[c], kb2 = kl[c];
                    #pragma unroll
                    for (int e = 0; e < 4; ++e) {
                        float qv = f16f(qa[e]) + f16f(qb[e]) * 0.015625f;
                        float kv = f16f(ka[e]) + f16f(kb2[e]) * 0.015625f;
                        part = fmaf(qv, kv, part);
                    }
                }
                #pragma unroll
                for (int off = 32; off; off >>= 1) part += __shfl_xor(part, off);
                float dd = qn[g] + kn[(long)b * SS + j] - 2.f * part;
                dd = fmaxf(dd, 0.f);
                if (lane == l2) d[s] = dd;
            }
        }

        sel &= ~cand;
        int C = 0;
        #pragma unroll
        for (int s = 0; s < 32; ++s) C += (int)__popcll(__ballot((sel >> s) & 1u));
        int need = KNEI - C;
        for (int t = 0; t < need; ++t) {
            unsigned long long best = ~0ull;
            #pragma unroll
            for (int s = 0; s < 32; ++s) {
                if (((cand >> s) & 1u) && !((sel >> s) & 1u)) {
                    unsigned long long key =
                        ((unsigned long long)__builtin_bit_cast(unsigned, d[s]) << 32)
                        | (unsigned)((s >> 2) * 256 + lane * 4 + (s & 3));
                    best = key < best ? key : best;
                }
            }
            #pragma unroll
            for (int off = 32; off; off >>= 1) {
                unsigned long long o = __shfl_xor(best, off);
                best = o < best ? o : best;
            }
            if (best != ~0ull) {
                int j = (int)(unsigned)best;
                if (lane == ((j >> 2) & 63)) sel |= 1u << (((j >> 8) << 2) | (j & 3));
            }
        }
    }

    // ---- Phase 4: rank-based selected-index assignment + batched bf16 gather ----
    int myj = 0;
    {
        int target = lane & 31;            // lane p (and p+32) own the p-th selected index
        int cum = 0;
        #pragma unroll
        for (int s = 0; s < 32; ++s) {
            unsigned long long m = __ballot((sel >> s) & 1u);
            int c = (int)__popcll(m);
            if (target >= cum && target < cum + c) {
                int nth = target - cum;
                unsigned long long mm = m;
                int base = 0;
                int c32 = (int)__popcll(mm & 0xffffffffull);
                if (nth >= c32) { nth -= c32; mm >>= 32; base += 32; }
                int c16 = (int)__popcll(mm & 0xffffull);
                if (nth >= c16) { nth -= c16; mm >>= 16; base += 16; }
                int c8 = (int)__popcll(mm & 0xffull);
                if (nth >= c8) { nth -= c8; mm >>= 8; base += 8; }
                int c4 = (int)__popcll(mm & 0xfull);
                if (nth >= c4) { nth -= c4; mm >>= 4; base += 4; }
                int c2 = (int)__popcll(mm & 0x3ull);
                if (nth >= c2) { nth -= c2; mm >>= 2; base += 2; }
                int c1 = (int)(mm & 1ull);
                if (nth >= c1) { base += 1; }
                myj = (s >> 2) * 256 + base * 4 + (s & 3);
            }
            cum += c;
        }
    }
    f32x4 a0 = {0.f, 0.f, 0.f, 0.f}, a1 = a0, a2 = a0;
    #pragma unroll
    for (int tb = 0; tb < 8; ++tb) {
        u16x4 r0[4], r1[4], r2[4];
        #pragma unroll
        for (int u = 0; u < 4; ++u) {
            int j = __shfl(myj, tb * 4 + u);
            const u16x4* vr = (const u16x4*)(vb + (long)j * DD);
            r0[u] = vr[lane];
            r1[u] = vr[lane + 64];
            r2[u] = vr[lane + 128];
        }
        #pragma unroll
        for (int u = 0; u < 4; ++u) {
            #pragma unroll
            for (int e = 0; e < 4; ++e) {
                a0[e] += bf16f(r0[u][e]);
                a1[e] += bf16f(r1[u][e]);
                a2[e] += bf16f(r2[u][e]);
            }
        }
    }
    const float sc = 1.0f / 32.0f;
    unsigned short* trow = topo_f16 + (long)g * DD;
    #pragma unroll
    for (int c = 0; c < 3; ++c) {
        f32x4 x = (c == 0) ? a0 : (c == 1) ? a1 : a2;
        u16x4 hi4;
        #pragma unroll
        for (int e = 0; e < 4; ++e) hi4[e] = ff16(x[e] * sc);
        *(u16x4*)&trow[c * 256 + lane * 4] = hi4;
    }
}

extern "C" void kernel_launch(void* const* d_in, const int* in_sizes, int n_in,
                              void* d_out, int out_size, void* d_ws, size_t ws_size,
                              hipStream_t stream)
{
    const float* hs = (const float*)d_in[0];
    const float* Wq = (const float*)d_in[1];
    const float* bq = (const float*)d_in[2];
    const float* Wk = (const float*)d_in[3];
    const float* bk = (const float*)d_in[4];
    const float* Wv = (const float*)d_in[5];
    const float* bv = (const float*)d_in[6];
    const float* W1 = (const float*)d_in[7];
    const float* b1 = (const float*)d_in[8];
    const float* W2 = (const float*)d_in[9];
    const float* b2 = (const float*)d_in[10];
    float* out = (float*)d_out;

    // ---- workspace layout (peak ~180 MB), time-overlaid ----
    char* w = (char*)d_ws;
    const long DISTB = (long)BB * SS * SS * 4;        // 67,108,864
    const long VB    = (long)BSR * DD * 2;            // 12,582,912 (bf16 v)
    const long WSPL  = (long)DD * K2;                 // elems per 3-term split weight

    float*          dist   = (float*)w;                               // [0, 67.1M)
    unsigned short* h_f16  = (unsigned short*)w;                      // overlays dead dist
    unsigned short* v      = (unsigned short*)(w + DISTB);            // bf16 v
    unsigned short* q_s    = (unsigned short*)(w + DISTB + VB);       // 2-slot
    unsigned short* k_s    = q_s + (long)BSR * QS;                    // 2-slot
    unsigned short* hs_s   = k_s + (long)BSR * QS;                    // 3-term A-layout
    unsigned short* topo_f16 = hs_s;                                  // overlays dead hs_s
    unsigned short* Wqkv_s = hs_s + (long)BSR * K2;                   // 3 weight splits adjacent
    unsigned short* W1_f16 = Wqkv_s;                                  // overlays dead Wqkv
    unsigned short* W2_f16 = Wqkv_s + (long)DD * DD;
    char* tail  = (char*)(Wqkv_s + 3 * WSPL);
    float* qn   = (float*)tail;                        // 8192
    float* kn   = qn + BSR;                            // 8192
    float* pn   = kn + BSR;                            // qnp[8192][12] + knp[8192][12]
    float* bqkv = pn + (long)2 * BSR * 12;             // 2304

    dim3 blk(256);
    const int convW  = (DD * (DD / 8)) / 256;          // 288 blocks per weight
    const int convHS = (BSR * (DD / 8)) / 256;         // 3072 blocks

    concat_bias<<<9, blk, 0, stream>>>(bq, bk, bv, bqkv);
    split_f16<2><<<convW, blk, 0, stream>>>(Wq, Wqkv_s, DD);
    split_f16<2><<<convW, blk, 0, stream>>>(Wk, Wqkv_s + WSPL, DD);
    split_f16<2><<<convW, blk, 0, stream>>>(Wv, Wqkv_s + 2 * WSPL, DD);
    split_f16<1><<<convHS, blk, 0, stream>>>(hs, hs_s, DD);

    // fused QKV gemm: q -> 2-slot q_s + norms, k -> 2-slot k_s + norms, v -> bf16 (K=768)
    gemm_mfma<4><<<dim3(2304 / 128, BSR / 128, 1), blk, 0, stream>>>(
        hs_s, Wqkv_s, bqkv, nullptr, BSR, 2304, K2, K2, K2,
        q_s, k_s, v, pn);

    // W1/W2 compact f16 converts into dead Wqkv region
    conv_f16<<<convW, blk, 0, stream>>>(W1, W1_f16);
    conv_f16<<<convW, blk, 0, stream>>>(W2, W2_f16);
    finish_norms<<<(2 * BSR) / 256, blk, 0, stream>>>(pn, qn, kn);

    // squared distance matrix per batch: single-term f16 (Kd=768, stride QS)
    gemm256_dist<<<dim3(SS / 256, SS / 256, BB), dim3(512), 0, stream>>>(
        q_s, k_s, qn, kn, dist, SS, DD, QS, QS,
        (long)SS * QS, (long)SS * QS, (long)SS * SS, SS);

    select_mean<<<BSR / 4, blk, 0, stream>>>(dist, v, q_s, k_s, qn, kn, topo_f16);

    // MLP single-term f16: gemm1 -> compact f16 h (relu fused), gemm2 -> f32 out
    gemm_mfma<3><<<dim3(DD / 128, BSR / 128, 1), blk, 0, stream>>>(
        topo_f16, W1_f16, b1, nullptr, BSR, DD, DD, DD, DD,
        h_f16, nullptr, nullptr, nullptr);
    gemm_mfma<0><<<dim3(DD / 128, BSR / 128, 1), blk, 0, stream>>>(
        h_f16, W2_f16, b2, out, BSR, DD, DD, DD, DD,
        nullptr, nullptr, nullptr, nullptr);
}

// Round 19
// 243.718 us; speedup vs baseline: 5.1391x; 1.0540x over previous
//
#include <hip/hip_runtime.h>
#include <float.h>

#define DD 768
#define SS 2048
#define BB 4
#define BSR (BB*SS)   // 8192 total rows
#define KNEI 32
#define K2 (3*DD)     // 2304: [hi | x | y] split concat along K (hs_s only)
#define QS (2*DD)     // 1536: 2-slot q_s/k_s layout [h, l*2^6]
#define MARGIN 0.12f  // >=6 sigma of single-term f16 pairwise dist error

typedef __attribute__((ext_vector_type(8))) _Float16 f16x8;
typedef __attribute__((ext_vector_type(4))) float f32x4;
typedef __attribute__((ext_vector_type(8))) unsigned short u16x8;
typedef __attribute__((ext_vector_type(4))) unsigned short u16x4;

__device__ __forceinline__ float f16f(unsigned short u) {
    return (float)__builtin_bit_cast(_Float16, u);
}
__device__ __forceinline__ unsigned short ff16(float x) {
    return __builtin_bit_cast(unsigned short, (_Float16)x);
}
__device__ __forceinline__ unsigned short rne_bf16(float x) {
    unsigned u = __builtin_bit_cast(unsigned, x);
    unsigned r = u + 0x7FFFu + ((u >> 16) & 1u);
    return (unsigned short)(r >> 16);
}
__device__ __forceinline__ float bf16f(unsigned short h) {
    return __builtin_bit_cast(float, (unsigned)h << 16);
}

__device__ __forceinline__ void gload_lds16(const void* g, void* l) {
    __builtin_amdgcn_global_load_lds(
        (const __attribute__((address_space(1))) unsigned int*)g,
        (__attribute__((address_space(3))) unsigned int*)l, 16, 0, 0);
}

// fp32 -> 3-slot f16 split body (8 elems at flat chunk id `idx`).
// A-layout (LO_SLOT=1): [h, l*2^6, h*2^-6];  B-layout (LO_SLOT=2): [h, h*2^-6, l*2^6]
template<int LO_SLOT>
__device__ __forceinline__ void split_body(const float* __restrict__ in,
                                           unsigned short* __restrict__ out,
                                           int idx, int Kc)
{
    int perRow = Kc >> 3;
    int row = idx / perRow, c8 = idx - row * perRow;
    const float* src = in + (long)row * Kc + c8 * 8;
    f32x4 x0 = *(const f32x4*)&src[0];
    f32x4 x1 = *(const f32x4*)&src[4];
    u16x8 hi, lsc, hsc;
    #pragma unroll
    for (int e = 0; e < 8; ++e) {
        float xv = (e < 4) ? x0[e] : x1[e - 4];
        _Float16 h = (_Float16)xv;
        float hf = (float)h;
        float l = xv - hf;
        hi[e]  = __builtin_bit_cast(unsigned short, h);
        lsc[e] = ff16(l * 64.f);
        hsc[e] = ff16(hf * 0.015625f);
    }
    long base = (long)row * (3 * Kc) + c8 * 8;
    *(u16x8*)&out[base] = hi;
    *(u16x8*)&out[base + Kc]     = (LO_SLOT == 1) ? lsc : hsc;
    *(u16x8*)&out[base + 2 * Kc] = (LO_SLOT == 1) ? hsc : lsc;
}

__device__ __forceinline__ void conv_body(const float* __restrict__ in,
                                          unsigned short* __restrict__ out, int idx)
{
    const float* src = in + (long)idx * 8;
    f32x4 x0 = *(const f32x4*)&src[0];
    f32x4 x1 = *(const f32x4*)&src[4];
    u16x8 o;
    #pragma unroll
    for (int e = 0; e < 8; ++e) {
        float xv = (e < 4) ? x0[e] : x1[e - 4];
        o[e] = ff16(xv);
    }
    *(u16x8*)&out[(long)idx * 8] = o;
}

// ---- merged prologue: 3 weight splits + hs split + 2 MLP convs + bias concat ----
// block ranges: [0,864) Wq/Wk/Wv split; [864,3936) hs split; [3936,4224) W1 conv;
// [4224,4512) W2 conv; [4512,4521) bias concat. All branches block-uniform.
__global__ __launch_bounds__(256)
void prep(const float* __restrict__ Wq, const float* __restrict__ Wk,
          const float* __restrict__ Wv, const float* __restrict__ hs,
          const float* __restrict__ W1, const float* __restrict__ W2,
          const float* __restrict__ bq, const float* __restrict__ bk,
          const float* __restrict__ bv,
          unsigned short* __restrict__ Wqkv_s, unsigned short* __restrict__ hs_s,
          unsigned short* __restrict__ W1_f16, unsigned short* __restrict__ W2_f16,
          float* __restrict__ bqkv)
{
    const long WSPL = (long)DD * K2;
    int bid = blockIdx.x;
    int tid = threadIdx.x;
    if (bid < 864) {
        int which = bid / 288, sub = bid - which * 288;
        const float* src = (which == 0) ? Wq : (which == 1) ? Wk : Wv;
        split_body<2>(src, Wqkv_s + (long)which * WSPL, sub * 256 + tid, DD);
    } else if (bid < 3936) {
        split_body<1>(hs, hs_s, (bid - 864) * 256 + tid, DD);
    } else if (bid < 4224) {
        conv_body(W1, W1_f16, (bid - 3936) * 256 + tid);
    } else if (bid < 4512) {
        conv_body(W2, W2_f16, (bid - 4224) * 256 + tid);
    } else {
        int i = (bid - 4512) * 256 + tid;
        if (i < 768) bqkv[i] = bq[i];
        else if (i < 1536) bqkv[i] = bk[i - 768];
        else if (i < 2304) bqkv[i] = bv[i - 1536];
    }
}

// pn rows: qnp[8192][12] then knp[8192][12] contiguous; fixed-order sum.
__global__ __launch_bounds__(256)
void finish_norms(const float* __restrict__ pn, float* __restrict__ qn, float* __restrict__ kn)
{
    int row = blockIdx.x * 256 + threadIdx.x;   // 0..16383
    const float* p = pn + (long)row * 12;
    float s = 0.f;
    #pragma unroll
    for (int c = 0; c < 12; ++c) s += p[c];
    if (row < BSR) qn[row] = s; else kn[row - BSR] = s;
}

// ---------------------------------------------------------------------------
// 256x256-tile distance GEMM, minimum-2-phase __syncthreads schedule
// (prefetch next tile into buf^1, compute buf[cur], ONE __syncthreads/tile).
// Single-term f16: Kd=768 (hi slots only), row stride lda/ldb = QS.
// ---------------------------------------------------------------------------
__global__ __launch_bounds__(512)
void gemm256_dist(const unsigned short* __restrict__ A, const unsigned short* __restrict__ B,
                  const float* __restrict__ rm, const float* __restrict__ rn,
                  float* __restrict__ C,
                  int N, int Kd, long lda, long ldb,
                  long sA, long sB, long sC, long sR)
{
    const int z = blockIdx.z;
    A += (long)z * sA;
    B += (long)z * sB;
    C += (long)z * sC;
    const float* rmz = rm + (long)z * sR;
    const float* rnz = rn + (long)z * sR;

    // bijective XCD swizzle over the 64 blocks of this batch
    int lid = blockIdx.y * gridDim.x + blockIdx.x;
    int xcd = lid & 7, pos = lid >> 3;
    int nlid = xcd * 8 + pos;
    const int bx = nlid & 7, by = nlid >> 3;

    __shared__ __align__(16) unsigned short lds[2 * 32768];  // 2 bufs x (A 16384 | B 16384) f16

    const int tid = threadIdx.x;
    const int lane = tid & 63;
    const int wave = tid >> 6;
    const int wm = wave >> 2, wn = wave & 3;   // 2 x 4 wave grid
    const int m0 = by * 256, n0 = bx * 256;
    const int r15 = lane & 15;
    const int g4 = lane >> 4;

    f32x4 acc[8][4] = {};

    long aB[4], bB[4];
    int lof[4];
    #pragma unroll
    for (int i = 0; i < 4; ++i) {
        int L = i * 512 + tid;          // 0..2047 chunk id (16B chunks)
        int row = L >> 3, ch = L & 7;
        int chs = ch ^ (row & 7);
        aB[i] = (long)(m0 + row) * lda * 2 + chs * 16;
        bB[i] = (long)(n0 + row) * ldb * 2 + chs * 16;
        lof[i] = L * 8;
    }

    const int NT = Kd >> 6;             // 12 K-tiles of 64

    // prologue: stage tile 0 into buf 0, full drain
    #pragma unroll
    for (int i = 0; i < 4; ++i) {
        gload_lds16((const char*)A + aB[i], &lds[lof[i]]);
        gload_lds16((const char*)B + bB[i], &lds[16384 + lof[i]]);
    }
    __syncthreads();

    int cur = 0;
    for (int t = 0; t < NT; ++t) {
        if (t + 1 < NT) {               // prefetch next tile into the other buffer
            long kb = (long)(t + 1) * 128;
            int off = (cur ^ 1) * 32768;
            #pragma unroll
            for (int i = 0; i < 4; ++i) {
                gload_lds16((const char*)A + aB[i] + kb, &lds[off + lof[i]]);
                gload_lds16((const char*)B + bB[i] + kb, &lds[off + 16384 + lof[i]]);
            }
        }
        const unsigned short* bufA = &lds[cur * 32768];
        const unsigned short* bufB = bufA + 16384;
        #pragma unroll
        for (int ks = 0; ks < 2; ++ks) {
            f16x8 af[8], bfr[4];
            #pragma unroll
            for (int i = 0; i < 8; ++i) {
                int r = wm * 128 + i * 16 + r15;
                int g = ks * 4 + g4;
                af[i] = *(const f16x8*)&bufA[r * 64 + (g ^ (r & 7)) * 8];
            }
            #pragma unroll
            for (int j = 0; j < 4; ++j) {
                int c = wn * 64 + j * 16 + r15;
                int g = ks * 4 + g4;
                bfr[j] = *(const f16x8*)&bufB[c * 64 + (g ^ (c & 7)) * 8];
            }
            #pragma unroll
            for (int i = 0; i < 8; ++i)
                #pragma unroll
                for (int j = 0; j < 4; ++j)
                    acc[i][j] = __builtin_amdgcn_mfma_f32_16x16x32_f16(
                        af[i], bfr[j], acc[i][j], 0, 0, 0);
        }
        __syncthreads();                // full drain: prefetch landed, reads done
        cur ^= 1;
    }

    // epilogue: C/D layout col=lane&15, row=(lane>>4)*4+reg
    float rnv[4];
    #pragma unroll
    for (int j = 0; j < 4; ++j)
        rnv[j] = rnz[n0 + wn * 64 + j * 16 + r15];
    #pragma unroll
    for (int i = 0; i < 8; ++i) {
        #pragma unroll
        for (int r = 0; r < 4; ++r) {
            int m = m0 + wm * 128 + i * 16 + g4 * 4 + r;
            float rmv = rmz[m];
            #pragma unroll
            for (int j = 0; j < 4; ++j) {
                int n = n0 + wn * 64 + j * 16 + r15;
                C[(long)m * N + n] = rmv + rnv[j] - 2.f * acc[i][j][r];
            }
        }
    }
}

// C[m][n] = epilogue( sum_k A[m][k]*B[n][k] ), NT f16 inputs, strides lda/ldb.
// Minimum-2-phase __syncthreads schedule (proven replay-stable).
// MODE 0: +bias[n] -> f32 C
// MODE 3: relu(+bias[n]) -> compact f16 oQ [m][768]
// MODE 4: combined QKV: seg 0 -> 2-slot q_s + qnp; 1 -> 2-slot k_s + knp;
//         2 -> bf16 oV with SINGLE-TERM K=768
template<int MODE>
__global__ __launch_bounds__(256)
void gemm_mfma(const unsigned short* __restrict__ A, const unsigned short* __restrict__ B,
               const float* __restrict__ bias,
               float* __restrict__ C,
               int M, int N, int Kd, long lda, long ldb,
               unsigned short* __restrict__ oQ, unsigned short* __restrict__ oK,
               unsigned short* __restrict__ oV, float* __restrict__ pn)
{
    // ---- bijective XCD swizzle (T1/m204) ----
    const int nwgx = gridDim.x;
    const int nwg  = nwgx * gridDim.y;
    int lid = blockIdx.y * nwgx + blockIdx.x;
    int qq = nwg >> 3, rr = nwg & 7;
    int xcd = lid & 7, pos = lid >> 3;
    int nlid = (xcd < rr ? xcd * (qq + 1) : rr * (qq + 1) + (xcd - rr) * qq) + pos;
    const int bx = nlid % nwgx;
    const int by = nlid / nwgx;

    __shared__ __align__(16) unsigned short lds[2 * 16384];  // 2 bufs x (A 8192 | B 8192)

    const int tid = threadIdx.x;
    const int lane = tid & 63;
    const int wave = tid >> 6;
    const int wm = wave >> 1, wn = wave & 1;
    const int m0 = by * 128, n0 = bx * 128;
    const int r15 = lane & 15;
    const int g4 = lane >> 4;

    f32x4 acc[4][4] = {};

    long aByte[4], bByte[4];
    int ldsOff[4];
    #pragma unroll
    for (int i = 0; i < 4; ++i) {
        int L = i * 256 + tid;
        int row = L >> 3, ch = L & 7;
        int chs = ch ^ (row & 7);
        aByte[i] = (long)(m0 + row) * lda * 2 + chs * 16;
        bByte[i] = (long)(n0 + row) * ldb * 2 + chs * 16;
        ldsOff[i] = L * 8;
    }

    int NT = Kd >> 6;                          // 36 (or 12 for v segment below)
    if (MODE == 4 && n0 >= 1536) NT = 12;      // v: single-term f16 (hi slots only)

    // prologue: stage tile 0 into buf 0, full drain
    #pragma unroll
    for (int i = 0; i < 4; ++i) {
        gload_lds16((const char*)A + aByte[i], &lds[ldsOff[i]]);
        gload_lds16((const char*)B + bByte[i], &lds[8192 + ldsOff[i]]);
    }
    __syncthreads();

    int cur = 0;
    for (int t = 0; t < NT; ++t) {
        if (t + 1 < NT) {
            long kb = (long)(t + 1) * 128;
            int off = (cur ^ 1) * 16384;
            #pragma unroll
            for (int i = 0; i < 4; ++i) {
                gload_lds16((const char*)A + aByte[i] + kb, &lds[off + ldsOff[i]]);
                gload_lds16((const char*)B + bByte[i] + kb, &lds[off + 8192 + ldsOff[i]]);
            }
        }
        const unsigned short* bufA = &lds[cur * 16384];
        const unsigned short* bufB = bufA + 8192;
        #pragma unroll
        for (int ks = 0; ks < 2; ++ks) {
            f16x8 af[4], bfr[4];
            #pragma unroll
            for (int i = 0; i < 4; ++i) {
                int row = wm * 64 + i * 16 + r15;
                int chs = (ks * 4 + g4) ^ (r15 & 7);
                af[i] = *(const f16x8*)&bufA[row * 64 + chs * 8];
            }
            #pragma unroll
            for (int j = 0; j < 4; ++j) {
                int row = wn * 64 + j * 16 + r15;
                int chs = (ks * 4 + g4) ^ (r15 & 7);
                bfr[j] = *(const f16x8*)&bufB[row * 64 + chs * 8];
            }
            #pragma unroll
            for (int i = 0; i < 4; ++i)
                #pragma unroll
                for (int j = 0; j < 4; ++j)
                    acc[i][j] = __builtin_amdgcn_mfma_f32_16x16x32_f16(
                        af[i], bfr[j], acc[i][j], 0, 0, 0);
        }
        __syncthreads();
        cur ^= 1;
    }

    float bj[4];
    #pragma unroll
    for (int j = 0; j < 4; ++j) {
        int n = n0 + wn * 64 + j * 16 + r15;
        bj[j] = bias[n];
    }

    if (MODE == 0) {
        #pragma unroll
        for (int i = 0; i < 4; ++i) {
            #pragma unroll
            for (int r = 0; r < 4; ++r) {
                int m = m0 + wm * 64 + i * 16 + g4 * 4 + r;
                #pragma unroll
                for (int j = 0; j < 4; ++j) {
                    int n = n0 + wn * 64 + j * 16 + r15;
                    C[(long)m * N + n] = acc[i][j][r] + bj[j];
                }
            }
        }
    }

    if (MODE == 3) {
        #pragma unroll
        for (int i = 0; i < 4; ++i) {
            #pragma unroll
            for (int r = 0; r < 4; ++r) {
                int m = m0 + wm * 64 + i * 16 + g4 * 4 + r;
                #pragma unroll
                for (int j = 0; j < 4; ++j) {
                    int e = n0 + wn * 64 + j * 16 + r15;
                    float xv = fmaxf(acc[i][j][r] + bj[j], 0.f);
                    oQ[(long)m * DD + e] = ff16(xv);
                }
            }
        }
    }

    if (MODE == 4) {
        const int seg = n0 / 768;                       // block-uniform: 0=q 1=k 2=v
        const int e0 = n0 - seg * 768 + wn * 64;
        const int chunk = (bx - seg * 6) * 2 + wn;      // 0..11 within segment
        #pragma unroll
        for (int i = 0; i < 4; ++i) {
            #pragma unroll
            for (int r = 0; r < 4; ++r) {
                int m = m0 + wm * 64 + i * 16 + g4 * 4 + r;
                float vals[4];
                #pragma unroll
                for (int j = 0; j < 4; ++j) vals[j] = acc[i][j][r] + bj[j];
                if (seg == 2) {
                    #pragma unroll
                    for (int j = 0; j < 4; ++j)
                        oV[(long)m * DD + e0 + j * 16 + r15] = rne_bf16(vals[j]);
                } else {
                    unsigned short* os = (seg == 0) ? oQ : oK;
                    #pragma unroll
                    for (int j = 0; j < 4; ++j) {
                        float xv = vals[j];
                        _Float16 hh = (_Float16)xv;
                        float hf = (float)hh;
                        float l = xv - hf;
                        long base = (long)m * QS + e0 + j * 16 + r15;
                        os[base]      = __builtin_bit_cast(unsigned short, hh);
                        os[base + DD] = ff16(l * 64.f);
                    }
                    float s = vals[0]*vals[0] + vals[1]*vals[1]
                            + vals[2]*vals[2] + vals[3]*vals[3];
                    s += __shfl_xor(s, 1); s += __shfl_xor(s, 2);
                    s += __shfl_xor(s, 4); s += __shfl_xor(s, 8);
                    if (r15 == 0)
                        pn[(seg ? (long)BSR * 12 : 0) + (long)m * 12 + chunk] = s;
                }
            }
        }
    }
}

// One WAVE per query row, zero LDS, zero barriers.
// Phase 1: streaming per-lane top-8 VALUES (u32, exec-masked sorted insert).
// Phase 2: threshold selection via common-prefix-narrowed binary search on
//          value bits (bitplane ballots); exact tie-break by index from d[];
//          wave-uniform fallback rebuilds u64 keys + 33-iteration tournament
//          on saturation (expected never).
// Phase 3: boundary-gap guard (exact fp32 recompute from 2-slot splits).
// Phase 4: rank-based index assignment; bf16 v gather batched 4 rows.
// Writes COMPACT f16 topo [g][768].
__global__ __launch_bounds__(256)
void select_mean(const float* __restrict__ dist, const unsigned short* __restrict__ v,
                 const unsigned short* __restrict__ q_s, const unsigned short* __restrict__ k_s,
                 const float* __restrict__ qn, const float* __restrict__ kn,
                 unsigned short* __restrict__ topo_f16)
{
    const int wv = threadIdx.x >> 6;
    const int lane = threadIdx.x & 63;
    const int g = blockIdx.x * 4 + wv;      // global row 0..8191
    const int b = g >> 11;
    const float* drow = dist + (long)b * SS * SS + (long)(g & (SS - 1)) * SS;
    const unsigned short* vb = v + (long)b * SS * DD;

    float d[32];
    unsigned h0 = 0xffffffffu, h1 = 0xffffffffu, h2 = 0xffffffffu, h3 = 0xffffffffu,
             h4 = 0xffffffffu, h5 = 0xffffffffu, h6 = 0xffffffffu, h7 = 0xffffffffu;
    const f32x4* dr4 = (const f32x4*)drow;
    #pragma unroll
    for (int c = 0; c < 8; ++c) {
        f32x4 tv = dr4[c * 64 + lane];
        #pragma unroll
        for (int i = 0; i < 4; ++i) {
            float x = fmaxf(tv[i], 0.f);
            d[c * 4 + i] = x;
            unsigned xv = __builtin_bit_cast(unsigned, x);
            if (xv < h7) {                  // exec-masked sorted insert (values only)
                bool l0 = xv < h0, l1 = xv < h1, l2 = xv < h2, l3 = xv < h3,
                     l4 = xv < h4, l5 = xv < h5, l6 = xv < h6;
                h7 = l6 ? h6 : xv;
                h6 = l6 ? (l5 ? h5 : xv) : h6;
                h5 = l5 ? (l4 ? h4 : xv) : h5;
                h4 = l4 ? (l3 ? h3 : xv) : h4;
                h3 = l3 ? (l2 ? h2 : xv) : h3;
                h2 = l2 ? (l1 ? h1 : xv) : h2;
                h1 = l1 ? (l0 ? h0 : xv) : h1;
                h0 = l0 ? xv : h0;
            }
        }
    }

    unsigned sel = 0;
    float d32v = 0.f, d33v = 0.f;

    // ---- Phase 2: narrowed binary search for the rank-31 value ----
    unsigned lo = h0, hi = h7;
    #pragma unroll
    for (int off = 32; off; off >>= 1) {
        unsigned ol = __shfl_xor(lo, off); lo = ol < lo ? ol : lo;
        unsigned oh = __shfl_xor(hi, off); hi = oh > hi ? oh : hi;
    }
    unsigned diffb = lo ^ hi;
    unsigned Vv; int nb;
    if (diffb == 0) { Vv = lo; nb = -1; }
    else {
        nb = 31 - __builtin_clz(diffb);
        Vv = (nb >= 31) ? 0u : (lo & ~((1u << (nb + 1)) - 1u));
    }
    for (int bit = nb; bit >= 0; --bit) {
        unsigned candv = Vv | (1u << bit);
        int c = (h0 < candv) + (h1 < candv) + (h2 < candv) + (h3 < candv)
              + (h4 < candv) + (h5 < candv) + (h6 < candv) + (h7 < candv);
        int tot = (int)__popcll(__ballot(c & 1))
                + 2 * (int)__popcll(__ballot(c & 2))
                + 4 * (int)__popcll(__ballot(c & 4))
                + 8 * (int)__popcll(__ballot(c & 8));
        if (tot <= 31) Vv = candv;
    }
    bool fallback = __any(h7 <= Vv);

    if (!fallback) {
        int cl = (h0 < Vv) + (h1 < Vv) + (h2 < Vv) + (h3 < Vv)
               + (h4 < Vv) + (h5 < Vv) + (h6 < Vv) + (h7 < Vv);
        int c_lt = (int)__popcll(__ballot(cl & 1))
                 + 2 * (int)__popcll(__ballot(cl & 2))
                 + 4 * (int)__popcll(__ballot(cl & 4))
                 + 8 * (int)__popcll(__ballot(cl & 8));
        #pragma unroll
        for (int s = 0; s < 32; ++s)
            if (__builtin_bit_cast(unsigned, d[s]) < Vv) sel |= 1u << s;
        int need = KNEI - c_lt;
        for (int t2 = 0; t2 < need; ++t2) {
            unsigned mi = 0xffffffffu;
            #pragma unroll
            for (int s = 0; s < 32; ++s) {
                bool eq = (__builtin_bit_cast(unsigned, d[s]) == Vv) && !((sel >> s) & 1u);
                unsigned jj = (unsigned)((s >> 2) * 256 + lane * 4 + (s & 3));
                if (eq && jj < mi) mi = jj;
            }
            #pragma unroll
            for (int off = 32; off; off >>= 1) {
                unsigned o = __shfl_xor(mi, off);
                mi = o < mi ? o : mi;
            }
            if (mi != 0xffffffffu && lane == ((mi >> 2) & 63))
                sel |= 1u << (((mi >> 8) << 2) | (mi & 3));
        }
        d32v = __builtin_bit_cast(float, Vv);
        int ce = (h0 <= Vv) + (h1 <= Vv) + (h2 <= Vv) + (h3 <= Vv)
               + (h4 <= Vv) + (h5 <= Vv) + (h6 <= Vv) + (h7 <= Vv);
        int c_le = (int)__popcll(__ballot(ce & 1))
                 + 2 * (int)__popcll(__ballot(ce & 2))
                 + 4 * (int)__popcll(__ballot(ce & 4))
                 + 8 * (int)__popcll(__ballot(ce & 8));
        if (c_le >= 33) {
            d33v = d32v;
        } else {
            unsigned mv = 0xffffffffu;
            if (h0 > Vv && h0 < mv) mv = h0;
            if (h1 > Vv && h1 < mv) mv = h1;
            if (h2 > Vv && h2 < mv) mv = h2;
            if (h3 > Vv && h3 < mv) mv = h3;
            if (h4 > Vv && h4 < mv) mv = h4;
            if (h5 > Vv && h5 < mv) mv = h5;
            if (h6 > Vv && h6 < mv) mv = h6;
            if (h7 > Vv && h7 < mv) mv = h7;
            #pragma unroll
            for (int off = 32; off; off >>= 1) {
                unsigned o = __shfl_xor(mv, off);
                mv = o < mv ? o : mv;
            }
            d33v = __builtin_bit_cast(float, mv);
        }
    } else {
        // ---- rare saturation path: rebuild u64 keys, 33-iteration tournament ----
        unsigned long long g0 = ~0ull, g1 = ~0ull, g2 = ~0ull, g3 = ~0ull,
                           g4b = ~0ull, g5 = ~0ull, g6 = ~0ull, g7 = ~0ull;
        #pragma unroll
        for (int s = 0; s < 32; ++s) {
            unsigned long long kk =
                ((unsigned long long)__builtin_bit_cast(unsigned, d[s]) << 32)
                | (unsigned)((s >> 2) * 256 + lane * 4 + (s & 3));
            if (kk < g7) {
                bool l0 = kk < g0, l1 = kk < g1, l2 = kk < g2, l3 = kk < g3,
                     l4 = kk < g4b, l5 = kk < g5, l6 = kk < g6;
                g7 = l6 ? g6 : kk;
                g6 = l6 ? (l5 ? g5 : kk) : g6;
                g5 = l5 ? (l4 ? g4b : kk) : g5;
                g4b = l4 ? (l3 ? g3 : kk) : g4b;
                g3 = l3 ? (l2 ? g2 : kk) : g3;
                g2 = l2 ? (l1 ? g1 : kk) : g2;
                g1 = l1 ? (l0 ? g0 : kk) : g1;
                g0 = l0 ? kk : g0;
            }
        }
        int cnt = 0;
        for (int t = 0; t < 33; ++t) {
            unsigned long long best = g0;
            #pragma unroll
            for (int off = 32; off; off >>= 1) {
                unsigned long long o = __shfl_xor(best, off);
                best = o < best ? o : best;
            }
            if (t == 32) {
                d33v = __builtin_bit_cast(float, (unsigned)(best >> 32));
                break;
            }
            int j = (int)(unsigned)best;
            bool won = (lane == ((j >> 2) & 63));
            if (won) sel |= 1u << (((j >> 8) << 2) | (j & 3));
            if (t == 31) d32v = __builtin_bit_cast(float, (unsigned)(best >> 32));

            if (won) cnt++;
            bool needScan = won && (cnt >= 8);
            bool adv = won && (cnt < 8);
            g0 = adv ? g1 : g0;  g1 = adv ? g2 : g1;  g2 = adv ? g3 : g2;
            g3 = adv ? g4b : g3; g4b = adv ? g5 : g4b; g5 = adv ? g6 : g5;
            g6 = adv ? g7 : g6;  g7 = adv ? ~0ull : g7;
            if (__any(needScan)) {
                if (needScan) {
                    float bv = FLT_MAX; int bs = 0; bool found = false;
                    #pragma unroll
                    for (int s = 0; s < 32; ++s) {
                        bool ok = !((sel >> s) & 1u);
                        bool lt = ok && (d[s] < bv);
                        bv = lt ? d[s] : bv; bs = lt ? s : bs; found |= ok;
                    }
                    g0 = found
                       ? (((unsigned long long)__builtin_bit_cast(unsigned, bv) << 32)
                          | (unsigned)((bs >> 2) * 256 + lane * 4 + (bs & 3)))
                       : ~0ull;
                }
            }
        }
    }

    // ---- Phase 3: boundary-gap guard (exact fp32 recompute for the window) ----
    if (d33v - d32v < MARGIN) {
        float lo2 = d32v - MARGIN, hi2 = d33v + MARGIN;
        unsigned cand = 0;
        #pragma unroll
        for (int s = 0; s < 32; ++s)
            if (d[s] >= lo2 && d[s] <= hi2) cand |= 1u << s;

        const unsigned short* qrow = q_s + (long)g * QS;
        const u16x4* qh = (const u16x4*)&qrow[lane * 12];
        const u16x4* ql = (const u16x4*)&qrow[DD + lane * 12];
        #pragma unroll
        for (int s = 0; s < 32; ++s) {
            unsigned long long m = __ballot((cand >> s) & 1u);
            while (m) {
                int l2 = __ffsll(m) - 1;
                m &= m - 1;
                int j = (s >> 2) * 256 + l2 * 4 + (s & 3);
                const unsigned short* krow = k_s + ((long)b * SS + j) * QS;
                const u16x4* kh = (const u16x4*)&krow[lane * 12];
                const u16x4* kl = (const u16x4*)&krow[DD + lane * 12];
                float part = 0.f;
                #pragma unroll
                for (int c = 0; c < 3; ++c) {
                    u16x4 qa = qh[c], qb = ql[c], ka = kh[c], kb2 = kl[c];
                    #pragma unroll
                    for (int e = 0; e < 4; ++e) {
                        float qv = f16f(qa[e]) + f16f(qb[e]) * 0.015625f;
                        float kv = f16f(ka[e]) + f16f(kb2[e]) * 0.015625f;
                        part = fmaf(qv, kv, part);
                    }
                }
                #pragma unroll
                for (int off = 32; off; off >>= 1) part += __shfl_xor(part, off);
                float dd = qn[g] + kn[(long)b * SS + j] - 2.f * part;
                dd = fmaxf(dd, 0.f);
                if (lane == l2) d[s] = dd;
            }
        }

        sel &= ~cand;
        int C = 0;
        #pragma unroll
        for (int s = 0; s < 32; ++s) C += (int)__popcll(__ballot((sel >> s) & 1u));
        int need = KNEI - C;
        for (int t = 0; t < need; ++t) {
            unsigned long long best = ~0ull;
            #pragma unroll
            for (int s = 0; s < 32; ++s) {
                if (((cand >> s) & 1u) && !((sel >> s) & 1u)) {
                    unsigned long long key =
                        ((unsigned long long)__builtin_bit_cast(unsigned, d[s]) << 32)
                        | (unsigned)((s >> 2) * 256 + lane * 4 + (s & 3));
                    best = key < best ? key : best;
                }
            }
            #pragma unroll
            for (int off = 32; off; off >>= 1) {
                unsigned long long o = __shfl_xor(best, off);
                best = o < best ? o : best;
            }
            if (best != ~0ull) {
                int j = (int)(unsigned)best;
                if (lane == ((j >> 2) & 63)) sel |= 1u << (((j >> 8) << 2) | (j & 3));
            }
        }
    }

    // ---- Phase 4: rank-based selected-index assignment + batched bf16 gather ----
    int myj = 0;
    {
        int target = lane & 31;            // lane p (and p+32) own the p-th selected index
        int cum = 0;
        #pragma unroll
        for (int s = 0; s < 32; ++s) {
            unsigned long long m = __ballot((sel >> s) & 1u);
            int c = (int)__popcll(m);
            if (target >= cum && target < cum + c) {
                int nth = target - cum;
                unsigned long long mm = m;
                int base = 0;
                int c32 = (int)__popcll(mm & 0xffffffffull);
                if (nth >= c32) { nth -= c32; mm >>= 32; base += 32; }
                int c16 = (int)__popcll(mm & 0xffffull);
                if (nth >= c16) { nth -= c16; mm >>= 16; base += 16; }
                int c8 = (int)__popcll(mm & 0xffull);
                if (nth >= c8) { nth -= c8; mm >>= 8; base += 8; }
                int c4 = (int)__popcll(mm & 0xfull);
                if (nth >= c4) { nth -= c4; mm >>= 4; base += 4; }
                int c2 = (int)__popcll(mm & 0x3ull);
                if (nth >= c2) { nth -= c2; mm >>= 2; base += 2; }
                int c1 = (int)(mm & 1ull);
                if (nth >= c1) { base += 1; }
                myj = (s >> 2) * 256 + base * 4 + (s & 3);
            }
            cum += c;
        }
    }
    f32x4 a0 = {0.f, 0.f, 0.f, 0.f}, a1 = a0, a2 = a0;
    #pragma unroll
    for (int tb = 0; tb < 8; ++tb) {
        u16x4 r0[4], r1[4], r2[4];
        #pragma unroll
        for (int u = 0; u < 4; ++u) {
            int j = __shfl(myj, tb * 4 + u);
            const u16x4* vr = (const u16x4*)(vb + (long)j * DD);
            r0[u] = vr[lane];
            r1[u] = vr[lane + 64];
            r2[u] = vr[lane + 128];
        }
        #pragma unroll
        for (int u = 0; u < 4; ++u) {
            #pragma unroll
            for (int e = 0; e < 4; ++e) {
                a0[e] += bf16f(r0[u][e]);
                a1[e] += bf16f(r1[u][e]);
                a2[e] += bf16f(r2[u][e]);
            }
        }
    }
    const float sc = 1.0f / 32.0f;
    unsigned short* trow = topo_f16 + (long)g * DD;
    #pragma unroll
    for (int c = 0; c < 3; ++c) {
        f32x4 x = (c == 0) ? a0 : (c == 1) ? a1 : a2;
        u16x4 hi4;
        #pragma unroll
        for (int e = 0; e < 4; ++e) hi4[e] = ff16(x[e] * sc);
        *(u16x4*)&trow[c * 256 + lane * 4] = hi4;
    }
}

extern "C" void kernel_launch(void* const* d_in, const int* in_sizes, int n_in,
                              void* d_out, int out_size, void* d_ws, size_t ws_size,
                              hipStream_t stream)
{
    const float* hs = (const float*)d_in[0];
    const float* Wq = (const float*)d_in[1];
    const float* bq = (const float*)d_in[2];
    const float* Wk = (const float*)d_in[3];
    const float* bk = (const float*)d_in[4];
    const float* Wv = (const float*)d_in[5];
    const float* bv = (const float*)d_in[6];
    const float* W1 = (const float*)d_in[7];
    const float* b1 = (const float*)d_in[8];
    const float* W2 = (const float*)d_in[9];
    const float* b2 = (const float*)d_in[10];
    float* out = (float*)d_out;

    // ---- workspace layout (peak ~180 MB), time-overlaid ----
    char* w = (char*)d_ws;
    const long DISTB = (long)BB * SS * SS * 4;        // 67,108,864
    const long VB    = (long)BSR * DD * 2;            // 12,582,912 (bf16 v)
    const long WSPL  = (long)DD * K2;                 // elems per 3-term split weight

    float*          dist   = (float*)w;                               // [0, 67.1M)
    unsigned short* h_f16  = (unsigned short*)w;                      // overlays dead dist
    unsigned short* v      = (unsigned short*)(w + DISTB);            // bf16 v
    unsigned short* q_s    = (unsigned short*)(w + DISTB + VB);       // 2-slot
    unsigned short* k_s    = q_s + (long)BSR * QS;                    // 2-slot
    unsigned short* hs_s   = k_s + (long)BSR * QS;                    // 3-term A-layout
    unsigned short* topo_f16 = hs_s;                                  // overlays dead hs_s
    unsigned short* Wqkv_s = hs_s + (long)BSR * K2;                   // 3 weight splits adjacent
    unsigned short* W1_f16 = Wqkv_s;                                  // overlays dead Wqkv
    unsigned short* W2_f16 = Wqkv_s + (long)DD * DD;
    char* tail  = (char*)(Wqkv_s + 3 * WSPL);
    float* qn   = (float*)tail;                        // 8192
    float* kn   = qn + BSR;                            // 8192
    float* pn   = kn + BSR;                            // qnp[8192][12] + knp[8192][12]
    float* bqkv = pn + (long)2 * BSR * 12;             // 2304
    // NOTE: W1_f16/W2_f16 overlay the dead Wqkv_s region, which is only dead
    // AFTER the QKV gemm. prep writes them at [Wqkv_s + 3*WSPL) instead and
    // they are copied... simpler: put W1/W2 f16 in fresh space after tail.
    unsigned short* W12 = (unsigned short*)(bqkv + 2304);
    W1_f16 = W12;
    W2_f16 = W12 + (long)DD * DD;                      // +2.25 MB total

    dim3 blk(256);

    // merged prologue: weight splits + hs split + W1/W2 conv + bias concat
    prep<<<4521, blk, 0, stream>>>(Wq, Wk, Wv, hs, W1, W2, bq, bk, bv,
                                   Wqkv_s, hs_s, W1_f16, W2_f16, bqkv);

    // fused QKV gemm: q -> 2-slot q_s + norms, k -> 2-slot k_s + norms, v -> bf16 (K=768)
    gemm_mfma<4><<<dim3(2304 / 128, BSR / 128, 1), blk, 0, stream>>>(
        hs_s, Wqkv_s, bqkv, nullptr, BSR, 2304, K2, K2, K2,
        q_s, k_s, v, pn);

    finish_norms<<<(2 * BSR) / 256, blk, 0, stream>>>(pn, qn, kn);

    // squared distance matrix per batch: single-term f16 (Kd=768, stride QS)
    gemm256_dist<<<dim3(SS / 256, SS / 256, BB), dim3(512), 0, stream>>>(
        q_s, k_s, qn, kn, dist, SS, DD, QS, QS,
        (long)SS * QS, (long)SS * QS, (long)SS * SS, SS);

    select_mean<<<BSR / 4, blk, 0, stream>>>(dist, v, q_s, k_s, qn, kn, topo_f16);

    // MLP single-term f16: gemm1 -> compact f16 h (relu fused), gemm2 -> f32 out
    gemm_mfma<3><<<dim3(DD / 128, BSR / 128, 1), blk, 0, stream>>>(
        topo_f16, W1_f16, b1, nullptr, BSR, DD, DD, DD, DD,
        h_f16, nullptr, nullptr, nullptr);
    gemm_mfma<0><<<dim3(DD / 128, BSR / 128, 1), blk, 0, stream>>>(
        h_f16, W2_f16, b2, out, BSR, DD, DD, DD, DD,
        nullptr, nullptr, nullptr, nullptr);
}